// Round 1
// baseline (14013.469 us; speedup 1.0000x reference)
//
#include <hip/hip_runtime.h>
#include <hip/hip_bf16.h>

#ifndef NINF_VAL
#define NINF_VAL (-10000.0f)
#endif

// ---------------------------------------------------------------------------
// Embedding: h[b,s,:] = emb[x[b,s],:] + posemb[s,:]
// ---------------------------------------------------------------------------
__global__ void embed_kernel(const int* __restrict__ x,
                             const float* __restrict__ emb,
                             const float* __restrict__ pos,
                             float* __restrict__ h,
                             int S, int D, int total)
{
    int i = blockIdx.x * blockDim.x + threadIdx.x;
    if (i >= total) return;
    int d  = i % D;
    int bs = i / D;
    int s  = bs % S;
    h[i] = emb[(long long)x[bs] * D + d] + pos[(long long)s * D + d];
}

// ---------------------------------------------------------------------------
// LayerNorm over rows of length D=768. One 256-thread block per row,
// 3 elements per thread, two-pass (mean, then var) for accuracy.
// ---------------------------------------------------------------------------
__global__ __launch_bounds__(256) void layernorm_f32(
    const float* __restrict__ X, const float* __restrict__ g,
    const float* __restrict__ b, float* __restrict__ Y, int D)
{
    const int row = blockIdx.x;
    const float* xr = X + (long long)row * D;
    float* yr = Y + (long long)row * D;
    const int tid = threadIdx.x;

    float vals[3];
    float s = 0.0f;
#pragma unroll
    for (int u = 0; u < 3; ++u) { vals[u] = xr[tid + u * 256]; s += vals[u]; }

    __shared__ float red[256];
    red[tid] = s;
    __syncthreads();
    for (int off = 128; off > 0; off >>= 1) {
        if (tid < off) red[tid] += red[tid + off];
        __syncthreads();
    }
    const float mean = red[0] / (float)D;
    __syncthreads();

    float vs = 0.0f;
#pragma unroll
    for (int u = 0; u < 3; ++u) { float d = vals[u] - mean; vs += d * d; }
    red[tid] = vs;
    __syncthreads();
    for (int off = 128; off > 0; off >>= 1) {
        if (tid < off) red[tid] += red[tid + off];
        __syncthreads();
    }
    const float var  = red[0] / (float)D;
    const float rstd = rsqrtf(var + 1e-6f);

#pragma unroll
    for (int u = 0; u < 3; ++u) {
        const int c = tid + u * 256;
        yr[c] = (vals[u] - mean) * rstd * g[c] + b[c];
    }
}

// ---------------------------------------------------------------------------
// In-place row softmax (max-subtracted). One 256-thread block per row.
// ---------------------------------------------------------------------------
__global__ __launch_bounds__(256) void softmax_rows(
    float* __restrict__ X, int cols, long long ld)
{
    float* xr = X + (long long)blockIdx.x * ld;
    const int tid = threadIdx.x;

    float m = -3.0e38f;
    for (int c = tid; c < cols; c += 256) m = fmaxf(m, xr[c]);
    __shared__ float red[256];
    red[tid] = m;
    __syncthreads();
    for (int off = 128; off > 0; off >>= 1) {
        if (tid < off) red[tid] = fmaxf(red[tid], red[tid + off]);
        __syncthreads();
    }
    m = red[0];
    __syncthreads();

    float s = 0.0f;
    for (int c = tid; c < cols; c += 256) {
        float e = expf(xr[c] - m);
        xr[c] = e;
        s += e;
    }
    red[tid] = s;
    __syncthreads();
    for (int off = 128; off > 0; off >>= 1) {
        if (tid < off) red[tid] += red[tid + off];
        __syncthreads();
    }
    const float inv = 1.0f / red[0];
    for (int c = tid; c < cols; c += 256) xr[c] *= inv;
}

// ---------------------------------------------------------------------------
// Generic batched tiled fp32 GEMM:  C = A[M,K] * B + bias  (+epilogue)
//   BT=false: B element [k][n] at B[k*ldb + n]
//   BT=true : B element [k][n] at B[n*ldb + k]   (B stored row-major [N,K])
//   MASK : C += NINF where col > row (causal), applied after *scale
//   ADD  : C[idx] += v (residual accumulate)
//   GELU : v = 0.5*v*(1+erf(v/sqrt(2)))
// Batch: z = blockIdx.z decomposed as (bb = z/HH, hh = z%HH) with per-dim
// element strides for A/B/C.
// Tiles: 64x64 output per 256-thread block, 4x4 per thread, TK=16.
// ---------------------------------------------------------------------------
template<bool BT, bool MASK, bool ADD, bool GELU_>
__global__ __launch_bounds__(256) void gemm_f32(
    const float* __restrict__ A, const float* __restrict__ Bm,
    const float* __restrict__ bias, float* __restrict__ C,
    int M, int N, int K, int lda, int ldb, int ldc,
    long long aSB, long long aSH,
    long long bSB, long long bSH,
    long long cSB, long long cSH,
    int HH, float scale)
{
    const int z  = blockIdx.z;
    const int bb = z / HH, hh = z % HH;
    A  += bb * aSB + (long long)hh * aSH;
    Bm += bb * bSB + (long long)hh * bSH;
    C  += bb * cSB + (long long)hh * cSH;

    __shared__ float sA[64][17];                 // m-major: conflict-free writes, broadcast reads
    __shared__ __align__(16) float sB[16][68];   // kk-major (+4 pad): aligned b128 reads

    const int tid  = threadIdx.x;
    const int tx   = tid & 15;
    const int ty   = tid >> 4;
    const int row0 = blockIdx.x * 64;
    const int col0 = blockIdx.y * 64;

    float acc[4][4] = {};

    for (int k0 = 0; k0 < K; k0 += 16) {
        // ---- stage A tile: sA[m][kk] = A[row0+m][k0+kk]
        {
            const int kk = tid & 15;
            const int mb = (tid >> 4) << 2;
#pragma unroll
            for (int u = 0; u < 4; ++u)
                sA[mb + u][kk] = A[(long long)(row0 + mb + u) * lda + (k0 + kk)];
        }
        // ---- stage B tile: sB[kk][n] = B[k0+kk][col0+n]
        if (!BT) {
            const int n  = tid & 63;
            const int kb = (tid >> 6) << 2;
            const int c  = col0 + n;
#pragma unroll
            for (int u = 0; u < 4; ++u)
                sB[kb + u][n] = (c < N) ? Bm[(long long)(k0 + kb + u) * ldb + c] : 0.0f;
        } else {
            const int kk = tid & 15;
            const int nb = (tid >> 4) << 2;
#pragma unroll
            for (int u = 0; u < 4; ++u) {
                const int c = col0 + nb + u;
                sB[kk][nb + u] = (c < N) ? Bm[(long long)c * ldb + (k0 + kk)] : 0.0f;
            }
        }
        __syncthreads();

#pragma unroll
        for (int kk = 0; kk < 16; ++kk) {
            const float4 b4 = *(const float4*)&sB[kk][tx << 2];
            float a[4];
#pragma unroll
            for (int i = 0; i < 4; ++i) a[i] = sA[(ty << 2) + i][kk];
            float bv[4] = { b4.x, b4.y, b4.z, b4.w };
#pragma unroll
            for (int i = 0; i < 4; ++i)
#pragma unroll
                for (int j = 0; j < 4; ++j)
                    acc[i][j] += a[i] * bv[j];
        }
        __syncthreads();
    }

#pragma unroll
    for (int i = 0; i < 4; ++i) {
        const int r = row0 + (ty << 2) + i;
#pragma unroll
        for (int j = 0; j < 4; ++j) {
            const int c = col0 + (tx << 2) + j;
            if (c < N) {
                float v = acc[i][j] * scale;
                if (bias) v += bias[c];
                if (MASK) { if (c > r) v += NINF_VAL; }
                if (GELU_) v = 0.5f * v * (1.0f + erff(v * 0.70710678118654752f));
                const long long idx = (long long)r * ldc + c;
                if (ADD) v += C[idx];
                C[idx] = v;
            }
        }
    }
}

// ---------------------------------------------------------------------------
// Launcher
// ---------------------------------------------------------------------------
extern "C" void kernel_launch(void* const* d_in, const int* in_sizes, int n_in,
                              void* d_out, int out_size, void* d_ws, size_t ws_size,
                              hipStream_t stream)
{
    constexpr int B = 4, S = 512, D = 768, L = 12, V = 50257, H = 12, F = 3072;
    constexpr int M  = B * S;     // 2048
    constexpr int TD = 3 * D;     // 2304
    const float SCALE = 0.125f;   // 1/sqrt(64)

    const int*   x    = (const int*)  d_in[0];
    const float* emb  = (const float*)d_in[1];
    const float* pos  = (const float*)d_in[2];
    const float* ln1g = (const float*)d_in[3];
    const float* ln1b = (const float*)d_in[4];
    const float* wqkv = (const float*)d_in[5];
    const float* bqkv = (const float*)d_in[6];
    const float* wo   = (const float*)d_in[7];
    const float* bo   = (const float*)d_in[8];
    const float* ln2g = (const float*)d_in[9];
    const float* ln2b = (const float*)d_in[10];
    const float* wfc  = (const float*)d_in[11];
    const float* bfc  = (const float*)d_in[12];
    const float* wpr  = (const float*)d_in[13];
    const float* bpr  = (const float*)d_in[14];
    const float* lnfg = (const float*)d_in[15];
    const float* lnfb = (const float*)d_in[16];

    float* probs  = (float*)d_out;                    // [M, V]
    float* hidden = probs + (size_t)M * V;            // [M, D]

    float* ws  = (float*)d_ws;
    float* h   = ws;                                  // [M, D]
    float* xn  = h   + (size_t)M * D;                 // [M, D]
    float* qkv = xn  + (size_t)M * D;                 // [M, 3D]
    float* o   = qkv + (size_t)M * TD;                // [M, D]
    float* big = o   + (size_t)M * D;                 // union: scores [B*H,S,S] / mid [M,F]
    float* sc  = big;
    float* mid = big;

    // ---- embedding
    embed_kernel<<<dim3((M * D + 255) / 256), 256, 0, stream>>>(x, emb, pos, h, S, D, M * D);

    for (int i = 0; i < L; ++i) {
        // pre-attn LN
        layernorm_f32<<<M, 256, 0, stream>>>(h, ln1g + (size_t)i * D, ln1b + (size_t)i * D, xn, D);

        // qkv = xn @ wqkv + bqkv    [M, 3D]
        gemm_f32<false, false, false, false><<<dim3(M / 64, TD / 64, 1), 256, 0, stream>>>(
            xn, wqkv + (size_t)i * D * TD, bqkv + (size_t)i * TD, qkv,
            M, TD, D, D, TD, TD,
            0, 0, 0, 0, 0, 0, 1, 1.0f);

        // scores[b,h,q,k] = scale * q.k^T + causal mask
        gemm_f32<true, true, false, false><<<dim3(S / 64, S / 64, B * H), 256, 0, stream>>>(
            qkv /*q*/, qkv + D /*k*/, nullptr, sc,
            S, S, 64, TD, TD, S,
            (long long)S * TD, 64,
            (long long)S * TD, 64,
            (long long)H * S * S, (long long)S * S, H, SCALE);

        // softmax over keys
        softmax_rows<<<B * H * S, 256, 0, stream>>>(sc, S, (long long)S);

        // o[b,q,h,:] = scores @ v
        gemm_f32<false, false, false, false><<<dim3(S / 64, 1, B * H), 256, 0, stream>>>(
            sc, qkv + 2 * D /*v*/, nullptr, o,
            S, 64, S, S, TD, D,
            (long long)H * S * S, (long long)S * S,
            (long long)S * TD, 64,
            (long long)S * D, 64, H, 1.0f);

        // h += o @ wo + bo
        gemm_f32<false, false, true, false><<<dim3(M / 64, D / 64, 1), 256, 0, stream>>>(
            o, wo + (size_t)i * D * D, bo + (size_t)i * D, h,
            M, D, D, D, D, D,
            0, 0, 0, 0, 0, 0, 1, 1.0f);

        // pre-MLP LN
        layernorm_f32<<<M, 256, 0, stream>>>(h, ln2g + (size_t)i * D, ln2b + (size_t)i * D, xn, D);

        // mid = gelu(xn @ wfc + bfc)   [M, F]
        gemm_f32<false, false, false, true><<<dim3(M / 64, F / 64, 1), 256, 0, stream>>>(
            xn, wfc + (size_t)i * D * F, bfc + (size_t)i * F, mid,
            M, F, D, D, F, F,
            0, 0, 0, 0, 0, 0, 1, 1.0f);

        // h += mid @ wproj + bproj
        gemm_f32<false, false, true, false><<<dim3(M / 64, D / 64, 1), 256, 0, stream>>>(
            mid, wpr + (size_t)i * F * D, bpr + (size_t)i * D, h,
            M, D, F, F, D, D,
            0, 0, 0, 0, 0, 0, 1, 1.0f);
    }

    // final LN -> hidden (output 1)
    layernorm_f32<<<M, 256, 0, stream>>>(h, lnfg, lnfb, hidden, D);

    // logits = hidden @ emb^T   -> probs region (output 0)
    gemm_f32<true, false, false, false><<<dim3(M / 64, (V + 63) / 64, 1), 256, 0, stream>>>(
        hidden, emb, nullptr, probs,
        M, V, D, D, D, V,
        0, 0, 0, 0, 0, 0, 1, 1.0f);

    // vocab softmax in place
    softmax_rows<<<M, 256, 0, stream>>>(probs, V, (long long)V);
}

// Round 2
// 4832.221 us; speedup vs baseline: 2.9000x; 2.9000x over previous
//
#include <hip/hip_runtime.h>
#include <hip/hip_bf16.h>

#ifndef NINF_VAL
#define NINF_VAL (-10000.0f)
#endif

typedef __bf16 bf16_t;
typedef bf16_t bf16x8 __attribute__((ext_vector_type(8)));
typedef float  f32x4  __attribute__((ext_vector_type(4)));

// ---------------------------------------------------------------------------
// global -> LDS async copy, 16B per lane. lds base must be wave-uniform.
// ---------------------------------------------------------------------------
__device__ __forceinline__ void gload16(const void* g, void* l) {
    __builtin_amdgcn_global_load_lds(
        (const __attribute__((address_space(1))) unsigned int*)g,
        (__attribute__((address_space(3))) unsigned int*)l, 16, 0, 0);
}

// ---------------------------------------------------------------------------
// Embedding: h[b,s,:] = emb[x[b,s],:] + posemb[s,:]
// ---------------------------------------------------------------------------
__global__ void embed_kernel(const int* __restrict__ x,
                             const float* __restrict__ emb,
                             const float* __restrict__ pos,
                             float* __restrict__ h,
                             int S, int D, int total)
{
    int i = blockIdx.x * blockDim.x + threadIdx.x;
    if (i >= total) return;
    int d  = i % D;
    int bs = i / D;
    int s  = bs % S;
    h[i] = emb[(long long)x[bs] * D + d] + pos[(long long)s * D + d];
}

// ---------------------------------------------------------------------------
// elementwise f32 -> bf16 (vectorized by 4)
// ---------------------------------------------------------------------------
__global__ void convert_bf16(const float* __restrict__ in, bf16_t* __restrict__ out, int n4)
{
    int i = blockIdx.x * blockDim.x + threadIdx.x;
    for (; i < n4; i += gridDim.x * blockDim.x) {
        float4 v = ((const float4*)in)[i];
        bf16_t* o = out + (size_t)i * 4;
        o[0] = (bf16_t)v.x; o[1] = (bf16_t)v.y; o[2] = (bf16_t)v.z; o[3] = (bf16_t)v.w;
    }
}

// ---------------------------------------------------------------------------
// Batched transpose + bf16 convert: out[z][n][k] = (bf16) in[z][k][n]
// 32x32 tiles, block (32,8).
// ---------------------------------------------------------------------------
__global__ __launch_bounds__(256) void transpose_to_bf16(
    const float* __restrict__ in, bf16_t* __restrict__ out, int K, int N)
{
    const float* ip = in  + (size_t)blockIdx.z * K * N;
    bf16_t*      op = out + (size_t)blockIdx.z * K * N;
    __shared__ float t[32][33];
    const int n0 = blockIdx.x * 32, k0 = blockIdx.y * 32;
    const int tx = threadIdx.x, ty = threadIdx.y;
#pragma unroll
    for (int u = 0; u < 4; ++u)
        t[ty + u * 8][tx] = ip[(size_t)(k0 + ty + u * 8) * N + (n0 + tx)];
    __syncthreads();
#pragma unroll
    for (int u = 0; u < 4; ++u)
        op[(size_t)(n0 + ty + u * 8) * K + (k0 + tx)] = (bf16_t)t[tx][ty + u * 8];
}

// ---------------------------------------------------------------------------
// LayerNorm rows of D=768; writes bf16 (always) and f32 (if Yf != nullptr).
// ---------------------------------------------------------------------------
__global__ __launch_bounds__(256) void layernorm_dual(
    const float* __restrict__ X, const float* __restrict__ g,
    const float* __restrict__ b, bf16_t* __restrict__ Yb,
    float* __restrict__ Yf, int D)
{
    const int row = blockIdx.x;
    const float* xr = X + (long long)row * D;
    const int tid = threadIdx.x;

    float vals[3];
    float s = 0.0f;
#pragma unroll
    for (int u = 0; u < 3; ++u) { vals[u] = xr[tid + u * 256]; s += vals[u]; }

    __shared__ float red[256];
    red[tid] = s;
    __syncthreads();
    for (int off = 128; off > 0; off >>= 1) {
        if (tid < off) red[tid] += red[tid + off];
        __syncthreads();
    }
    const float mean = red[0] / (float)D;
    __syncthreads();

    float vs = 0.0f;
#pragma unroll
    for (int u = 0; u < 3; ++u) { float d = vals[u] - mean; vs += d * d; }
    red[tid] = vs;
    __syncthreads();
    for (int off = 128; off > 0; off >>= 1) {
        if (tid < off) red[tid] += red[tid + off];
        __syncthreads();
    }
    const float var  = red[0] / (float)D;
    const float rstd = rsqrtf(var + 1e-6f);

#pragma unroll
    for (int u = 0; u < 3; ++u) {
        const int c = tid + u * 256;
        const float y = (vals[u] - mean) * rstd * g[c] + b[c];
        Yb[(long long)row * D + c] = (bf16_t)y;
        if (Yf) Yf[(long long)row * D + c] = y;
    }
}

// ---------------------------------------------------------------------------
// In-place row softmax (max-subtracted). One 256-thread block per row.
// ---------------------------------------------------------------------------
__global__ __launch_bounds__(256) void softmax_rows(
    float* __restrict__ X, int cols, long long ld)
{
    float* xr = X + (long long)blockIdx.x * ld;
    const int tid = threadIdx.x;

    float m = -3.0e38f;
    for (int c = tid; c < cols; c += 256) m = fmaxf(m, xr[c]);
    __shared__ float red[256];
    red[tid] = m;
    __syncthreads();
    for (int off = 128; off > 0; off >>= 1) {
        if (tid < off) red[tid] = fmaxf(red[tid], red[tid + off]);
        __syncthreads();
    }
    m = red[0];
    __syncthreads();

    float s = 0.0f;
    for (int c = tid; c < cols; c += 256) {
        float e = expf(xr[c] - m);
        xr[c] = e;
        s += e;
    }
    red[tid] = s;
    __syncthreads();
    for (int off = 128; off > 0; off >>= 1) {
        if (tid < off) red[tid] += red[tid + off];
        __syncthreads();
    }
    const float inv = 1.0f / red[0];
    for (int c = tid; c < cols; c += 256) xr[c] *= inv;
}

// ---------------------------------------------------------------------------
// bf16 MFMA GEMM (m97 structure): C[M,N] = A[M,K] @ B^T[N,K] + bias
//   128x128 tile / 256 threads (4 waves in 2x2, 64x64 per wave, 4x4 frags)
//   BK=32, global_load_lds width-16 staging, 16x16x32 bf16 MFMA, fp32 acc.
//   ADD: C += v (fp32 residual); GELU_: erf-gelu; OUTBF: write bf16 to C.
//   M % 128 == 0 and K % 32 == 0 required; N guarded.
// ---------------------------------------------------------------------------
template<bool ADD, bool GELU_, bool OUTBF>
__global__ __launch_bounds__(256) void gemm_mfma(
    const bf16_t* __restrict__ A, const bf16_t* __restrict__ Bw,
    const float* __restrict__ bias, float* __restrict__ C,
    int M, int N, int K, int ldc)
{
    __shared__ bf16_t lds[8192];            // A tile [128][32] @0, B tile [128][32] @4096

    const int tid  = threadIdx.x;
    const int lane = tid & 63;
    const int w    = tid >> 6;
    const int wr   = w >> 1, wc = w & 1;
    const int row0 = blockIdx.x * 128;
    const int col0 = blockIdx.y * 128;

    // staging addresses: each wave stages 32 rows of A and 32 rows of B^T,
    // 2 chunks of 16 rows; 4 lanes per row (16B each).
    const int lrow = lane >> 2;             // 0..15
    const int lq   = lane & 3;              // 16B sub-chunk within 64B row
    const int aRow = row0 + w * 32 + lrow;
    int br0 = col0 + w * 32 + lrow;
    int br1 = br0 + 16;
    if (br0 >= N) br0 = 0;                  // clamp (values unused)
    if (br1 >= N) br1 = 0;

    const bf16_t* aSrc0 = A  + (size_t)aRow * K + lq * 8;
    const bf16_t* aSrc1 = aSrc0 + (size_t)16 * K;
    const bf16_t* bSrc0 = Bw + (size_t)br0 * K + lq * 8;
    const bf16_t* bSrc1 = Bw + (size_t)br1 * K + lq * 8;

    bf16_t* ldsA = lds + w * 1024;          // wave-uniform bases (HW adds lane*16B)
    bf16_t* ldsB = lds + 4096 + w * 1024;

    f32x4 acc[4][4];
#pragma unroll
    for (int m = 0; m < 4; ++m)
#pragma unroll
        for (int n = 0; n < 4; ++n)
            acc[m][n] = (f32x4){0.f, 0.f, 0.f, 0.f};

    const int fr  = lane & 15;              // fragment row/col within 16
    const int sub = (lane >> 4) * 8;        // k sub-block

    for (int k0 = 0; k0 < K; k0 += 32) {
        gload16(aSrc0, ldsA);
        gload16(aSrc1, ldsA + 512);
        gload16(bSrc0, ldsB);
        gload16(bSrc1, ldsB + 512);
        aSrc0 += 32; aSrc1 += 32; bSrc0 += 32; bSrc1 += 32;
        __syncthreads();                    // drains vmcnt + barrier

        bf16x8 af[4], bfr[4];
#pragma unroll
        for (int m = 0; m < 4; ++m)
            af[m] = *(const bf16x8*)&lds[(wr * 64 + m * 16 + fr) * 32 + sub];
#pragma unroll
        for (int n = 0; n < 4; ++n)
            bfr[n] = *(const bf16x8*)&lds[4096 + (wc * 64 + n * 16 + fr) * 32 + sub];

#pragma unroll
        for (int m = 0; m < 4; ++m)
#pragma unroll
            for (int n = 0; n < 4; ++n)
                acc[m][n] = __builtin_amdgcn_mfma_f32_16x16x32_bf16(
                    af[m], bfr[n], acc[m][n], 0, 0, 0);
        __syncthreads();
    }

    // epilogue: C/D layout col = lane&15, row = (lane>>4)*4 + reg
    const int rBase = row0 + wr * 64 + (lane >> 4) * 4;
    const int cBase = col0 + wc * 64 + fr;
#pragma unroll
    for (int n = 0; n < 4; ++n) {
        const int c = cBase + n * 16;
        if (c >= N) continue;
        const float bv = bias ? bias[c] : 0.0f;
#pragma unroll
        for (int m = 0; m < 4; ++m) {
#pragma unroll
            for (int r = 0; r < 4; ++r) {
                const int rr = rBase + m * 16 + r;
                float v = acc[m][n][r] + bv;
                if (GELU_) v = 0.5f * v * (1.0f + erff(v * 0.70710678118654752f));
                const size_t idx = (size_t)rr * ldc + c;
                if (OUTBF) {
                    ((bf16_t*)C)[idx] = (bf16_t)v;
                } else {
                    if (ADD) v += C[idx];
                    C[idx] = v;
                }
            }
        }
    }
}

// ---------------------------------------------------------------------------
// fp32 SIMT GEMM (attention only): C = A[M,K] * B (+scale, +causal mask)
//   BT: B stored [N,K] (row-major) ; OUTBF: write bf16
//   batched via blockIdx.z -> (bb, hh) with element strides.
// ---------------------------------------------------------------------------
template<bool BT, bool MASK, bool OUTBF>
__global__ __launch_bounds__(256) void gemm_f32(
    const float* __restrict__ A, const float* __restrict__ Bm,
    float* __restrict__ C,
    int M, int N, int K, int lda, int ldb, int ldc,
    long long aSB, long long aSH,
    long long bSB, long long bSH,
    long long cSB, long long cSH,
    int HH, float scale)
{
    const int z  = blockIdx.z;
    const int bb = z / HH, hh = z % HH;
    A  += bb * aSB + (long long)hh * aSH;
    Bm += bb * bSB + (long long)hh * bSH;
    const long long cOff = bb * cSB + (long long)hh * cSH;

    __shared__ float sA[64][17];
    __shared__ __align__(16) float sB[16][68];

    const int tid  = threadIdx.x;
    const int tx   = tid & 15;
    const int ty   = tid >> 4;
    const int row0 = blockIdx.x * 64;
    const int col0 = blockIdx.y * 64;

    float acc[4][4] = {};

    for (int k0 = 0; k0 < K; k0 += 16) {
        {
            const int kk = tid & 15;
            const int mb = (tid >> 4) << 2;
#pragma unroll
            for (int u = 0; u < 4; ++u)
                sA[mb + u][kk] = A[(long long)(row0 + mb + u) * lda + (k0 + kk)];
        }
        if (!BT) {
            const int n  = tid & 63;
            const int kb = (tid >> 6) << 2;
            const int c  = col0 + n;
#pragma unroll
            for (int u = 0; u < 4; ++u)
                sB[kb + u][n] = (c < N) ? Bm[(long long)(k0 + kb + u) * ldb + c] : 0.0f;
        } else {
            const int kk = tid & 15;
            const int nb = (tid >> 4) << 2;
#pragma unroll
            for (int u = 0; u < 4; ++u) {
                const int c = col0 + nb + u;
                sB[kk][nb + u] = (c < N) ? Bm[(long long)c * ldb + (k0 + kk)] : 0.0f;
            }
        }
        __syncthreads();

#pragma unroll
        for (int kk = 0; kk < 16; ++kk) {
            const float4 b4 = *(const float4*)&sB[kk][tx << 2];
            float a[4];
#pragma unroll
            for (int i = 0; i < 4; ++i) a[i] = sA[(ty << 2) + i][kk];
            float bv[4] = { b4.x, b4.y, b4.z, b4.w };
#pragma unroll
            for (int i = 0; i < 4; ++i)
#pragma unroll
                for (int j = 0; j < 4; ++j)
                    acc[i][j] += a[i] * bv[j];
        }
        __syncthreads();
    }

#pragma unroll
    for (int i = 0; i < 4; ++i) {
        const int r = row0 + (ty << 2) + i;
#pragma unroll
        for (int j = 0; j < 4; ++j) {
            const int c = col0 + (tx << 2) + j;
            if (c < N) {
                float v = acc[i][j] * scale;
                if (MASK) { if (c > r) v += NINF_VAL; }
                const long long idx = cOff + (long long)r * ldc + c;
                if (OUTBF) ((bf16_t*)C)[idx] = (bf16_t)v;
                else       C[idx] = v;
            }
        }
    }
}

// ---------------------------------------------------------------------------
// Launcher
// ---------------------------------------------------------------------------
extern "C" void kernel_launch(void* const* d_in, const int* in_sizes, int n_in,
                              void* d_out, int out_size, void* d_ws, size_t ws_size,
                              hipStream_t stream)
{
    constexpr int B = 4, S = 512, D = 768, L = 12, V = 50257, H = 12, F = 3072;
    constexpr int M  = B * S;     // 2048
    constexpr int TD = 3 * D;     // 2304
    const float SCALE = 0.125f;   // 1/sqrt(64)

    const int*   x    = (const int*)  d_in[0];
    const float* emb  = (const float*)d_in[1];
    const float* pos  = (const float*)d_in[2];
    const float* ln1g = (const float*)d_in[3];
    const float* ln1b = (const float*)d_in[4];
    const float* wqkv = (const float*)d_in[5];
    const float* bqkv = (const float*)d_in[6];
    const float* wo   = (const float*)d_in[7];
    const float* bo   = (const float*)d_in[8];
    const float* ln2g = (const float*)d_in[9];
    const float* ln2b = (const float*)d_in[10];
    const float* wfc  = (const float*)d_in[11];
    const float* bfc  = (const float*)d_in[12];
    const float* wpr  = (const float*)d_in[13];
    const float* bpr  = (const float*)d_in[14];
    const float* lnfg = (const float*)d_in[15];
    const float* lnfb = (const float*)d_in[16];

    float* probs  = (float*)d_out;                    // [M, V]
    float* hidden = probs + (size_t)M * V;            // [M, D]

    // ---- workspace layout
    float* ws = (float*)d_ws;
    float* h   = ws;                                  // [M, D] f32
    float* qkv = h   + (size_t)M * D;                 // [M, 3D] f32
    float* sc  = qkv + (size_t)M * TD;                // [B*H, S, S] f32
    bf16_t* bws    = (bf16_t*)(sc + (size_t)B * H * S * S);
    bf16_t* xn_bf  = bws;                             // [M, D]
    bf16_t* o_bf   = xn_bf  + (size_t)M * D;          // [M, D]
    bf16_t* mid_bf = o_bf   + (size_t)M * D;          // [M, F]
    bf16_t* hid_bf = mid_bf + (size_t)M * F;          // [M, D]
    bf16_t* wqkvT  = hid_bf + (size_t)M * D;          // [L, 3D, D]
    bf16_t* woT    = wqkvT  + (size_t)L * D * TD;     // [L, D, D]
    bf16_t* wfcT   = woT    + (size_t)L * D * D;      // [L, F, D]
    bf16_t* wprT   = wfcT   + (size_t)L * D * F;      // [L, D, F]
    bf16_t* embB   = wprT   + (size_t)L * F * D;      // [V, D]

    // ---- weight prep (per launch; deterministic)
    convert_bf16<<<2048, 256, 0, stream>>>(emb, embB, (V * D) / 4);
    transpose_to_bf16<<<dim3(TD / 32, D / 32, L), dim3(32, 8), 0, stream>>>(wqkv, wqkvT, D, TD);
    transpose_to_bf16<<<dim3(D / 32,  D / 32, L), dim3(32, 8), 0, stream>>>(wo,   woT,   D, D);
    transpose_to_bf16<<<dim3(F / 32,  D / 32, L), dim3(32, 8), 0, stream>>>(wfc,  wfcT,  D, F);
    transpose_to_bf16<<<dim3(D / 32,  F / 32, L), dim3(32, 8), 0, stream>>>(wpr,  wprT,  F, D);

    // ---- embedding
    embed_kernel<<<dim3((M * D + 255) / 256), 256, 0, stream>>>(x, emb, pos, h, S, D, M * D);

    for (int i = 0; i < L; ++i) {
        // pre-attn LN -> bf16
        layernorm_dual<<<M, 256, 0, stream>>>(h, ln1g + (size_t)i * D, ln1b + (size_t)i * D,
                                              xn_bf, nullptr, D);

        // qkv = xn @ wqkv + bqkv   (f32 out)
        gemm_mfma<false, false, false><<<dim3(M / 128, TD / 128), 256, 0, stream>>>(
            xn_bf, wqkvT + (size_t)i * D * TD, bqkv + (size_t)i * TD, qkv,
            M, TD, D, TD);

        // scores = scale * q.k^T + causal mask  (f32)
        gemm_f32<true, true, false><<<dim3(S / 64, S / 64, B * H), 256, 0, stream>>>(
            qkv /*q*/, qkv + D /*k*/, sc,
            S, S, 64, TD, TD, S,
            (long long)S * TD, 64,
            (long long)S * TD, 64,
            (long long)H * S * S, (long long)S * S, H, SCALE);

        softmax_rows<<<B * H * S, 256, 0, stream>>>(sc, S, (long long)S);

        // o = scores @ v  -> bf16 [M, D] (per-head 64-col slices)
        gemm_f32<false, false, true><<<dim3(S / 64, 1, B * H), 256, 0, stream>>>(
            sc, qkv + 2 * D /*v*/, (float*)o_bf,
            S, 64, S, S, TD, D,
            (long long)H * S * S, (long long)S * S,
            (long long)S * TD, 64,
            (long long)S * D, 64, H, 1.0f);

        // h += o @ wo + bo
        gemm_mfma<true, false, false><<<dim3(M / 128, D / 128), 256, 0, stream>>>(
            o_bf, woT + (size_t)i * D * D, bo + (size_t)i * D, h,
            M, D, D, D);

        // pre-MLP LN -> bf16
        layernorm_dual<<<M, 256, 0, stream>>>(h, ln2g + (size_t)i * D, ln2b + (size_t)i * D,
                                              xn_bf, nullptr, D);

        // mid = gelu(xn @ wfc + bfc)  -> bf16
        gemm_mfma<false, true, true><<<dim3(M / 128, F / 128), 256, 0, stream>>>(
            xn_bf, wfcT + (size_t)i * D * F, bfc + (size_t)i * F, (float*)mid_bf,
            M, F, D, F);

        // h += mid @ wproj + bproj
        gemm_mfma<true, false, false><<<dim3(M / 128, D / 128), 256, 0, stream>>>(
            mid_bf, wprT + (size_t)i * F * D, bpr + (size_t)i * D, h,
            M, D, F, D);
    }

    // final LN -> hidden f32 (output 1) + bf16 copy
    layernorm_dual<<<M, 256, 0, stream>>>(h, lnfg, lnfb, hid_bf, hidden, D);

    // logits = hidden @ emb^T  (emb is [V,K] = B^T form already)
    gemm_mfma<false, false, false><<<dim3(M / 128, (V + 127) / 128), 256, 0, stream>>>(
        hid_bf, embB, nullptr, probs,
        M, V, D, V);

    // vocab softmax in place
    softmax_rows<<<M, 256, 0, stream>>>(probs, V, (long long)V);
}

// Round 3
// 3677.541 us; speedup vs baseline: 3.8106x; 1.3140x over previous
//
#include <hip/hip_runtime.h>
#include <hip/hip_bf16.h>

#ifndef NINF_VAL
#define NINF_VAL (-10000.0f)
#endif

typedef __bf16 bf16_t;
typedef bf16_t bf16x8 __attribute__((ext_vector_type(8)));
typedef bf16_t bf16x2 __attribute__((ext_vector_type(2)));
typedef float  f32x4  __attribute__((ext_vector_type(4)));

// ---------------------------------------------------------------------------
// global -> LDS async copy, 16B per lane. lds base must be wave-uniform.
// ---------------------------------------------------------------------------
__device__ __forceinline__ void gload16(const void* g, void* l) {
    __builtin_amdgcn_global_load_lds(
        (const __attribute__((address_space(1))) unsigned int*)g,
        (__attribute__((address_space(3))) unsigned int*)l, 16, 0, 0);
}

// ---------------------------------------------------------------------------
// Embedding: h[b,s,:] = emb[x[b,s],:] + posemb[s,:]
// ---------------------------------------------------------------------------
__global__ void embed_kernel(const int* __restrict__ x,
                             const float* __restrict__ emb,
                             const float* __restrict__ pos,
                             float* __restrict__ h,
                             int S, int D, int total)
{
    int i = blockIdx.x * blockDim.x + threadIdx.x;
    if (i >= total) return;
    int d  = i % D;
    int bs = i / D;
    int s  = bs % S;
    h[i] = emb[(long long)x[bs] * D + d] + pos[(long long)s * D + d];
}

// ---------------------------------------------------------------------------
// elementwise f32 -> bf16 (vectorized by 4)
// ---------------------------------------------------------------------------
__global__ void convert_bf16(const float* __restrict__ in, bf16_t* __restrict__ out, int n4)
{
    int i = blockIdx.x * blockDim.x + threadIdx.x;
    for (; i < n4; i += gridDim.x * blockDim.x) {
        float4 v = ((const float4*)in)[i];
        bf16_t* o = out + (size_t)i * 4;
        o[0] = (bf16_t)v.x; o[1] = (bf16_t)v.y; o[2] = (bf16_t)v.z; o[3] = (bf16_t)v.w;
    }
}

// ---------------------------------------------------------------------------
// Batched transpose + bf16 convert: out[z][n][k] = (bf16) in[z][k][n]
// ---------------------------------------------------------------------------
__global__ __launch_bounds__(256) void transpose_to_bf16(
    const float* __restrict__ in, bf16_t* __restrict__ out, int K, int N)
{
    const float* ip = in  + (size_t)blockIdx.z * K * N;
    bf16_t*      op = out + (size_t)blockIdx.z * K * N;
    __shared__ float t[32][33];
    const int n0 = blockIdx.x * 32, k0 = blockIdx.y * 32;
    const int tx = threadIdx.x, ty = threadIdx.y;
#pragma unroll
    for (int u = 0; u < 4; ++u)
        t[ty + u * 8][tx] = ip[(size_t)(k0 + ty + u * 8) * N + (n0 + tx)];
    __syncthreads();
#pragma unroll
    for (int u = 0; u < 4; ++u)
        op[(size_t)(n0 + ty + u * 8) * K + (k0 + tx)] = (bf16_t)t[tx][ty + u * 8];
}

// ---------------------------------------------------------------------------
// Per-head V transpose: vT[z][d][k] = qkv[bb*S + k][2D + hh*64 + d], z=bb*H+hh
// ---------------------------------------------------------------------------
__global__ __launch_bounds__(256) void transpose_v(
    const bf16_t* __restrict__ qkv, bf16_t* __restrict__ vT)
{
    constexpr int S = 512, TD = 2304, D = 768, H = 12;
    const int z = blockIdx.y, bb = z / H, hh = z - bb * H;
    const int k0 = blockIdx.x * 64;
    const bf16_t* src = qkv + (size_t)(bb * S + k0) * TD + 2 * D + hh * 64;
    bf16_t* dst = vT + (size_t)z * 64 * S + k0;
    __shared__ bf16_t sm[64][68];
    const int c = threadIdx.x & 63, rq = threadIdx.x >> 6;
#pragma unroll
    for (int u = 0; u < 16; ++u) {
        const int r = u * 4 + rq;
        sm[r][c] = src[(size_t)r * TD + c];
    }
    __syncthreads();
#pragma unroll
    for (int u = 0; u < 16; ++u) {
        const int d = u * 4 + rq;
        dst[(size_t)d * S + c] = sm[c][d];
    }
}

// ---------------------------------------------------------------------------
// LayerNorm rows of D=768; writes bf16 (always) and f32 (if Yf != nullptr).
// ---------------------------------------------------------------------------
__global__ __launch_bounds__(256) void layernorm_dual(
    const float* __restrict__ X, const float* __restrict__ g,
    const float* __restrict__ b, bf16_t* __restrict__ Yb,
    float* __restrict__ Yf, int D)
{
    const int row = blockIdx.x;
    const float* xr = X + (long long)row * D;
    const int tid = threadIdx.x;

    float vals[3];
    float s = 0.0f;
#pragma unroll
    for (int u = 0; u < 3; ++u) { vals[u] = xr[tid + u * 256]; s += vals[u]; }

    __shared__ float red[256];
    red[tid] = s;
    __syncthreads();
    for (int off = 128; off > 0; off >>= 1) {
        if (tid < off) red[tid] += red[tid + off];
        __syncthreads();
    }
    const float mean = red[0] / (float)D;
    __syncthreads();

    float vs = 0.0f;
#pragma unroll
    for (int u = 0; u < 3; ++u) { float d = vals[u] - mean; vs += d * d; }
    red[tid] = vs;
    __syncthreads();
    for (int off = 128; off > 0; off >>= 1) {
        if (tid < off) red[tid] += red[tid + off];
        __syncthreads();
    }
    const float var  = red[0] / (float)D;
    const float rstd = rsqrtf(var + 1e-6f);

#pragma unroll
    for (int u = 0; u < 3; ++u) {
        const int c = tid + u * 256;
        const float y = (vals[u] - mean) * rstd * g[c] + b[c];
        Yb[(long long)row * D + c] = (bf16_t)y;
        if (Yf) Yf[(long long)row * D + c] = y;
    }
}

// ---------------------------------------------------------------------------
// Score softmax: one block per row of 512 f32 scores -> bf16 probabilities.
// ---------------------------------------------------------------------------
__global__ __launch_bounds__(256) void softmax_scores(
    const float* __restrict__ sc, bf16_t* __restrict__ P)
{
    const long long base = (long long)blockIdx.x * 512;
    const int tid = threadIdx.x;
    const float2 v2 = ((const float2*)(sc + base))[tid];

    __shared__ float red[256];
    float m = fmaxf(v2.x, v2.y);
    red[tid] = m;
    __syncthreads();
    for (int off = 128; off > 0; off >>= 1) {
        if (tid < off) red[tid] = fmaxf(red[tid], red[tid + off]);
        __syncthreads();
    }
    m = red[0];
    __syncthreads();

    const float e0 = expf(v2.x - m), e1 = expf(v2.y - m);
    red[tid] = e0 + e1;
    __syncthreads();
    for (int off = 128; off > 0; off >>= 1) {
        if (tid < off) red[tid] += red[tid + off];
        __syncthreads();
    }
    const float inv = 1.0f / red[0];
    bf16x2 o; o.x = (bf16_t)(e0 * inv); o.y = (bf16_t)(e1 * inv);
    ((bf16x2*)(P + base))[tid] = o;
}

// ---------------------------------------------------------------------------
// Vocab softmax: bf16 logits (row stride Vp) -> f32 probs (row stride V).
// Pass 1: online (max,sum) in one read. Pass 2: write exp(v-m)/s.
// ---------------------------------------------------------------------------
__global__ __launch_bounds__(256) void softmax_vocab(
    const bf16_t* __restrict__ logits, float* __restrict__ probs, int V, int Vp)
{
    const int tid = threadIdx.x;
    const bf16_t* lr = logits + (size_t)blockIdx.x * Vp;
    float* pr = probs + (size_t)blockIdx.x * V;
    const int nfull = V >> 3, rem = V & 7;

    float m = -3.0e38f, s = 0.0f;
    for (int c8 = tid; c8 < nfull; c8 += 256) {
        const bf16x8 v = *(const bf16x8*)(lr + (size_t)c8 * 8);
#pragma unroll
        for (int j = 0; j < 8; ++j) {
            const float f = (float)v[j];
            if (f > m) { s = s * expf(m - f) + 1.0f; m = f; }
            else       { s += expf(f - m); }
        }
    }
    if (tid == 0) {
        for (int j = 0; j < rem; ++j) {
            const float f = (float)lr[nfull * 8 + j];
            if (f > m) { s = s * expf(m - f) + 1.0f; m = f; }
            else       { s += expf(f - m); }
        }
    }

    __shared__ float mS[256], sS[256];
    mS[tid] = m; sS[tid] = s;
    __syncthreads();
    for (int off = 128; off > 0; off >>= 1) {
        if (tid < off) {
            const float m1 = mS[tid], m2 = mS[tid + off];
            const float M_ = fmaxf(m1, m2);
            sS[tid] = sS[tid] * expf(m1 - M_) + sS[tid + off] * expf(m2 - M_);
            mS[tid] = M_;
        }
        __syncthreads();
    }
    const float M_ = mS[0];
    const float inv = 1.0f / sS[0];

    for (int c8 = tid; c8 < nfull; c8 += 256) {
        const bf16x8 v = *(const bf16x8*)(lr + (size_t)c8 * 8);
#pragma unroll
        for (int j = 0; j < 8; ++j)
            pr[(size_t)c8 * 8 + j] = expf((float)v[j] - M_) * inv;
    }
    if (tid == 0)
        for (int j = 0; j < rem; ++j)
            pr[nfull * 8 + j] = expf((float)lr[nfull * 8 + j] - M_) * inv;
}

// ---------------------------------------------------------------------------
// bf16 MFMA GEMM (m97 structure): C[M,N] = scale * A[M,K] @ B^T[N,K] + bias
//   128x128 tile / 4 waves, BK=32, global_load_lds staging, 16x16x32 MFMA.
//   MASK : causal (col>row -> +NINF); fully-masked tiles short-circuit.
//   CK   : trim K loop to row0+128 (P is exactly 0 beyond the causal edge).
//   ADD  : f32 C += v (residual).   GELU_: erf-gelu.   OUTBF: bf16 C.
//   Batched via blockIdx.z -> (bb=z/HH, hh=z%HH), element strides per operand.
// ---------------------------------------------------------------------------
template<bool MASK, bool CK, bool ADD, bool GELU_, bool OUTBF>
__global__ __launch_bounds__(256) void gemm_mfma(
    const bf16_t* __restrict__ A, const bf16_t* __restrict__ Bw,
    const float* __restrict__ bias, void* __restrict__ Cv,
    int M, int N, int K, int lda, int ldb, int ldc,
    long long aSB, long long aSH, long long bSB, long long bSH,
    long long cSB, long long cSH, int HH, float scale)
{
    __shared__ bf16_t lds[8192];            // A tile [128][32] @0, B tile @4096

    const int tid  = threadIdx.x;
    const int lane = tid & 63;
    const int w    = tid >> 6;
    const int wr   = w >> 1, wc = w & 1;
    const int row0 = blockIdx.x * 128;
    const int col0 = blockIdx.y * 128;
    const int z    = blockIdx.z;
    const int bb   = z / HH, hh = z - bb * HH;
    A  += bb * aSB + (long long)hh * aSH;
    Bw += bb * bSB + (long long)hh * bSH;
    const long long cOff = bb * cSB + (long long)hh * cSH;

    const int fr    = lane & 15;
    const int rBase = row0 + wr * 64 + (lane >> 4) * 4;
    const int cBase = col0 + wc * 64 + fr;

    if (MASK && col0 > row0 + 127) {
        // fully-masked tile: write NINF, skip compute
        float* Cf = (float*)Cv;
#pragma unroll
        for (int n = 0; n < 4; ++n) {
            const int c = cBase + n * 16;
            if (c >= N) continue;
#pragma unroll
            for (int m = 0; m < 4; ++m)
#pragma unroll
                for (int r = 0; r < 4; ++r)
                    Cf[cOff + (long long)(rBase + m * 16 + r) * ldc + c] = NINF_VAL;
        }
        return;
    }

    const int lrow = lane >> 2;             // 0..15
    const int lq   = lane & 3;              // 16B sub-chunk within 64B row
    const int aRow = row0 + w * 32 + lrow;
    int br0 = col0 + w * 32 + lrow;
    int br1 = br0 + 16;
    if (br0 >= N) br0 = 0;                  // clamp (values unused)
    if (br1 >= N) br1 = 0;

    const bf16_t* aSrc0 = A  + (size_t)aRow * lda + lq * 8;
    const bf16_t* aSrc1 = aSrc0 + (size_t)16 * lda;
    const bf16_t* bSrc0 = Bw + (size_t)br0 * ldb + lq * 8;
    const bf16_t* bSrc1 = Bw + (size_t)br1 * ldb + lq * 8;

    bf16_t* ldsA = lds + w * 1024;
    bf16_t* ldsB = lds + 4096 + w * 1024;

    f32x4 acc[4][4];
#pragma unroll
    for (int m = 0; m < 4; ++m)
#pragma unroll
        for (int n = 0; n < 4; ++n)
            acc[m][n] = (f32x4){0.f, 0.f, 0.f, 0.f};

    const int sub = (lane >> 4) * 8;
    const int Keff = CK ? min(K, row0 + 128) : K;

    for (int k0 = 0; k0 < Keff; k0 += 32) {
        gload16(aSrc0, ldsA);
        gload16(aSrc1, ldsA + 512);
        gload16(bSrc0, ldsB);
        gload16(bSrc1, ldsB + 512);
        aSrc0 += 32; aSrc1 += 32; bSrc0 += 32; bSrc1 += 32;
        __syncthreads();

        bf16x8 af[4], bfr[4];
#pragma unroll
        for (int m = 0; m < 4; ++m)
            af[m] = *(const bf16x8*)&lds[(wr * 64 + m * 16 + fr) * 32 + sub];
#pragma unroll
        for (int n = 0; n < 4; ++n)
            bfr[n] = *(const bf16x8*)&lds[4096 + (wc * 64 + n * 16 + fr) * 32 + sub];

#pragma unroll
        for (int m = 0; m < 4; ++m)
#pragma unroll
            for (int n = 0; n < 4; ++n)
                acc[m][n] = __builtin_amdgcn_mfma_f32_16x16x32_bf16(
                    af[m], bfr[n], acc[m][n], 0, 0, 0);
        __syncthreads();
    }

#pragma unroll
    for (int n = 0; n < 4; ++n) {
        const int c = cBase + n * 16;
        if (c >= N) continue;
        const float bv = bias ? bias[c] : 0.0f;
#pragma unroll
        for (int m = 0; m < 4; ++m) {
#pragma unroll
            for (int r = 0; r < 4; ++r) {
                const int rr = rBase + m * 16 + r;
                float v = acc[m][n][r] * scale + bv;
                if (MASK) { if (c > rr) v += NINF_VAL; }
                if (GELU_) v = 0.5f * v * (1.0f + erff(v * 0.70710678118654752f));
                const long long idx = cOff + (long long)rr * ldc + c;
                if (OUTBF) {
                    ((bf16_t*)Cv)[idx] = (bf16_t)v;
                } else {
                    float* Cf = (float*)Cv;
                    if (ADD) v += Cf[idx];
                    Cf[idx] = v;
                }
            }
        }
    }
}

// ---------------------------------------------------------------------------
// Launcher
// ---------------------------------------------------------------------------
extern "C" void kernel_launch(void* const* d_in, const int* in_sizes, int n_in,
                              void* d_out, int out_size, void* d_ws, size_t ws_size,
                              hipStream_t stream)
{
    constexpr int B = 4, S = 512, D = 768, L = 12, V = 50257, H = 12, F = 3072;
    constexpr int M  = B * S;     // 2048
    constexpr int TD = 3 * D;     // 2304
    constexpr int BH = B * H;     // 48
    constexpr int Vp = 50264;     // V padded to multiple of 8 (16B bf16 rows)
    const float SCALE = 0.125f;   // 1/sqrt(64)

    const int*   x    = (const int*)  d_in[0];
    const float* emb  = (const float*)d_in[1];
    const float* pos  = (const float*)d_in[2];
    const float* ln1g = (const float*)d_in[3];
    const float* ln1b = (const float*)d_in[4];
    const float* wqkv = (const float*)d_in[5];
    const float* bqkv = (const float*)d_in[6];
    const float* wo   = (const float*)d_in[7];
    const float* bo   = (const float*)d_in[8];
    const float* ln2g = (const float*)d_in[9];
    const float* ln2b = (const float*)d_in[10];
    const float* wfc  = (const float*)d_in[11];
    const float* bfc  = (const float*)d_in[12];
    const float* wpr  = (const float*)d_in[13];
    const float* bpr  = (const float*)d_in[14];
    const float* lnfg = (const float*)d_in[15];
    const float* lnfb = (const float*)d_in[16];

    float* probs  = (float*)d_out;                    // [M, V]
    float* hidden = probs + (size_t)M * V;            // [M, D]

    // ---- workspace layout -------------------------------------------------
    float* h  = (float*)d_ws;                         // [M,D] f32 (persistent)
    float* sc = h + (size_t)M * D;                    // [BH,S,S] f32  -- X region start
    bf16_t* P      = (bf16_t*)(sc + (size_t)BH * S * S);   // [BH,S,S]
    bf16_t* qkv_bf = P      + (size_t)BH * S * S;     // [M,TD]
    bf16_t* vT     = qkv_bf + (size_t)M * TD;         // [BH,64,S]
    bf16_t* xn_bf  = vT     + (size_t)BH * 64 * S;    // [M,D]
    bf16_t* o_bf   = xn_bf  + (size_t)M * D;          // [M,D]
    bf16_t* mid_bf = o_bf   + (size_t)M * D;          // [M,F]
    bf16_t* wqkvT  = mid_bf + (size_t)M * F;          // [L,TD,D]
    bf16_t* woT    = wqkvT  + (size_t)L * D * TD;     // [L,D,D]
    bf16_t* wfcT   = woT    + (size_t)L * D * D;      // [L,F,D]
    bf16_t* wprT   = wfcT   + (size_t)L * D * F;      // [L,D,F]  -- X region end
    bf16_t* hid_bf = wprT   + (size_t)L * F * D;      // [M,D]
    bf16_t* embB   = hid_bf + (size_t)M * D;          // [V,D]
    // logits [M,Vp] bf16 aliases the X region (dead after final LN)
    bf16_t* logits = (bf16_t*)sc;

    // ---- weight prep (per launch; deterministic) --------------------------
    convert_bf16<<<2048, 256, 0, stream>>>(emb, embB, (V * D) / 4);
    transpose_to_bf16<<<dim3(TD / 32, D / 32, L), dim3(32, 8), 0, stream>>>(wqkv, wqkvT, D, TD);
    transpose_to_bf16<<<dim3(D / 32,  D / 32, L), dim3(32, 8), 0, stream>>>(wo,   woT,   D, D);
    transpose_to_bf16<<<dim3(F / 32,  D / 32, L), dim3(32, 8), 0, stream>>>(wfc,  wfcT,  D, F);
    transpose_to_bf16<<<dim3(D / 32,  F / 32, L), dim3(32, 8), 0, stream>>>(wpr,  wprT,  F, D);

    // ---- embedding
    embed_kernel<<<dim3((M * D + 255) / 256), 256, 0, stream>>>(x, emb, pos, h, S, D, M * D);

    for (int i = 0; i < L; ++i) {
        // pre-attn LN -> bf16
        layernorm_dual<<<M, 256, 0, stream>>>(h, ln1g + (size_t)i * D, ln1b + (size_t)i * D,
                                              xn_bf, nullptr, D);

        // qkv = xn @ wqkv + bqkv  -> bf16 [M,TD]
        gemm_mfma<false, false, false, false, true><<<dim3(M / 128, TD / 128, 1), 256, 0, stream>>>(
            xn_bf, wqkvT + (size_t)i * D * TD, bqkv + (size_t)i * TD, qkv_bf,
            M, TD, D, D, D, TD, 0, 0, 0, 0, 0, 0, 1, 1.0f);

        // vT[z][d][k] = V^T per head
        transpose_v<<<dim3(S / 64, BH), 256, 0, stream>>>(qkv_bf, vT);

        // scores = scale * Q@K^T + causal mask (f32)
        gemm_mfma<true, false, false, false, false><<<dim3(S / 128, S / 128, BH), 256, 0, stream>>>(
            qkv_bf, qkv_bf + D, nullptr, sc,
            S, S, 64, TD, TD, S,
            (long long)S * TD, 64,
            (long long)S * TD, 64,
            (long long)H * S * S, (long long)S * S, H, SCALE);

        // softmax over keys -> bf16 P
        softmax_scores<<<BH * S, 256, 0, stream>>>(sc, P);

        // o = P @ V  (V^T in B^T form), causal-trimmed K loop -> bf16 [M,D]
        gemm_mfma<false, true, false, false, true><<<dim3(S / 128, 1, BH), 256, 0, stream>>>(
            P, vT, nullptr, o_bf,
            S, 64, S, S, S, D,
            (long long)H * S * S, (long long)S * S,
            (long long)H * 64 * S, (long long)64 * S,
            (long long)S * D, 64, H, 1.0f);

        // h += o @ wo + bo
        gemm_mfma<false, false, true, false, false><<<dim3(M / 128, D / 128, 1), 256, 0, stream>>>(
            o_bf, woT + (size_t)i * D * D, bo + (size_t)i * D, h,
            M, D, D, D, D, D, 0, 0, 0, 0, 0, 0, 1, 1.0f);

        // pre-MLP LN -> bf16
        layernorm_dual<<<M, 256, 0, stream>>>(h, ln2g + (size_t)i * D, ln2b + (size_t)i * D,
                                              xn_bf, nullptr, D);

        // mid = gelu(xn @ wfc + bfc) -> bf16
        gemm_mfma<false, false, false, true, true><<<dim3(M / 128, F / 128, 1), 256, 0, stream>>>(
            xn_bf, wfcT + (size_t)i * D * F, bfc + (size_t)i * F, mid_bf,
            M, F, D, D, D, F, 0, 0, 0, 0, 0, 0, 1, 1.0f);

        // h += mid @ wproj + bproj
        gemm_mfma<false, false, true, false, false><<<dim3(M / 128, D / 128, 1), 256, 0, stream>>>(
            mid_bf, wprT + (size_t)i * F * D, bpr + (size_t)i * D, h,
            M, D, F, F, F, D, 0, 0, 0, 0, 0, 0, 1, 1.0f);
    }

    // final LN -> hidden f32 (output 1) + bf16 copy
    layernorm_dual<<<M, 256, 0, stream>>>(h, lnfg, lnfb, hid_bf, hidden, D);

    // logits = hidden @ emb^T -> bf16 [M,Vp]
    gemm_mfma<false, false, false, false, true><<<dim3(M / 128, (V + 127) / 128, 1), 256, 0, stream>>>(
        hid_bf, embB, nullptr, logits,
        M, V, D, D, D, Vp, 0, 0, 0, 0, 0, 0, 1, 1.0f);

    // vocab softmax: bf16 logits -> f32 probs
    softmax_vocab<<<M, 256, 0, stream>>>(logits, probs, V, Vp);
}

// Round 4
// 3236.738 us; speedup vs baseline: 4.3295x; 1.1362x over previous
//
#include <hip/hip_runtime.h>
#include <hip/hip_bf16.h>

typedef __bf16 bf16_t;
typedef bf16_t bf16x8 __attribute__((ext_vector_type(8)));
typedef float  f32x4  __attribute__((ext_vector_type(4)));

// ---------------------------------------------------------------------------
// global -> LDS async copy, 16B per lane. lds base must be wave-uniform.
// ---------------------------------------------------------------------------
__device__ __forceinline__ void gload16(const void* g, void* l) {
    __builtin_amdgcn_global_load_lds(
        (const __attribute__((address_space(1))) unsigned int*)g,
        (__attribute__((address_space(3))) unsigned int*)l, 16, 0, 0);
}

// ---------------------------------------------------------------------------
// Embedding: h[b,s,:] = emb[x[b,s],:] + posemb[s,:]
// ---------------------------------------------------------------------------
__global__ void embed_kernel(const int* __restrict__ x,
                             const float* __restrict__ emb,
                             const float* __restrict__ pos,
                             float* __restrict__ h,
                             int S, int D, int total)
{
    int i = blockIdx.x * blockDim.x + threadIdx.x;
    if (i >= total) return;
    int d  = i % D;
    int bs = i / D;
    int s  = bs % S;
    h[i] = emb[(long long)x[bs] * D + d] + pos[(long long)s * D + d];
}

// ---------------------------------------------------------------------------
// elementwise f32 -> bf16 (vectorized by 4)
// ---------------------------------------------------------------------------
__global__ void convert_bf16(const float* __restrict__ in, bf16_t* __restrict__ out, int n4)
{
    int i = blockIdx.x * blockDim.x + threadIdx.x;
    for (; i < n4; i += gridDim.x * blockDim.x) {
        float4 v = ((const float4*)in)[i];
        bf16_t* o = out + (size_t)i * 4;
        o[0] = (bf16_t)v.x; o[1] = (bf16_t)v.y; o[2] = (bf16_t)v.z; o[3] = (bf16_t)v.w;
    }
}

// ---------------------------------------------------------------------------
// Batched transpose + bf16 convert: out[z][n][k] = (bf16) in[z][k][n]
// ---------------------------------------------------------------------------
__global__ __launch_bounds__(256) void transpose_to_bf16(
    const float* __restrict__ in, bf16_t* __restrict__ out, int K, int N)
{
    const float* ip = in  + (size_t)blockIdx.z * K * N;
    bf16_t*      op = out + (size_t)blockIdx.z * K * N;
    __shared__ float t[32][33];
    const int n0 = blockIdx.x * 32, k0 = blockIdx.y * 32;
    const int tx = threadIdx.x, ty = threadIdx.y;
#pragma unroll
    for (int u = 0; u < 4; ++u)
        t[ty + u * 8][tx] = ip[(size_t)(k0 + ty + u * 8) * N + (n0 + tx)];
    __syncthreads();
#pragma unroll
    for (int u = 0; u < 4; ++u)
        op[(size_t)(n0 + ty + u * 8) * K + (k0 + tx)] = (bf16_t)t[tx][ty + u * 8];
}

// ---------------------------------------------------------------------------
// Per-head V transpose: vT[z][d][k] = qkv[bb*S + k][2D + hh*64 + d], z=bb*H+hh
// ---------------------------------------------------------------------------
__global__ __launch_bounds__(256) void transpose_v(
    const bf16_t* __restrict__ qkv, bf16_t* __restrict__ vT)
{
    constexpr int S = 512, TD = 2304, D = 768, H = 12;
    const int z = blockIdx.y, bb = z / H, hh = z - bb * H;
    const int k0 = blockIdx.x * 64;
    const bf16_t* src = qkv + (size_t)(bb * S + k0) * TD + 2 * D + hh * 64;
    bf16_t* dst = vT + (size_t)z * 64 * S + k0;
    __shared__ bf16_t sm[64][68];
    const int c = threadIdx.x & 63, rq = threadIdx.x >> 6;
#pragma unroll
    for (int u = 0; u < 16; ++u) {
        const int r = u * 4 + rq;
        sm[r][c] = src[(size_t)r * TD + c];
    }
    __syncthreads();
#pragma unroll
    for (int u = 0; u < 16; ++u) {
        const int d = u * 4 + rq;
        dst[(size_t)d * S + c] = sm[c][d];
    }
}

// ---------------------------------------------------------------------------
// LayerNorm rows of D=768; writes bf16 (always) and f32 (if Yf != nullptr).
// ---------------------------------------------------------------------------
__global__ __launch_bounds__(256) void layernorm_dual(
    const float* __restrict__ X, const float* __restrict__ g,
    const float* __restrict__ b, bf16_t* __restrict__ Yb,
    float* __restrict__ Yf, int D)
{
    const int row = blockIdx.x;
    const float* xr = X + (long long)row * D;
    const int tid = threadIdx.x;

    float vals[3];
    float s = 0.0f;
#pragma unroll
    for (int u = 0; u < 3; ++u) { vals[u] = xr[tid + u * 256]; s += vals[u]; }

    __shared__ float red[256];
    red[tid] = s;
    __syncthreads();
    for (int off = 128; off > 0; off >>= 1) {
        if (tid < off) red[tid] += red[tid + off];
        __syncthreads();
    }
    const float mean = red[0] / (float)D;
    __syncthreads();

    float vs = 0.0f;
#pragma unroll
    for (int u = 0; u < 3; ++u) { float d = vals[u] - mean; vs += d * d; }
    red[tid] = vs;
    __syncthreads();
    for (int off = 128; off > 0; off >>= 1) {
        if (tid < off) red[tid] += red[tid + off];
        __syncthreads();
    }
    const float var  = red[0] / (float)D;
    const float rstd = rsqrtf(var + 1e-6f);

#pragma unroll
    for (int u = 0; u < 3; ++u) {
        const int c = tid + u * 256;
        const float y = (vals[u] - mean) * rstd * g[c] + b[c];
        Yb[(long long)row * D + c] = (bf16_t)y;
        if (Yf) Yf[(long long)row * D + c] = y;
    }
}

// ---------------------------------------------------------------------------
// Fused flash attention (causal, hd=64, S=512).
// Grid: (S/128 q-tiles, B*H). Block: 256 threads = 4 waves, 32 q-rows each.
// Q,K from qkv_bf [M][2304]; V^T from vT [BH][64][S]; out -> o [M][768].
// K/V tiles staged via global_load_lds with both-sides XOR chunk swizzle.
// ---------------------------------------------------------------------------
__global__ __launch_bounds__(256) void flash_attn(
    const bf16_t* __restrict__ qkv, const bf16_t* __restrict__ vT,
    bf16_t* __restrict__ o)
{
    constexpr int S = 512, TD = 2304, D = 768, H = 12;
    const int qt = blockIdx.x;
    const int z  = blockIdx.y;
    const int bb = z / H, hh = z - bb * H;
    const int tid = threadIdx.x, lane = tid & 63, w = tid >> 6;
    const int fr = lane & 15, g = lane >> 4, sub = g * 8;

    __shared__ bf16_t kS[4096];          // K tile [64 key][64 k], chunk-swizzled
    __shared__ bf16_t vS[4096];          // V^T tile [64 d][64 key], chunk-swizzled
    __shared__ bf16_t pS[4][32 * 72];    // per-wave P [32 q][64 key], padded

    // ---- Q fragments in registers, scaled by 1/sqrt(64)
    bf16x8 qf[2][2];
    const bf16_t* qbase = qkv + (size_t)(bb * S + qt * 128 + w * 32) * TD + hh * 64;
#pragma unroll
    for (int m = 0; m < 2; ++m)
#pragma unroll
        for (int ks = 0; ks < 2; ++ks) {
            bf16x8 v = *(const bf16x8*)&qbase[(size_t)(m * 16 + fr) * TD + ks * 32 + sub];
#pragma unroll
            for (int j = 0; j < 8; ++j) v[j] = v[j] * (bf16_t)0.125f;
            qf[m][ks] = v;
        }

    f32x4 oacc[2][4];
    float mrun[2][4], lrun[2][4];
#pragma unroll
    for (int m = 0; m < 2; ++m)
#pragma unroll
        for (int r = 0; r < 4; ++r) { mrun[m][r] = -3.0e38f; lrun[m][r] = 0.0f; }
#pragma unroll
    for (int m = 0; m < 2; ++m)
#pragma unroll
        for (int n = 0; n < 4; ++n)
            oacc[m][n] = (f32x4){0.f, 0.f, 0.f, 0.f};

    int qr[2][4];
#pragma unroll
    for (int m = 0; m < 2; ++m)
#pragma unroll
        for (int r = 0; r < 4; ++r)
            qr[m][r] = qt * 128 + w * 32 + m * 16 + g * 4 + r;

    // staging: e = it*256 + tid; row = e>>3 (64 rows), chunk slot = e&7 (16B).
    // source chunk pre-swizzled so LDS reads at chunk^(row&7) are conflict-free.
    const int srow8  = lane >> 3;                      // row = it*32 + w*8 + srow8
    const int schunk = (lane & 7) ^ (srow8 & 7);       // (row&7) == (srow8&7)

    const bf16_t* kGbase = qkv + (size_t)(bb * S) * TD + D + hh * 64;
    const bf16_t* vGbase = vT + (size_t)z * 64 * S;
    const int nkv = 2 * qt + 2;

    for (int t = 0; t < nkv; ++t) {
#pragma unroll
        for (int it = 0; it < 2; ++it) {
            const int row = it * 32 + w * 8 + srow8;
            gload16(kGbase + (size_t)(t * 64 + row) * TD + schunk * 8,
                    kS + it * 2048 + w * 512);
            gload16(vGbase + (size_t)row * S + t * 64 + schunk * 8,
                    vS + it * 2048 + w * 512);
        }
        __syncthreads();

        // ---- S = (Q/8) K^T
        f32x4 sacc[2][4];
#pragma unroll
        for (int m = 0; m < 2; ++m)
#pragma unroll
            for (int n = 0; n < 4; ++n)
                sacc[m][n] = (f32x4){0.f, 0.f, 0.f, 0.f};
#pragma unroll
        for (int ks = 0; ks < 2; ++ks) {
            bf16x8 bK[4];
#pragma unroll
            for (int n = 0; n < 4; ++n) {
                const int rw = n * 16 + fr;
                const int c  = ks * 4 + g;
                bK[n] = *(const bf16x8*)&kS[rw * 64 + ((c ^ (rw & 7)) << 3)];
            }
#pragma unroll
            for (int m = 0; m < 2; ++m)
#pragma unroll
                for (int n = 0; n < 4; ++n)
                    sacc[m][n] = __builtin_amdgcn_mfma_f32_16x16x32_bf16(
                        qf[m][ks], bK[n], sacc[m][n], 0, 0, 0);
        }

        // ---- causal mask on diagonal tiles
        if (t >= 2 * qt) {
#pragma unroll
            for (int m = 0; m < 2; ++m)
#pragma unroll
                for (int n = 0; n < 4; ++n) {
                    const int key = t * 64 + n * 16 + fr;
#pragma unroll
                    for (int r = 0; r < 4; ++r)
                        if (key > qr[m][r]) sacc[m][n][r] = -3.0e38f;
                }
        }

        // ---- online softmax
        float sf[2][4], rs[2][4];
#pragma unroll
        for (int m = 0; m < 2; ++m)
#pragma unroll
            for (int r = 0; r < 4; ++r) {
                float v = fmaxf(fmaxf(sacc[m][0][r], sacc[m][1][r]),
                                fmaxf(sacc[m][2][r], sacc[m][3][r]));
#pragma unroll
                for (int off = 1; off < 16; off <<= 1)
                    v = fmaxf(v, __shfl_xor(v, off));
                const float mn = fmaxf(mrun[m][r], v);
                sf[m][r] = __expf(mrun[m][r] - mn);
                mrun[m][r] = mn;
                lrun[m][r] *= sf[m][r];
            }
#pragma unroll
        for (int m = 0; m < 2; ++m)
#pragma unroll
            for (int n = 0; n < 4; ++n)
#pragma unroll
                for (int r = 0; r < 4; ++r)
                    oacc[m][n][r] *= sf[m][r];
#pragma unroll
        for (int m = 0; m < 2; ++m)
#pragma unroll
            for (int r = 0; r < 4; ++r) rs[m][r] = 0.0f;
#pragma unroll
        for (int m = 0; m < 2; ++m)
#pragma unroll
            for (int n = 0; n < 4; ++n)
#pragma unroll
                for (int r = 0; r < 4; ++r) {
                    const float p = __expf(sacc[m][n][r] - mrun[m][r]);
                    sacc[m][n][r] = p;
                    rs[m][r] += p;
                }
#pragma unroll
        for (int m = 0; m < 2; ++m)
#pragma unroll
            for (int r = 0; r < 4; ++r) {
                float v = rs[m][r];
#pragma unroll
                for (int off = 1; off < 16; off <<= 1) v += __shfl_xor(v, off);
                lrun[m][r] += v;
            }

        // ---- P -> per-wave LDS (C layout -> A layout round trip)
        bf16_t* pw = pS[w];
#pragma unroll
        for (int m = 0; m < 2; ++m)
#pragma unroll
            for (int n = 0; n < 4; ++n)
#pragma unroll
                for (int r = 0; r < 4; ++r)
                    pw[(m * 16 + g * 4 + r) * 72 + n * 16 + fr] = (bf16_t)sacc[m][n][r];

        // ---- O += P V
#pragma unroll
        for (int ks = 0; ks < 2; ++ks) {
            bf16x8 pa[2], vb[4];
#pragma unroll
            for (int m = 0; m < 2; ++m)
                pa[m] = *(const bf16x8*)&pw[(m * 16 + fr) * 72 + ks * 32 + sub];
#pragma unroll
            for (int n = 0; n < 4; ++n) {
                const int rw = n * 16 + fr;
                const int c  = ks * 4 + g;
                vb[n] = *(const bf16x8*)&vS[rw * 64 + ((c ^ (rw & 7)) << 3)];
            }
#pragma unroll
            for (int m = 0; m < 2; ++m)
#pragma unroll
                for (int n = 0; n < 4; ++n)
                    oacc[m][n] = __builtin_amdgcn_mfma_f32_16x16x32_bf16(
                        pa[m], vb[n], oacc[m][n], 0, 0, 0);
        }
        __syncthreads();
    }

    // ---- epilogue: normalize, write bf16
    bf16_t* obase = o + (size_t)(bb * S + qt * 128 + w * 32) * D + hh * 64;
#pragma unroll
    for (int m = 0; m < 2; ++m)
#pragma unroll
        for (int r = 0; r < 4; ++r) {
            const float inv = 1.0f / lrun[m][r];
#pragma unroll
            for (int n = 0; n < 4; ++n)
                obase[(size_t)(m * 16 + g * 4 + r) * D + n * 16 + fr] =
                    (bf16_t)(oacc[m][n][r] * inv);
        }
}

// ---------------------------------------------------------------------------
// Vocab softmax: bf16 logits (stride Vp) -> f32 probs (stride V).
// 3 element-strided scans (max, sum, write); rows L2-hot on re-read.
// ---------------------------------------------------------------------------
__global__ __launch_bounds__(256) void softmax_vocab(
    const bf16_t* __restrict__ logits, float* __restrict__ probs, int V, int Vp)
{
    const int tid = threadIdx.x;
    const bf16_t* lr = logits + (size_t)blockIdx.x * Vp;
    float* pr = probs + (size_t)blockIdx.x * V;
    __shared__ float red[256];

    float m = -3.0e38f;
    for (int c = tid; c < V; c += 256) m = fmaxf(m, (float)lr[c]);
    red[tid] = m;
    __syncthreads();
    for (int off = 128; off > 0; off >>= 1) {
        if (tid < off) red[tid] = fmaxf(red[tid], red[tid + off]);
        __syncthreads();
    }
    m = red[0];
    __syncthreads();

    float s = 0.0f;
    for (int c = tid; c < V; c += 256) s += __expf((float)lr[c] - m);
    red[tid] = s;
    __syncthreads();
    for (int off = 128; off > 0; off >>= 1) {
        if (tid < off) red[tid] += red[tid + off];
        __syncthreads();
    }
    const float inv = 1.0f / red[0];

    for (int c = tid; c < V; c += 256) pr[c] = __expf((float)lr[c] - m) * inv;
}

// ---------------------------------------------------------------------------
// bf16 MFMA GEMM (m97 structure): C[M,N] = A[M,K] @ B^T[N,K] + bias
//   128x128 tile / 4 waves, BK=32, global_load_lds staging, 16x16x32 MFMA.
//   ADD: f32 C += v.  GELU_: erf-gelu.  OUTBF: bf16 C.  SWZ: XCD block swizzle.
// ---------------------------------------------------------------------------
template<bool ADD, bool GELU_, bool OUTBF, bool SWZ>
__global__ __launch_bounds__(256) void gemm_mfma(
    const bf16_t* __restrict__ A, const bf16_t* __restrict__ Bw,
    const float* __restrict__ bias, void* __restrict__ Cv,
    int M, int N, int K, int lda, int ldb, int ldc)
{
    __shared__ bf16_t lds[8192];

    int bx = blockIdx.x, by = blockIdx.y;
    if (SWZ) {
        const int nwg = gridDim.x * gridDim.y;
        int flat = by * gridDim.x + bx;
        const int q = nwg >> 3, r = nwg & 7;
        const int xcd = flat & 7, pos = flat >> 3;
        flat = (xcd < r ? xcd * (q + 1) : r * (q + 1) + (xcd - r) * q) + pos;
        bx = flat % gridDim.x; by = flat / gridDim.x;
    }

    const int tid  = threadIdx.x;
    const int lane = tid & 63;
    const int w    = tid >> 6;
    const int wr   = w >> 1, wc = w & 1;
    const int row0 = bx * 128;
    const int col0 = by * 128;

    const int lrow = lane >> 2;
    const int lq   = lane & 3;
    const int aRow = row0 + w * 32 + lrow;
    int br0 = col0 + w * 32 + lrow;
    int br1 = br0 + 16;
    if (br0 >= N) br0 = 0;
    if (br1 >= N) br1 = 0;

    const bf16_t* aSrc0 = A  + (size_t)aRow * lda + lq * 8;
    const bf16_t* aSrc1 = aSrc0 + (size_t)16 * lda;
    const bf16_t* bSrc0 = Bw + (size_t)br0 * ldb + lq * 8;
    const bf16_t* bSrc1 = Bw + (size_t)br1 * ldb + lq * 8;

    bf16_t* ldsA = lds + w * 1024;
    bf16_t* ldsB = lds + 4096 + w * 1024;

    f32x4 acc[4][4];
#pragma unroll
    for (int m = 0; m < 4; ++m)
#pragma unroll
        for (int n = 0; n < 4; ++n)
            acc[m][n] = (f32x4){0.f, 0.f, 0.f, 0.f};

    const int fr  = lane & 15;
    const int sub = (lane >> 4) * 8;

    for (int k0 = 0; k0 < K; k0 += 32) {
        gload16(aSrc0, ldsA);
        gload16(aSrc1, ldsA + 512);
        gload16(bSrc0, ldsB);
        gload16(bSrc1, ldsB + 512);
        aSrc0 += 32; aSrc1 += 32; bSrc0 += 32; bSrc1 += 32;
        __syncthreads();

        bf16x8 af[4], bfr[4];
#pragma unroll
        for (int m = 0; m < 4; ++m)
            af[m] = *(const bf16x8*)&lds[(wr * 64 + m * 16 + fr) * 32 + sub];
#pragma unroll
        for (int n = 0; n < 4; ++n)
            bfr[n] = *(const bf16x8*)&lds[4096 + (wc * 64 + n * 16 + fr) * 32 + sub];

#pragma unroll
        for (int m = 0; m < 4; ++m)
#pragma unroll
            for (int n = 0; n < 4; ++n)
                acc[m][n] = __builtin_amdgcn_mfma_f32_16x16x32_bf16(
                    af[m], bfr[n], acc[m][n], 0, 0, 0);
        __syncthreads();
    }

    const int rBase = row0 + wr * 64 + (lane >> 4) * 4;
    const int cBase = col0 + wc * 64 + fr;
#pragma unroll
    for (int n = 0; n < 4; ++n) {
        const int c = cBase + n * 16;
        if (c >= N) continue;
        const float bv = bias ? bias[c] : 0.0f;
#pragma unroll
        for (int m = 0; m < 4; ++m) {
#pragma unroll
            for (int r = 0; r < 4; ++r) {
                const int rr = rBase + m * 16 + r;
                float v = acc[m][n][r] + bv;
                if (GELU_) v = 0.5f * v * (1.0f + erff(v * 0.70710678118654752f));
                const size_t idx = (size_t)rr * ldc + c;
                if (OUTBF) {
                    ((bf16_t*)Cv)[idx] = (bf16_t)v;
                } else {
                    float* Cf = (float*)Cv;
                    if (ADD) v += Cf[idx];
                    Cf[idx] = v;
                }
            }
        }
    }
}

// ---------------------------------------------------------------------------
// Launcher
// ---------------------------------------------------------------------------
extern "C" void kernel_launch(void* const* d_in, const int* in_sizes, int n_in,
                              void* d_out, int out_size, void* d_ws, size_t ws_size,
                              hipStream_t stream)
{
    constexpr int B = 4, S = 512, D = 768, L = 12, V = 50257, H = 12, F = 3072;
    constexpr int M  = B * S;     // 2048
    constexpr int TD = 3 * D;     // 2304
    constexpr int BH = B * H;     // 48
    constexpr int Vp = 50264;     // V padded to multiple of 8

    const int*   x    = (const int*)  d_in[0];
    const float* emb  = (const float*)d_in[1];
    const float* pos  = (const float*)d_in[2];
    const float* ln1g = (const float*)d_in[3];
    const float* ln1b = (const float*)d_in[4];
    const float* wqkv = (const float*)d_in[5];
    const float* bqkv = (const float*)d_in[6];
    const float* wo   = (const float*)d_in[7];
    const float* bo   = (const float*)d_in[8];
    const float* ln2g = (const float*)d_in[9];
    const float* ln2b = (const float*)d_in[10];
    const float* wfc  = (const float*)d_in[11];
    const float* bfc  = (const float*)d_in[12];
    const float* wpr  = (const float*)d_in[13];
    const float* bpr  = (const float*)d_in[14];
    const float* lnfg = (const float*)d_in[15];
    const float* lnfb = (const float*)d_in[16];

    float* probs  = (float*)d_out;                    // [M, V]
    float* hidden = probs + (size_t)M * V;            // [M, D]

    // ---- workspace layout -------------------------------------------------
    // [h][qkv][vT][xn][o][mid][wqkvT][woT][wfcT][wprT] all dead before the
    // logits GEMM -> logits [M,Vp] bf16 aliases from the start of ws.
    float*  h      = (float*)d_ws;                    // [M,D] f32
    bf16_t* qkv_bf = (bf16_t*)(h + (size_t)M * D);    // [M,TD]
    bf16_t* vT     = qkv_bf + (size_t)M * TD;         // [BH,64,S]
    bf16_t* xn_bf  = vT     + (size_t)BH * 64 * S;    // [M,D]
    bf16_t* o_bf   = xn_bf  + (size_t)M * D;          // [M,D]
    bf16_t* mid_bf = o_bf   + (size_t)M * D;          // [M,F]
    bf16_t* wqkvT  = mid_bf + (size_t)M * F;          // [L,TD,D]
    bf16_t* woT    = wqkvT  + (size_t)L * D * TD;     // [L,D,D]
    bf16_t* wfcT   = woT    + (size_t)L * D * D;      // [L,F,D]
    bf16_t* wprT   = wfcT   + (size_t)L * D * F;      // [L,D,F]
    bf16_t* hid_bf = wprT   + (size_t)L * F * D;      // [M,D]   (live at end)
    bf16_t* embB   = hid_bf + (size_t)M * D;          // [V,D]   (live at end)
    bf16_t* logits = (bf16_t*)d_ws;                   // [M,Vp] alias

    // ---- weight prep ------------------------------------------------------
    convert_bf16<<<2048, 256, 0, stream>>>(emb, embB, (V * D) / 4);
    transpose_to_bf16<<<dim3(TD / 32, D / 32, L), dim3(32, 8), 0, stream>>>(wqkv, wqkvT, D, TD);
    transpose_to_bf16<<<dim3(D / 32,  D / 32, L), dim3(32, 8), 0, stream>>>(wo,   woT,   D, D);
    transpose_to_bf16<<<dim3(F / 32,  D / 32, L), dim3(32, 8), 0, stream>>>(wfc,  wfcT,  D, F);
    transpose_to_bf16<<<dim3(D / 32,  F / 32, L), dim3(32, 8), 0, stream>>>(wpr,  wprT,  F, D);

    // ---- embedding
    embed_kernel<<<dim3((M * D + 255) / 256), 256, 0, stream>>>(x, emb, pos, h, S, D, M * D);

    for (int i = 0; i < L; ++i) {
        layernorm_dual<<<M, 256, 0, stream>>>(h, ln1g + (size_t)i * D, ln1b + (size_t)i * D,
                                              xn_bf, nullptr, D);

        gemm_mfma<false, false, true, false><<<dim3(M / 128, TD / 128), 256, 0, stream>>>(
            xn_bf, wqkvT + (size_t)i * D * TD, bqkv + (size_t)i * TD, qkv_bf,
            M, TD, D, D, D, TD);

        transpose_v<<<dim3(S / 64, BH), 256, 0, stream>>>(qkv_bf, vT);

        flash_attn<<<dim3(S / 128, BH), 256, 0, stream>>>(qkv_bf, vT, o_bf);

        gemm_mfma<true, false, false, false><<<dim3(M / 128, D / 128), 256, 0, stream>>>(
            o_bf, woT + (size_t)i * D * D, bo + (size_t)i * D, h,
            M, D, D, D, D, D);

        layernorm_dual<<<M, 256, 0, stream>>>(h, ln2g + (size_t)i * D, ln2b + (size_t)i * D,
                                              xn_bf, nullptr, D);

        gemm_mfma<false, true, true, false><<<dim3(M / 128, F / 128), 256, 0, stream>>>(
            xn_bf, wfcT + (size_t)i * D * F, bfc + (size_t)i * F, mid_bf,
            M, F, D, D, D, F);

        gemm_mfma<true, false, false, false><<<dim3(M / 128, D / 128), 256, 0, stream>>>(
            mid_bf, wprT + (size_t)i * F * D, bpr + (size_t)i * D, h,
            M, D, F, F, F, D);
    }

    layernorm_dual<<<M, 256, 0, stream>>>(h, lnfg, lnfb, hid_bf, hidden, D);

    gemm_mfma<false, false, true, true><<<dim3(M / 128, (V + 127) / 128), 256, 0, stream>>>(
        hid_bf, embB, nullptr, logits,
        M, V, D, D, D, Vp);

    softmax_vocab<<<M, 256, 0, stream>>>(logits, probs, V, Vp);
}

// Round 5
// 2874.235 us; speedup vs baseline: 4.8755x; 1.1261x over previous
//
#include <hip/hip_runtime.h>
#include <hip/hip_bf16.h>

typedef __bf16 bf16_t;
typedef bf16_t bf16x8 __attribute__((ext_vector_type(8)));
typedef float  f32x4  __attribute__((ext_vector_type(4)));

// ---------------------------------------------------------------------------
// global -> LDS async copy, 16B per lane. lds base must be wave-uniform.
// ---------------------------------------------------------------------------
__device__ __forceinline__ void gload16(const void* g, void* l) {
    __builtin_amdgcn_global_load_lds(
        (const __attribute__((address_space(1))) unsigned int*)g,
        (__attribute__((address_space(3))) unsigned int*)l, 16, 0, 0);
}

// ---------------------------------------------------------------------------
// Embedding: h[b,s,:] = emb[x[b,s],:] + posemb[s,:]
// ---------------------------------------------------------------------------
__global__ void embed_kernel(const int* __restrict__ x,
                             const float* __restrict__ emb,
                             const float* __restrict__ pos,
                             float* __restrict__ h,
                             int S, int D, int total)
{
    int i = blockIdx.x * blockDim.x + threadIdx.x;
    if (i >= total) return;
    int d  = i % D;
    int bs = i / D;
    int s  = bs % S;
    h[i] = emb[(long long)x[bs] * D + d] + pos[(long long)s * D + d];
}

// ---------------------------------------------------------------------------
// elementwise f32 -> bf16 (vectorized by 4)
// ---------------------------------------------------------------------------
__global__ void convert_bf16(const float* __restrict__ in, bf16_t* __restrict__ out, int n4)
{
    int i = blockIdx.x * blockDim.x + threadIdx.x;
    for (; i < n4; i += gridDim.x * blockDim.x) {
        float4 v = ((const float4*)in)[i];
        bf16_t* o = out + (size_t)i * 4;
        o[0] = (bf16_t)v.x; o[1] = (bf16_t)v.y; o[2] = (bf16_t)v.z; o[3] = (bf16_t)v.w;
    }
}

// ---------------------------------------------------------------------------
// Batched transpose + bf16 convert: out[z][n][k] = (bf16) in[z][k][n]
// ---------------------------------------------------------------------------
__global__ __launch_bounds__(256) void transpose_to_bf16(
    const float* __restrict__ in, bf16_t* __restrict__ out, int K, int N)
{
    const float* ip = in  + (size_t)blockIdx.z * K * N;
    bf16_t*      op = out + (size_t)blockIdx.z * K * N;
    __shared__ float t[32][33];
    const int n0 = blockIdx.x * 32, k0 = blockIdx.y * 32;
    const int tx = threadIdx.x, ty = threadIdx.y;
#pragma unroll
    for (int u = 0; u < 4; ++u)
        t[ty + u * 8][tx] = ip[(size_t)(k0 + ty + u * 8) * N + (n0 + tx)];
    __syncthreads();
#pragma unroll
    for (int u = 0; u < 4; ++u)
        op[(size_t)(n0 + ty + u * 8) * K + (k0 + tx)] = (bf16_t)t[tx][ty + u * 8];
}

// ---------------------------------------------------------------------------
// LayerNorm rows of D=768; writes bf16 (always) and f32 (if Yf != nullptr).
// ---------------------------------------------------------------------------
__global__ __launch_bounds__(256) void layernorm_dual(
    const float* __restrict__ X, const float* __restrict__ g,
    const float* __restrict__ b, bf16_t* __restrict__ Yb,
    float* __restrict__ Yf, int D)
{
    const int row = blockIdx.x;
    const float* xr = X + (long long)row * D;
    const int tid = threadIdx.x;

    float vals[3];
    float s = 0.0f;
#pragma unroll
    for (int u = 0; u < 3; ++u) { vals[u] = xr[tid + u * 256]; s += vals[u]; }

    __shared__ float red[256];
    red[tid] = s;
    __syncthreads();
    for (int off = 128; off > 0; off >>= 1) {
        if (tid < off) red[tid] += red[tid + off];
        __syncthreads();
    }
    const float mean = red[0] / (float)D;
    __syncthreads();

    float vs = 0.0f;
#pragma unroll
    for (int u = 0; u < 3; ++u) { float d = vals[u] - mean; vs += d * d; }
    red[tid] = vs;
    __syncthreads();
    for (int off = 128; off > 0; off >>= 1) {
        if (tid < off) red[tid] += red[tid + off];
        __syncthreads();
    }
    const float var  = red[0] / (float)D;
    const float rstd = rsqrtf(var + 1e-6f);

#pragma unroll
    for (int u = 0; u < 3; ++u) {
        const int c = tid + u * 256;
        const float y = (vals[u] - mean) * rstd * g[c] + b[c];
        Yb[(long long)row * D + c] = (bf16_t)y;
        if (Yf) Yf[(long long)row * D + c] = y;
    }
}

// ---------------------------------------------------------------------------
// Fused flash attention (causal, hd=64, S=512).
// Grid: (S/128 q-tiles, B*H). Block: 256 threads = 4 waves, 32 q-rows each.
// ---------------------------------------------------------------------------
__global__ __launch_bounds__(256) void flash_attn(
    const bf16_t* __restrict__ qkv, const bf16_t* __restrict__ vT,
    bf16_t* __restrict__ o)
{
    constexpr int S = 512, TD = 2304, D = 768, H = 12;
    const int qt = blockIdx.x;
    const int z  = blockIdx.y;
    const int bb = z / H, hh = z - bb * H;
    const int tid = threadIdx.x, lane = tid & 63, w = tid >> 6;
    const int fr = lane & 15, g = lane >> 4, sub = g * 8;

    __shared__ bf16_t kS[4096];          // K tile [64 key][64 k], chunk-swizzled
    __shared__ bf16_t vS[4096];          // V^T tile [64 d][64 key], chunk-swizzled
    __shared__ bf16_t pS[4][32 * 72];    // per-wave P [32 q][64 key], padded

    bf16x8 qf[2][2];
    const bf16_t* qbase = qkv + (size_t)(bb * S + qt * 128 + w * 32) * TD + hh * 64;
#pragma unroll
    for (int m = 0; m < 2; ++m)
#pragma unroll
        for (int ks = 0; ks < 2; ++ks) {
            bf16x8 v = *(const bf16x8*)&qbase[(size_t)(m * 16 + fr) * TD + ks * 32 + sub];
#pragma unroll
            for (int j = 0; j < 8; ++j) v[j] = v[j] * (bf16_t)0.125f;
            qf[m][ks] = v;
        }

    f32x4 oacc[2][4];
    float mrun[2][4], lrun[2][4];
#pragma unroll
    for (int m = 0; m < 2; ++m)
#pragma unroll
        for (int r = 0; r < 4; ++r) { mrun[m][r] = -3.0e38f; lrun[m][r] = 0.0f; }
#pragma unroll
    for (int m = 0; m < 2; ++m)
#pragma unroll
        for (int n = 0; n < 4; ++n)
            oacc[m][n] = (f32x4){0.f, 0.f, 0.f, 0.f};

    int qr[2][4];
#pragma unroll
    for (int m = 0; m < 2; ++m)
#pragma unroll
        for (int r = 0; r < 4; ++r)
            qr[m][r] = qt * 128 + w * 32 + m * 16 + g * 4 + r;

    const int srow8  = lane >> 3;
    const int schunk = (lane & 7) ^ (srow8 & 7);

    const bf16_t* kGbase = qkv + (size_t)(bb * S) * TD + D + hh * 64;
    const bf16_t* vGbase = vT + (size_t)z * 64 * S;
    const int nkv = 2 * qt + 2;

    for (int t = 0; t < nkv; ++t) {
#pragma unroll
        for (int it = 0; it < 2; ++it) {
            const int row = it * 32 + w * 8 + srow8;
            gload16(kGbase + (size_t)(t * 64 + row) * TD + schunk * 8,
                    kS + it * 2048 + w * 512);
            gload16(vGbase + (size_t)row * S + t * 64 + schunk * 8,
                    vS + it * 2048 + w * 512);
        }
        __syncthreads();

        f32x4 sacc[2][4];
#pragma unroll
        for (int m = 0; m < 2; ++m)
#pragma unroll
            for (int n = 0; n < 4; ++n)
                sacc[m][n] = (f32x4){0.f, 0.f, 0.f, 0.f};
#pragma unroll
        for (int ks = 0; ks < 2; ++ks) {
            bf16x8 bK[4];
#pragma unroll
            for (int n = 0; n < 4; ++n) {
                const int rw = n * 16 + fr;
                const int c  = ks * 4 + g;
                bK[n] = *(const bf16x8*)&kS[rw * 64 + ((c ^ (rw & 7)) << 3)];
            }
#pragma unroll
            for (int m = 0; m < 2; ++m)
#pragma unroll
                for (int n = 0; n < 4; ++n)
                    sacc[m][n] = __builtin_amdgcn_mfma_f32_16x16x32_bf16(
                        qf[m][ks], bK[n], sacc[m][n], 0, 0, 0);
        }

        if (t >= 2 * qt) {
#pragma unroll
            for (int m = 0; m < 2; ++m)
#pragma unroll
                for (int n = 0; n < 4; ++n) {
                    const int key = t * 64 + n * 16 + fr;
#pragma unroll
                    for (int r = 0; r < 4; ++r)
                        if (key > qr[m][r]) sacc[m][n][r] = -3.0e38f;
                }
        }

        float sf[2][4], rs[2][4];
#pragma unroll
        for (int m = 0; m < 2; ++m)
#pragma unroll
            for (int r = 0; r < 4; ++r) {
                float v = fmaxf(fmaxf(sacc[m][0][r], sacc[m][1][r]),
                                fmaxf(sacc[m][2][r], sacc[m][3][r]));
#pragma unroll
                for (int off = 1; off < 16; off <<= 1)
                    v = fmaxf(v, __shfl_xor(v, off));
                const float mn = fmaxf(mrun[m][r], v);
                sf[m][r] = __expf(mrun[m][r] - mn);
                mrun[m][r] = mn;
                lrun[m][r] *= sf[m][r];
            }
#pragma unroll
        for (int m = 0; m < 2; ++m)
#pragma unroll
            for (int n = 0; n < 4; ++n)
#pragma unroll
                for (int r = 0; r < 4; ++r)
                    oacc[m][n][r] *= sf[m][r];
#pragma unroll
        for (int m = 0; m < 2; ++m)
#pragma unroll
            for (int r = 0; r < 4; ++r) rs[m][r] = 0.0f;
#pragma unroll
        for (int m = 0; m < 2; ++m)
#pragma unroll
            for (int n = 0; n < 4; ++n)
#pragma unroll
                for (int r = 0; r < 4; ++r) {
                    const float p = __expf(sacc[m][n][r] - mrun[m][r]);
                    sacc[m][n][r] = p;
                    rs[m][r] += p;
                }
#pragma unroll
        for (int m = 0; m < 2; ++m)
#pragma unroll
            for (int r = 0; r < 4; ++r) {
                float v = rs[m][r];
#pragma unroll
                for (int off = 1; off < 16; off <<= 1) v += __shfl_xor(v, off);
                lrun[m][r] += v;
            }

        bf16_t* pw = pS[w];
#pragma unroll
        for (int m = 0; m < 2; ++m)
#pragma unroll
            for (int n = 0; n < 4; ++n)
#pragma unroll
                for (int r = 0; r < 4; ++r)
                    pw[(m * 16 + g * 4 + r) * 72 + n * 16 + fr] = (bf16_t)sacc[m][n][r];

#pragma unroll
        for (int ks = 0; ks < 2; ++ks) {
            bf16x8 pa[2], vb[4];
#pragma unroll
            for (int m = 0; m < 2; ++m)
                pa[m] = *(const bf16x8*)&pw[(m * 16 + fr) * 72 + ks * 32 + sub];
#pragma unroll
            for (int n = 0; n < 4; ++n) {
                const int rw = n * 16 + fr;
                const int c  = ks * 4 + g;
                vb[n] = *(const bf16x8*)&vS[rw * 64 + ((c ^ (rw & 7)) << 3)];
            }
#pragma unroll
            for (int m = 0; m < 2; ++m)
#pragma unroll
                for (int n = 0; n < 4; ++n)
                    oacc[m][n] = __builtin_amdgcn_mfma_f32_16x16x32_bf16(
                        pa[m], vb[n], oacc[m][n], 0, 0, 0);
        }
        __syncthreads();
    }

    bf16_t* obase = o + (size_t)(bb * S + qt * 128 + w * 32) * D + hh * 64;
#pragma unroll
    for (int m = 0; m < 2; ++m)
#pragma unroll
        for (int r = 0; r < 4; ++r) {
            const float inv = 1.0f / lrun[m][r];
#pragma unroll
            for (int n = 0; n < 4; ++n)
                obase[(size_t)(m * 16 + g * 4 + r) * D + n * 16 + fr] =
                    (bf16_t)(oacc[m][n][r] * inv);
        }
}

// ---------------------------------------------------------------------------
// Vocab softmax: bf16 logits (stride Vp) -> f32 probs (stride V).
// Pass 1: single vectorized online (max,sum) read. Pass 2: write probs.
// ---------------------------------------------------------------------------
__global__ __launch_bounds__(256) void softmax_vocab(
    const bf16_t* __restrict__ logits, float* __restrict__ probs, int V, int Vp)
{
    const int tid = threadIdx.x;
    const bf16_t* lr = logits + (size_t)blockIdx.x * Vp;
    float* pr = probs + (size_t)blockIdx.x * V;
    const int n8 = V >> 3;

    float m = -3.0e38f, s = 0.0f;
    for (int c8 = tid; c8 < n8; c8 += 256) {
        const bf16x8 v = *(const bf16x8*)(lr + (size_t)c8 * 8);
        float f[8], lm = -3.0e38f;
#pragma unroll
        for (int j = 0; j < 8; ++j) { f[j] = (float)v[j]; lm = fmaxf(lm, f[j]); }
        if (lm > m) { s *= __expf(m - lm); m = lm; }
#pragma unroll
        for (int j = 0; j < 8; ++j) s += __expf(f[j] - m);
    }
    for (int c = n8 * 8 + tid; c < V; c += 256) {
        const float f = (float)lr[c];
        if (f > m) { s *= __expf(m - f); m = f; }
        s += __expf(f - m);
    }

    __shared__ float mS[256], sS[256];
    mS[tid] = m; sS[tid] = s;
    __syncthreads();
    for (int off = 128; off > 0; off >>= 1) {
        if (tid < off) {
            const float m1 = mS[tid], m2 = mS[tid + off];
            const float M_ = fmaxf(m1, m2);
            sS[tid] = sS[tid] * __expf(m1 - M_) + sS[tid + off] * __expf(m2 - M_);
            mS[tid] = M_;
        }
        __syncthreads();
    }
    const float M_  = mS[0];
    const float inv = 1.0f / sS[0];

    for (int c8 = tid; c8 < n8; c8 += 256) {
        const bf16x8 v = *(const bf16x8*)(lr + (size_t)c8 * 8);
#pragma unroll
        for (int j = 0; j < 8; ++j)
            pr[(size_t)c8 * 8 + j] = __expf((float)v[j] - M_) * inv;
    }
    for (int c = n8 * 8 + tid; c < V; c += 256)
        pr[c] = __expf((float)lr[c] - M_) * inv;
}

// ---------------------------------------------------------------------------
// bf16 MFMA GEMM: C[M,N] = A[M,K] @ B^T[N,K] + bias
//   128x128 tile / 4 waves, BK=64, global_load_lds staging with both-sides
//   XOR chunk swizzle (bank-conflict-free ds_read_b128), 16x16x32 MFMA.
//   ADD: f32 C += v.  GELU_: erf-gelu.  OUTBF: bf16 C.
//   VOUT: QKV mode — tiles with col >= 1536 (V block) write transposed into
//         vTo[bb*12+hh][d][srow] instead of C.
//   K % 64 == 0, M % 128 == 0 required; N guarded.
// ---------------------------------------------------------------------------
template<bool ADD, bool GELU_, bool OUTBF, bool VOUT>
__global__ __launch_bounds__(256) void gemm_mfma(
    const bf16_t* __restrict__ A, const bf16_t* __restrict__ Bw,
    const float* __restrict__ bias, void* __restrict__ Cv,
    bf16_t* __restrict__ vTo,
    int M, int N, int K, int lda, int ldb, int ldc)
{
    __shared__ bf16_t lds[16384];           // A [128][64] @0, B [128][64] @8192

    const int tid  = threadIdx.x;
    const int lane = tid & 63;
    const int w    = tid >> 6;
    const int wr   = w >> 1, wc = w & 1;
    const int row0 = blockIdx.x * 128;
    const int col0 = blockIdx.y * 128;

    // staging: per round it (0..3), wave w covers rows w*32+it*8 .. +8.
    // lane = row8*8 + slot; global chunk = slot ^ row8 (involution) so that
    // the swizzled ds_read below hits distinct banks.
    const int row8 = lane >> 3;
    const int sch  = (lane & 7) ^ row8;

    const int aRowB = row0 + w * 32;
    const int bRowB = col0 + w * 32;

    f32x4 acc[4][4];
#pragma unroll
    for (int m = 0; m < 4; ++m)
#pragma unroll
        for (int n = 0; n < 4; ++n)
            acc[m][n] = (f32x4){0.f, 0.f, 0.f, 0.f};

    const int fr = lane & 15;
    const int g  = lane >> 4;

    for (int k0 = 0; k0 < K; k0 += 64) {
#pragma unroll
        for (int it = 0; it < 4; ++it) {
            const int ar = aRowB + it * 8 + row8;
            gload16(A + (size_t)ar * lda + k0 + sch * 8,
                    lds + w * 2048 + it * 512);
            int br = bRowB + it * 8 + row8;
            if (br >= N) br = 0;
            gload16(Bw + (size_t)br * ldb + k0 + sch * 8,
                    lds + 8192 + w * 2048 + it * 512);
        }
        __syncthreads();

#pragma unroll
        for (int ks = 0; ks < 2; ++ks) {
            bf16x8 af[4], bfr[4];
            const int cs = ks * 4 + g;
#pragma unroll
            for (int m = 0; m < 4; ++m) {
                const int row = wr * 64 + m * 16 + fr;
                af[m] = *(const bf16x8*)&lds[row * 64 + ((cs ^ (fr & 7)) << 3)];
            }
#pragma unroll
            for (int n = 0; n < 4; ++n) {
                const int row = wc * 64 + n * 16 + fr;
                bfr[n] = *(const bf16x8*)&lds[8192 + row * 64 + ((cs ^ (fr & 7)) << 3)];
            }
#pragma unroll
            for (int m = 0; m < 4; ++m)
#pragma unroll
                for (int n = 0; n < 4; ++n)
                    acc[m][n] = __builtin_amdgcn_mfma_f32_16x16x32_bf16(
                        af[m], bfr[n], acc[m][n], 0, 0, 0);
        }
        __syncthreads();
    }

    const int rBase = row0 + wr * 64 + g * 4;
    const int cBase = col0 + wc * 64 + fr;
#pragma unroll
    for (int n = 0; n < 4; ++n) {
        const int c = cBase + n * 16;
        if (c >= N) continue;
        const float bv = bias ? bias[c] : 0.0f;
#pragma unroll
        for (int m = 0; m < 4; ++m) {
#pragma unroll
            for (int r = 0; r < 4; ++r) {
                const int rr = rBase + m * 16 + r;
                float v = acc[m][n][r] + bv;
                if (GELU_) v = 0.5f * v * (1.0f + erff(v * 0.70710678118654752f));
                if (VOUT && c >= 1536) {
                    // V block of QKV: write transposed per-head into vTo
                    const int bb = rr >> 9, srow = rr & 511;
                    const int hd = c - 1536, hh = hd >> 6, d = hd & 63;
                    vTo[(size_t)((bb * 12 + hh) * 64 + d) * 512 + srow] = (bf16_t)v;
                } else if (OUTBF) {
                    ((bf16_t*)Cv)[(size_t)rr * ldc + c] = (bf16_t)v;
                } else {
                    float* Cf = (float*)Cv;
                    const size_t idx = (size_t)rr * ldc + c;
                    if (ADD) v += Cf[idx];
                    Cf[idx] = v;
                }
            }
        }
    }
}

// ---------------------------------------------------------------------------
// Launcher
// ---------------------------------------------------------------------------
extern "C" void kernel_launch(void* const* d_in, const int* in_sizes, int n_in,
                              void* d_out, int out_size, void* d_ws, size_t ws_size,
                              hipStream_t stream)
{
    constexpr int B = 4, S = 512, D = 768, L = 12, V = 50257, H = 12, F = 3072;
    constexpr int M  = B * S;     // 2048
    constexpr int TD = 3 * D;     // 2304
    constexpr int BH = B * H;     // 48
    constexpr int Vp = 50264;     // V padded to multiple of 8

    const int*   x    = (const int*)  d_in[0];
    const float* emb  = (const float*)d_in[1];
    const float* pos  = (const float*)d_in[2];
    const float* ln1g = (const float*)d_in[3];
    const float* ln1b = (const float*)d_in[4];
    const float* wqkv = (const float*)d_in[5];
    const float* bqkv = (const float*)d_in[6];
    const float* wo   = (const float*)d_in[7];
    const float* bo   = (const float*)d_in[8];
    const float* ln2g = (const float*)d_in[9];
    const float* ln2b = (const float*)d_in[10];
    const float* wfc  = (const float*)d_in[11];
    const float* bfc  = (const float*)d_in[12];
    const float* wpr  = (const float*)d_in[13];
    const float* bpr  = (const float*)d_in[14];
    const float* lnfg = (const float*)d_in[15];
    const float* lnfb = (const float*)d_in[16];

    float* probs  = (float*)d_out;                    // [M, V]
    float* hidden = probs + (size_t)M * V;            // [M, D]

    // ---- workspace layout -------------------------------------------------
    float*  h      = (float*)d_ws;                    // [M,D] f32
    bf16_t* qkv_bf = (bf16_t*)(h + (size_t)M * D);    // [M,TD]
    bf16_t* vT     = qkv_bf + (size_t)M * TD;         // [BH,64,S]
    bf16_t* xn_bf  = vT     + (size_t)BH * 64 * S;    // [M,D]
    bf16_t* o_bf   = xn_bf  + (size_t)M * D;          // [M,D]
    bf16_t* mid_bf = o_bf   + (size_t)M * D;          // [M,F]
    bf16_t* wqkvT  = mid_bf + (size_t)M * F;          // [L,TD,D]
    bf16_t* woT    = wqkvT  + (size_t)L * D * TD;     // [L,D,D]
    bf16_t* wfcT   = woT    + (size_t)L * D * D;      // [L,F,D]
    bf16_t* wprT   = wfcT   + (size_t)L * D * F;      // [L,D,F]
    bf16_t* hid_bf = wprT   + (size_t)L * F * D;      // [M,D]   (live at end)
    bf16_t* embB   = hid_bf + (size_t)M * D;          // [V,D]   (live at end)
    bf16_t* logits = (bf16_t*)d_ws;                   // [M,Vp] alias (h dead)

    // ---- weight prep ------------------------------------------------------
    convert_bf16<<<2048, 256, 0, stream>>>(emb, embB, (V * D) / 4);
    transpose_to_bf16<<<dim3(TD / 32, D / 32, L), dim3(32, 8), 0, stream>>>(wqkv, wqkvT, D, TD);
    transpose_to_bf16<<<dim3(D / 32,  D / 32, L), dim3(32, 8), 0, stream>>>(wo,   woT,   D, D);
    transpose_to_bf16<<<dim3(F / 32,  D / 32, L), dim3(32, 8), 0, stream>>>(wfc,  wfcT,  D, F);
    transpose_to_bf16<<<dim3(D / 32,  F / 32, L), dim3(32, 8), 0, stream>>>(wpr,  wprT,  F, D);

    // ---- embedding
    embed_kernel<<<dim3((M * D + 255) / 256), 256, 0, stream>>>(x, emb, pos, h, S, D, M * D);

    for (int i = 0; i < L; ++i) {
        layernorm_dual<<<M, 256, 0, stream>>>(h, ln1g + (size_t)i * D, ln1b + (size_t)i * D,
                                              xn_bf, nullptr, D);

        // qkv (Q,K -> qkv_bf; V -> vT transposed)
        gemm_mfma<false, false, true, true><<<dim3(M / 128, TD / 128), 256, 0, stream>>>(
            xn_bf, wqkvT + (size_t)i * D * TD, bqkv + (size_t)i * TD, qkv_bf, vT,
            M, TD, D, D, D, TD);

        flash_attn<<<dim3(S / 128, BH), 256, 0, stream>>>(qkv_bf, vT, o_bf);

        gemm_mfma<true, false, false, false><<<dim3(M / 128, D / 128), 256, 0, stream>>>(
            o_bf, woT + (size_t)i * D * D, bo + (size_t)i * D, h, nullptr,
            M, D, D, D, D, D);

        layernorm_dual<<<M, 256, 0, stream>>>(h, ln2g + (size_t)i * D, ln2b + (size_t)i * D,
                                              xn_bf, nullptr, D);

        gemm_mfma<false, true, true, false><<<dim3(M / 128, F / 128), 256, 0, stream>>>(
            xn_bf, wfcT + (size_t)i * D * F, bfc + (size_t)i * F, mid_bf, nullptr,
            M, F, D, D, D, F);

        gemm_mfma<true, false, false, false><<<dim3(M / 128, D / 128), 256, 0, stream>>>(
            mid_bf, wprT + (size_t)i * F * D, bpr + (size_t)i * D, h, nullptr,
            M, D, F, F, F, D);
    }

    layernorm_dual<<<M, 256, 0, stream>>>(h, lnfg, lnfb, hid_bf, hidden, D);

    gemm_mfma<false, false, true, false><<<dim3(M / 128, (V + 127) / 128), 256, 0, stream>>>(
        hid_bf, embB, nullptr, logits, nullptr,
        M, V, D, D, D, Vp);

    softmax_vocab<<<M, 256, 0, stream>>>(logits, probs, V, Vp);
}

// Round 6
// 2764.823 us; speedup vs baseline: 5.0685x; 1.0396x over previous
//
#include <hip/hip_runtime.h>
#include <hip/hip_bf16.h>

typedef __bf16 bf16_t;
typedef bf16_t bf16x8 __attribute__((ext_vector_type(8)));
typedef float  f32x4  __attribute__((ext_vector_type(4)));

// ---------------------------------------------------------------------------
// global -> LDS async copy, 16B per lane. lds base must be wave-uniform.
// ---------------------------------------------------------------------------
__device__ __forceinline__ void gload16(const void* g, void* l) {
    __builtin_amdgcn_global_load_lds(
        (const __attribute__((address_space(1))) unsigned int*)g,
        (__attribute__((address_space(3))) unsigned int*)l, 16, 0, 0);
}

__device__ __forceinline__ void drain_and_barrier() {
    __builtin_amdgcn_sched_barrier(0);
    asm volatile("s_waitcnt vmcnt(0)" ::: "memory");
    __builtin_amdgcn_s_barrier();
    __builtin_amdgcn_sched_barrier(0);
}

// ---------------------------------------------------------------------------
// Embedding: h[b,s,:] = emb[x[b,s],:] + posemb[s,:]
// ---------------------------------------------------------------------------
__global__ void embed_kernel(const int* __restrict__ x,
                             const float* __restrict__ emb,
                             const float* __restrict__ pos,
                             float* __restrict__ h,
                             int S, int D, int total)
{
    int i = blockIdx.x * blockDim.x + threadIdx.x;
    if (i >= total) return;
    int d  = i % D;
    int bs = i / D;
    int s  = bs % S;
    h[i] = emb[(long long)x[bs] * D + d] + pos[(long long)s * D + d];
}

// ---------------------------------------------------------------------------
// elementwise f32 -> bf16 (vectorized by 4)
// ---------------------------------------------------------------------------
__global__ void convert_bf16(const float* __restrict__ in, bf16_t* __restrict__ out, int n4)
{
    int i = blockIdx.x * blockDim.x + threadIdx.x;
    for (; i < n4; i += gridDim.x * blockDim.x) {
        float4 v = ((const float4*)in)[i];
        bf16_t* o = out + (size_t)i * 4;
        o[0] = (bf16_t)v.x; o[1] = (bf16_t)v.y; o[2] = (bf16_t)v.z; o[3] = (bf16_t)v.w;
    }
}

// ---------------------------------------------------------------------------
// Batched transpose + bf16 convert: out[z][n][k] = (bf16) in[z][k][n]
// ---------------------------------------------------------------------------
__global__ __launch_bounds__(256) void transpose_to_bf16(
    const float* __restrict__ in, bf16_t* __restrict__ out, int K, int N)
{
    const float* ip = in  + (size_t)blockIdx.z * K * N;
    bf16_t*      op = out + (size_t)blockIdx.z * K * N;
    __shared__ float t[32][33];
    const int n0 = blockIdx.x * 32, k0 = blockIdx.y * 32;
    const int tx = threadIdx.x, ty = threadIdx.y;
#pragma unroll
    for (int u = 0; u < 4; ++u)
        t[ty + u * 8][tx] = ip[(size_t)(k0 + ty + u * 8) * N + (n0 + tx)];
    __syncthreads();
#pragma unroll
    for (int u = 0; u < 4; ++u)
        op[(size_t)(n0 + ty + u * 8) * K + (k0 + tx)] = (bf16_t)t[tx][ty + u * 8];
}

// ---------------------------------------------------------------------------
// LayerNorm rows of D=768; writes bf16 (always) and f32 (if Yf != nullptr).
// ---------------------------------------------------------------------------
__global__ __launch_bounds__(256) void layernorm_dual(
    const float* __restrict__ X, const float* __restrict__ g,
    const float* __restrict__ b, bf16_t* __restrict__ Yb,
    float* __restrict__ Yf, int D)
{
    const int row = blockIdx.x;
    const float* xr = X + (long long)row * D;
    const int tid = threadIdx.x;

    float vals[3];
    float s = 0.0f;
#pragma unroll
    for (int u = 0; u < 3; ++u) { vals[u] = xr[tid + u * 256]; s += vals[u]; }

    __shared__ float red[256];
    red[tid] = s;
    __syncthreads();
    for (int off = 128; off > 0; off >>= 1) {
        if (tid < off) red[tid] += red[tid + off];
        __syncthreads();
    }
    const float mean = red[0] / (float)D;
    __syncthreads();

    float vs = 0.0f;
#pragma unroll
    for (int u = 0; u < 3; ++u) { float d = vals[u] - mean; vs += d * d; }
    red[tid] = vs;
    __syncthreads();
    for (int off = 128; off > 0; off >>= 1) {
        if (tid < off) red[tid] += red[tid + off];
        __syncthreads();
    }
    const float var  = red[0] / (float)D;
    const float rstd = rsqrtf(var + 1e-6f);

#pragma unroll
    for (int u = 0; u < 3; ++u) {
        const int c = tid + u * 256;
        const float y = (vals[u] - mean) * rstd * g[c] + b[c];
        Yb[(long long)row * D + c] = (bf16_t)y;
        if (Yf) Yf[(long long)row * D + c] = y;
    }
}

// ---------------------------------------------------------------------------
// Fused flash attention (causal, hd=64, S=512), 2-phase K/V pipeline.
// Grid: (S/128 q-tiles, B*H). Block: 256 threads = 4 waves, 32 q-rows each.
// ---------------------------------------------------------------------------
__global__ __launch_bounds__(256) void flash_attn(
    const bf16_t* __restrict__ qkv, const bf16_t* __restrict__ vT,
    bf16_t* __restrict__ o)
{
    constexpr int S = 512, TD = 2304, D = 768, H = 12;
    const int qt = blockIdx.x;
    const int z  = blockIdx.y;
    const int bb = z / H, hh = z - bb * H;
    const int tid = threadIdx.x, lane = tid & 63, w = tid >> 6;
    const int fr = lane & 15, g = lane >> 4, sub = g * 8;

    __shared__ bf16_t kS[2][4096];       // K tile [64 key][64 k], chunk-swizzled
    __shared__ bf16_t vS[2][4096];       // V^T tile [64 d][64 key], chunk-swizzled
    __shared__ bf16_t pS[4][32 * 72];    // per-wave P [32 q][64 key], padded

    bf16x8 qf[2][2];
    const bf16_t* qbase = qkv + (size_t)(bb * S + qt * 128 + w * 32) * TD + hh * 64;
#pragma unroll
    for (int m = 0; m < 2; ++m)
#pragma unroll
        for (int ks = 0; ks < 2; ++ks) {
            bf16x8 v = *(const bf16x8*)&qbase[(size_t)(m * 16 + fr) * TD + ks * 32 + sub];
#pragma unroll
            for (int j = 0; j < 8; ++j) v[j] = v[j] * (bf16_t)0.125f;
            qf[m][ks] = v;
        }

    f32x4 oacc[2][4];
    float mrun[2][4], lrun[2][4];
#pragma unroll
    for (int m = 0; m < 2; ++m)
#pragma unroll
        for (int r = 0; r < 4; ++r) { mrun[m][r] = -3.0e38f; lrun[m][r] = 0.0f; }
#pragma unroll
    for (int m = 0; m < 2; ++m)
#pragma unroll
        for (int n = 0; n < 4; ++n)
            oacc[m][n] = (f32x4){0.f, 0.f, 0.f, 0.f};

    int qr[2][4];
#pragma unroll
    for (int m = 0; m < 2; ++m)
#pragma unroll
        for (int r = 0; r < 4; ++r)
            qr[m][r] = qt * 128 + w * 32 + m * 16 + g * 4 + r;

    const int srow8  = lane >> 3;
    const int schunk = (lane & 7) ^ (srow8 & 7);

    const bf16_t* kGbase = qkv + (size_t)(bb * S) * TD + D + hh * 64;
    const bf16_t* vGbase = vT + (size_t)z * 64 * S;
    const int nkv = 2 * qt + 2;

    // stage K/V tile t into buffer buf
#define STAGE_KV(buf, t)                                                        \
    {                                                                           \
        _Pragma("unroll")                                                       \
        for (int it = 0; it < 2; ++it) {                                        \
            const int row = it * 32 + w * 8 + srow8;                            \
            gload16(kGbase + (size_t)((t) * 64 + row) * TD + schunk * 8,        \
                    &kS[buf][it * 2048 + w * 512]);                             \
            gload16(vGbase + (size_t)row * S + (t) * 64 + schunk * 8,           \
                    &vS[buf][it * 2048 + w * 512]);                             \
        }                                                                       \
    }

    STAGE_KV(0, 0);
    drain_and_barrier();

    int cur = 0;
    for (int t = 0; t < nkv; ++t) {
        if (t + 1 < nkv) STAGE_KV(cur ^ 1, t + 1);

        f32x4 sacc[2][4];
#pragma unroll
        for (int m = 0; m < 2; ++m)
#pragma unroll
            for (int n = 0; n < 4; ++n)
                sacc[m][n] = (f32x4){0.f, 0.f, 0.f, 0.f};
#pragma unroll
        for (int ks = 0; ks < 2; ++ks) {
            bf16x8 bK[4];
#pragma unroll
            for (int n = 0; n < 4; ++n) {
                const int rw = n * 16 + fr;
                const int c  = ks * 4 + g;
                bK[n] = *(const bf16x8*)&kS[cur][rw * 64 + ((c ^ (rw & 7)) << 3)];
            }
#pragma unroll
            for (int m = 0; m < 2; ++m)
#pragma unroll
                for (int n = 0; n < 4; ++n)
                    sacc[m][n] = __builtin_amdgcn_mfma_f32_16x16x32_bf16(
                        qf[m][ks], bK[n], sacc[m][n], 0, 0, 0);
        }

        if (t >= 2 * qt) {
#pragma unroll
            for (int m = 0; m < 2; ++m)
#pragma unroll
                for (int n = 0; n < 4; ++n) {
                    const int key = t * 64 + n * 16 + fr;
#pragma unroll
                    for (int r = 0; r < 4; ++r)
                        if (key > qr[m][r]) sacc[m][n][r] = -3.0e38f;
                }
        }

        float sf[2][4], rs[2][4];
#pragma unroll
        for (int m = 0; m < 2; ++m)
#pragma unroll
            for (int r = 0; r < 4; ++r) {
                float v = fmaxf(fmaxf(sacc[m][0][r], sacc[m][1][r]),
                                fmaxf(sacc[m][2][r], sacc[m][3][r]));
#pragma unroll
                for (int off = 1; off < 16; off <<= 1)
                    v = fmaxf(v, __shfl_xor(v, off));
                const float mn = fmaxf(mrun[m][r], v);
                sf[m][r] = __expf(mrun[m][r] - mn);
                mrun[m][r] = mn;
                lrun[m][r] *= sf[m][r];
            }
#pragma unroll
        for (int m = 0; m < 2; ++m)
#pragma unroll
            for (int n = 0; n < 4; ++n)
#pragma unroll
                for (int r = 0; r < 4; ++r)
                    oacc[m][n][r] *= sf[m][r];
#pragma unroll
        for (int m = 0; m < 2; ++m)
#pragma unroll
            for (int r = 0; r < 4; ++r) rs[m][r] = 0.0f;
#pragma unroll
        for (int m = 0; m < 2; ++m)
#pragma unroll
            for (int n = 0; n < 4; ++n)
#pragma unroll
                for (int r = 0; r < 4; ++r) {
                    const float p = __expf(sacc[m][n][r] - mrun[m][r]);
                    sacc[m][n][r] = p;
                    rs[m][r] += p;
                }
#pragma unroll
        for (int m = 0; m < 2; ++m)
#pragma unroll
            for (int r = 0; r < 4; ++r) {
                float v = rs[m][r];
#pragma unroll
                for (int off = 1; off < 16; off <<= 1) v += __shfl_xor(v, off);
                lrun[m][r] += v;
            }

        bf16_t* pw = pS[w];
#pragma unroll
        for (int m = 0; m < 2; ++m)
#pragma unroll
            for (int n = 0; n < 4; ++n)
#pragma unroll
                for (int r = 0; r < 4; ++r)
                    pw[(m * 16 + g * 4 + r) * 72 + n * 16 + fr] = (bf16_t)sacc[m][n][r];

#pragma unroll
        for (int ks = 0; ks < 2; ++ks) {
            bf16x8 pa[2], vb[4];
#pragma unroll
            for (int m = 0; m < 2; ++m)
                pa[m] = *(const bf16x8*)&pw[(m * 16 + fr) * 72 + ks * 32 + sub];
#pragma unroll
            for (int n = 0; n < 4; ++n) {
                const int rw = n * 16 + fr;
                const int c  = ks * 4 + g;
                vb[n] = *(const bf16x8*)&vS[cur][rw * 64 + ((c ^ (rw & 7)) << 3)];
            }
#pragma unroll
            for (int m = 0; m < 2; ++m)
#pragma unroll
                for (int n = 0; n < 4; ++n)
                    oacc[m][n] = __builtin_amdgcn_mfma_f32_16x16x32_bf16(
                        pa[m], vb[n], oacc[m][n], 0, 0, 0);
        }
        drain_and_barrier();
        cur ^= 1;
    }
#undef STAGE_KV

    bf16_t* obase = o + (size_t)(bb * S + qt * 128 + w * 32) * D + hh * 64;
#pragma unroll
    for (int m = 0; m < 2; ++m)
#pragma unroll
        for (int r = 0; r < 4; ++r) {
            const float inv = 1.0f / lrun[m][r];
#pragma unroll
            for (int n = 0; n < 4; ++n)
                obase[(size_t)(m * 16 + g * 4 + r) * D + n * 16 + fr] =
                    (bf16_t)(oacc[m][n][r] * inv);
        }
}

// ---------------------------------------------------------------------------
// Vocab softmax: bf16 logits (stride Vp) -> f32 probs (stride V).
// ---------------------------------------------------------------------------
__global__ __launch_bounds__(256) void softmax_vocab(
    const bf16_t* __restrict__ logits, float* __restrict__ probs, int V, int Vp)
{
    const int tid = threadIdx.x;
    const bf16_t* lr = logits + (size_t)blockIdx.x * Vp;
    float* pr = probs + (size_t)blockIdx.x * V;
    const int n8 = V >> 3;

    float m = -3.0e38f, s = 0.0f;
    for (int c8 = tid; c8 < n8; c8 += 256) {
        const bf16x8 v = *(const bf16x8*)(lr + (size_t)c8 * 8);
        float f[8], lm = -3.0e38f;
#pragma unroll
        for (int j = 0; j < 8; ++j) { f[j] = (float)v[j]; lm = fmaxf(lm, f[j]); }
        if (lm > m) { s *= __expf(m - lm); m = lm; }
#pragma unroll
        for (int j = 0; j < 8; ++j) s += __expf(f[j] - m);
    }
    for (int c = n8 * 8 + tid; c < V; c += 256) {
        const float f = (float)lr[c];
        if (f > m) { s *= __expf(m - f); m = f; }
        s += __expf(f - m);
    }

    __shared__ float mS[256], sS[256];
    mS[tid] = m; sS[tid] = s;
    __syncthreads();
    for (int off = 128; off > 0; off >>= 1) {
        if (tid < off) {
            const float m1 = mS[tid], m2 = mS[tid + off];
            const float M_ = fmaxf(m1, m2);
            sS[tid] = sS[tid] * __expf(m1 - M_) + sS[tid + off] * __expf(m2 - M_);
            mS[tid] = M_;
        }
        __syncthreads();
    }
    const float M_  = mS[0];
    const float inv = 1.0f / sS[0];

    for (int c8 = tid; c8 < n8; c8 += 256) {
        const bf16x8 v = *(const bf16x8*)(lr + (size_t)c8 * 8);
#pragma unroll
        for (int j = 0; j < 8; ++j)
            pr[(size_t)c8 * 8 + j] = __expf((float)v[j] - M_) * inv;
    }
    for (int c = n8 * 8 + tid; c < V; c += 256)
        pr[c] = __expf((float)lr[c] - M_) * inv;
}

// ---------------------------------------------------------------------------
// bf16 MFMA GEMM: C[M,N] = A[M,K] @ B^T[N,K] + bias
//   128x128 tile / 4 waves, BK=64, 2-phase double-buffered global_load_lds
//   staging with both-sides XOR chunk swizzle, 16x16x32 MFMA, fp32 acc.
//   ADD: f32 C += v.  GELU_: erf-gelu.  OUTBF: bf16 C.
//   VOUT: QKV mode — cols >= 1536 (V block) write transposed into vTo.
//   K % 64 == 0 (nt >= 2), M % 128 == 0 required; N guarded.
// ---------------------------------------------------------------------------
template<bool ADD, bool GELU_, bool OUTBF, bool VOUT>
__global__ __launch_bounds__(256) void gemm_mfma(
    const bf16_t* __restrict__ A, const bf16_t* __restrict__ Bw,
    const float* __restrict__ bias, void* __restrict__ Cv,
    bf16_t* __restrict__ vTo,
    int M, int N, int K, int lda, int ldb, int ldc)
{
    __shared__ bf16_t lds[2][16384];        // [buf][ A[128][64] | B[128][64] ]

    const int tid  = threadIdx.x;
    const int lane = tid & 63;
    const int w    = tid >> 6;
    const int wr   = w >> 1, wc = w & 1;
    const int row0 = blockIdx.x * 128;
    const int col0 = blockIdx.y * 128;

    const int row8 = lane >> 3;
    const int sch  = (lane & 7) ^ row8;
    const int aRowB = row0 + w * 32;
    const int bRowB = col0 + w * 32;

    f32x4 acc[4][4];
#pragma unroll
    for (int m = 0; m < 4; ++m)
#pragma unroll
        for (int n = 0; n < 4; ++n)
            acc[m][n] = (f32x4){0.f, 0.f, 0.f, 0.f};

    const int fr = lane & 15;
    const int g  = lane >> 4;

#define STAGE_AB(buf, k0)                                                       \
    {                                                                           \
        _Pragma("unroll")                                                       \
        for (int it = 0; it < 4; ++it) {                                        \
            const int ar = aRowB + it * 8 + row8;                               \
            gload16(A + (size_t)ar * lda + (k0) + sch * 8,                      \
                    &lds[buf][w * 2048 + it * 512]);                            \
            int br = bRowB + it * 8 + row8;                                     \
            if (br >= N) br = 0;                                                \
            gload16(Bw + (size_t)br * ldb + (k0) + sch * 8,                     \
                    &lds[buf][8192 + w * 2048 + it * 512]);                     \
        }                                                                       \
    }

    const int nt = K >> 6;
    STAGE_AB(0, 0);
    drain_and_barrier();

    int cur = 0;
    for (int t = 0; t < nt; ++t) {
        if (t + 1 < nt) STAGE_AB(cur ^ 1, (t + 1) << 6);

#pragma unroll
        for (int ks = 0; ks < 2; ++ks) {
            bf16x8 af[4], bfr[4];
            const int cs = ks * 4 + g;
#pragma unroll
            for (int m = 0; m < 4; ++m) {
                const int row = wr * 64 + m * 16 + fr;
                af[m] = *(const bf16x8*)&lds[cur][row * 64 + ((cs ^ (fr & 7)) << 3)];
            }
#pragma unroll
            for (int n = 0; n < 4; ++n) {
                const int row = wc * 64 + n * 16 + fr;
                bfr[n] = *(const bf16x8*)&lds[cur][8192 + row * 64 + ((cs ^ (fr & 7)) << 3)];
            }
#pragma unroll
            for (int m = 0; m < 4; ++m)
#pragma unroll
                for (int n = 0; n < 4; ++n)
                    acc[m][n] = __builtin_amdgcn_mfma_f32_16x16x32_bf16(
                        af[m], bfr[n], acc[m][n], 0, 0, 0);
        }
        drain_and_barrier();
        cur ^= 1;
    }
#undef STAGE_AB

    // epilogue: row-major store order (n innermost) so each 128B line of a row
    // is filled by 4 consecutive wave-stores -> full-line write merge, no RFO.
    const int rBase = row0 + wr * 64 + g * 4;
    const int cBase = col0 + wc * 64 + fr;
    float bv[4];
#pragma unroll
    for (int n = 0; n < 4; ++n) {
        const int c = cBase + n * 16;
        bv[n] = (bias && c < N) ? bias[c] : 0.0f;
    }
#pragma unroll
    for (int m = 0; m < 4; ++m) {
#pragma unroll
        for (int r = 0; r < 4; ++r) {
            const int rr = rBase + m * 16 + r;
#pragma unroll
            for (int n = 0; n < 4; ++n) {
                const int c = cBase + n * 16;
                if (c >= N) continue;
                float v = acc[m][n][r] + bv[n];
                if (GELU_) v = 0.5f * v * (1.0f + erff(v * 0.70710678118654752f));
                if (VOUT && c >= 1536) {
                    const int bb = rr >> 9, srow = rr & 511;
                    const int hd = c - 1536, hh = hd >> 6, d = hd & 63;
                    vTo[(size_t)((bb * 12 + hh) * 64 + d) * 512 + srow] = (bf16_t)v;
                } else if (OUTBF) {
                    ((bf16_t*)Cv)[(size_t)rr * ldc + c] = (bf16_t)v;
                } else {
                    float* Cf = (float*)Cv;
                    const size_t idx = (size_t)rr * ldc + c;
                    if (ADD) v += Cf[idx];
                    Cf[idx] = v;
                }
            }
        }
    }
}

// ---------------------------------------------------------------------------
// Launcher
// ---------------------------------------------------------------------------
extern "C" void kernel_launch(void* const* d_in, const int* in_sizes, int n_in,
                              void* d_out, int out_size, void* d_ws, size_t ws_size,
                              hipStream_t stream)
{
    constexpr int B = 4, S = 512, D = 768, L = 12, V = 50257, H = 12, F = 3072;
    constexpr int M  = B * S;     // 2048
    constexpr int TD = 3 * D;     // 2304
    constexpr int BH = B * H;     // 48
    constexpr int Vp = 50264;     // V padded to multiple of 8

    const int*   x    = (const int*)  d_in[0];
    const float* emb  = (const float*)d_in[1];
    const float* pos  = (const float*)d_in[2];
    const float* ln1g = (const float*)d_in[3];
    const float* ln1b = (const float*)d_in[4];
    const float* wqkv = (const float*)d_in[5];
    const float* bqkv = (const float*)d_in[6];
    const float* wo   = (const float*)d_in[7];
    const float* bo   = (const float*)d_in[8];
    const float* ln2g = (const float*)d_in[9];
    const float* ln2b = (const float*)d_in[10];
    const float* wfc  = (const float*)d_in[11];
    const float* bfc  = (const float*)d_in[12];
    const float* wpr  = (const float*)d_in[13];
    const float* bpr  = (const float*)d_in[14];
    const float* lnfg = (const float*)d_in[15];
    const float* lnfb = (const float*)d_in[16];

    float* probs  = (float*)d_out;                    // [M, V]
    float* hidden = probs + (size_t)M * V;            // [M, D]

    // ---- workspace layout -------------------------------------------------
    float*  h      = (float*)d_ws;                    // [M,D] f32
    bf16_t* qkv_bf = (bf16_t*)(h + (size_t)M * D);    // [M,TD]
    bf16_t* vT     = qkv_bf + (size_t)M * TD;         // [BH,64,S]
    bf16_t* xn_bf  = vT     + (size_t)BH * 64 * S;    // [M,D]
    bf16_t* o_bf   = xn_bf  + (size_t)M * D;          // [M,D]
    bf16_t* mid_bf = o_bf   + (size_t)M * D;          // [M,F]
    bf16_t* wqkvT  = mid_bf + (size_t)M * F;          // [L,TD,D]
    bf16_t* woT    = wqkvT  + (size_t)L * D * TD;     // [L,D,D]
    bf16_t* wfcT   = woT    + (size_t)L * D * D;      // [L,F,D]
    bf16_t* wprT   = wfcT   + (size_t)L * D * F;      // [L,D,F]
    bf16_t* hid_bf = wprT   + (size_t)L * F * D;      // [M,D]   (live at end)
    bf16_t* embB   = hid_bf + (size_t)M * D;          // [V,D]   (live at end)
    bf16_t* logits = (bf16_t*)d_ws;                   // [M,Vp] alias (h dead)

    // ---- weight prep ------------------------------------------------------
    convert_bf16<<<2048, 256, 0, stream>>>(emb, embB, (V * D) / 4);
    transpose_to_bf16<<<dim3(TD / 32, D / 32, L), dim3(32, 8), 0, stream>>>(wqkv, wqkvT, D, TD);
    transpose_to_bf16<<<dim3(D / 32,  D / 32, L), dim3(32, 8), 0, stream>>>(wo,   woT,   D, D);
    transpose_to_bf16<<<dim3(F / 32,  D / 32, L), dim3(32, 8), 0, stream>>>(wfc,  wfcT,  D, F);
    transpose_to_bf16<<<dim3(D / 32,  F / 32, L), dim3(32, 8), 0, stream>>>(wpr,  wprT,  F, D);

    // ---- embedding
    embed_kernel<<<dim3((M * D + 255) / 256), 256, 0, stream>>>(x, emb, pos, h, S, D, M * D);

    for (int i = 0; i < L; ++i) {
        layernorm_dual<<<M, 256, 0, stream>>>(h, ln1g + (size_t)i * D, ln1b + (size_t)i * D,
                                              xn_bf, nullptr, D);

        // qkv (Q,K -> qkv_bf; V -> vT transposed)
        gemm_mfma<false, false, true, true><<<dim3(M / 128, TD / 128), 256, 0, stream>>>(
            xn_bf, wqkvT + (size_t)i * D * TD, bqkv + (size_t)i * TD, qkv_bf, vT,
            M, TD, D, D, D, TD);

        flash_attn<<<dim3(S / 128, BH), 256, 0, stream>>>(qkv_bf, vT, o_bf);

        gemm_mfma<true, false, false, false><<<dim3(M / 128, D / 128), 256, 0, stream>>>(
            o_bf, woT + (size_t)i * D * D, bo + (size_t)i * D, h, nullptr,
            M, D, D, D, D, D);

        layernorm_dual<<<M, 256, 0, stream>>>(h, ln2g + (size_t)i * D, ln2b + (size_t)i * D,
                                              xn_bf, nullptr, D);

        gemm_mfma<false, true, true, false><<<dim3(M / 128, F / 128), 256, 0, stream>>>(
            xn_bf, wfcT + (size_t)i * D * F, bfc + (size_t)i * F, mid_bf, nullptr,
            M, F, D, D, D, F);

        gemm_mfma<true, false, false, false><<<dim3(M / 128, D / 128), 256, 0, stream>>>(
            mid_bf, wprT + (size_t)i * F * D, bpr + (size_t)i * D, h, nullptr,
            M, D, F, F, F, D);
    }

    layernorm_dual<<<M, 256, 0, stream>>>(h, lnfg, lnfb, hid_bf, hidden, D);

    gemm_mfma<false, false, true, false><<<dim3(M / 128, (V + 127) / 128), 256, 0, stream>>>(
        hid_bf, embB, nullptr, logits, nullptr,
        M, V, D, D, D, Vp);

    softmax_vocab<<<M, 256, 0, stream>>>(logits, probs, V, Vp);
}

// Round 7
// 2396.083 us; speedup vs baseline: 5.8485x; 1.1539x over previous
//
#include <hip/hip_runtime.h>
#include <hip/hip_bf16.h>

typedef __bf16 bf16_t;
typedef bf16_t bf16x8 __attribute__((ext_vector_type(8)));
typedef float  f32x4  __attribute__((ext_vector_type(4)));

// ---------------------------------------------------------------------------
// global -> LDS async copy, 16B per lane. lds base must be wave-uniform.
// ---------------------------------------------------------------------------
__device__ __forceinline__ void gload16(const void* g, void* l) {
    __builtin_amdgcn_global_load_lds(
        (const __attribute__((address_space(1))) unsigned int*)g,
        (__attribute__((address_space(3))) unsigned int*)l, 16, 0, 0);
}

__device__ __forceinline__ void drain_and_barrier() {
    __builtin_amdgcn_sched_barrier(0);
    asm volatile("s_waitcnt vmcnt(0)" ::: "memory");
    __builtin_amdgcn_s_barrier();
    __builtin_amdgcn_sched_barrier(0);
}

// ---------------------------------------------------------------------------
// Embedding: h[b,s,:] = emb[x[b,s],:] + posemb[s,:]
// ---------------------------------------------------------------------------
__global__ void embed_kernel(const int* __restrict__ x,
                             const float* __restrict__ emb,
                             const float* __restrict__ pos,
                             float* __restrict__ h,
                             int S, int D, int total)
{
    int i = blockIdx.x * blockDim.x + threadIdx.x;
    if (i >= total) return;
    int d  = i % D;
    int bs = i / D;
    int s  = bs % S;
    h[i] = emb[(long long)x[bs] * D + d] + pos[(long long)s * D + d];
}

// ---------------------------------------------------------------------------
// elementwise f32 -> bf16 (vectorized by 4)
// ---------------------------------------------------------------------------
__global__ void convert_bf16(const float* __restrict__ in, bf16_t* __restrict__ out, int n4)
{
    int i = blockIdx.x * blockDim.x + threadIdx.x;
    for (; i < n4; i += gridDim.x * blockDim.x) {
        float4 v = ((const float4*)in)[i];
        bf16_t* o = out + (size_t)i * 4;
        o[0] = (bf16_t)v.x; o[1] = (bf16_t)v.y; o[2] = (bf16_t)v.z; o[3] = (bf16_t)v.w;
    }
}

// ---------------------------------------------------------------------------
// Batched transpose + bf16 convert: out[z][n][k] = (bf16) in[z][k][n]
// ---------------------------------------------------------------------------
__global__ __launch_bounds__(256) void transpose_to_bf16(
    const float* __restrict__ in, bf16_t* __restrict__ out, int K, int N)
{
    const float* ip = in  + (size_t)blockIdx.z * K * N;
    bf16_t*      op = out + (size_t)blockIdx.z * K * N;
    __shared__ float t[32][33];
    const int n0 = blockIdx.x * 32, k0 = blockIdx.y * 32;
    const int tx = threadIdx.x, ty = threadIdx.y;
#pragma unroll
    for (int u = 0; u < 4; ++u)
        t[ty + u * 8][tx] = ip[(size_t)(k0 + ty + u * 8) * N + (n0 + tx)];
    __syncthreads();
#pragma unroll
    for (int u = 0; u < 4; ++u)
        op[(size_t)(n0 + ty + u * 8) * K + (k0 + tx)] = (bf16_t)t[tx][ty + u * 8];
}

// ---------------------------------------------------------------------------
// Per-head V transpose: vT[z][d][k] = qkv[bb*S + k][2D + hh*64 + d], z=bb*H+hh
// ---------------------------------------------------------------------------
__global__ __launch_bounds__(256) void transpose_v(
    const bf16_t* __restrict__ qkv, bf16_t* __restrict__ vT)
{
    constexpr int S = 512, TD = 2304, D = 768, H = 12;
    const int z = blockIdx.y, bb = z / H, hh = z - bb * H;
    const int k0 = blockIdx.x * 64;
    const bf16_t* src = qkv + (size_t)(bb * S + k0) * TD + 2 * D + hh * 64;
    bf16_t* dst = vT + (size_t)z * 64 * S + k0;
    __shared__ bf16_t sm[64][68];
    const int c = threadIdx.x & 63, rq = threadIdx.x >> 6;
#pragma unroll
    for (int u = 0; u < 16; ++u) {
        const int r = u * 4 + rq;
        sm[r][c] = src[(size_t)r * TD + c];
    }
    __syncthreads();
#pragma unroll
    for (int u = 0; u < 16; ++u) {
        const int d = u * 4 + rq;
        dst[(size_t)d * S + c] = sm[c][d];
    }
}

// ---------------------------------------------------------------------------
// LayerNorm rows of D=768; writes bf16 (always) and f32 (if Yf != nullptr).
// ---------------------------------------------------------------------------
__global__ __launch_bounds__(256) void layernorm_dual(
    const float* __restrict__ X, const float* __restrict__ g,
    const float* __restrict__ b, bf16_t* __restrict__ Yb,
    float* __restrict__ Yf, int D)
{
    const int row = blockIdx.x;
    const float* xr = X + (long long)row * D;
    const int tid = threadIdx.x;

    float vals[3];
    float s = 0.0f;
#pragma unroll
    for (int u = 0; u < 3; ++u) { vals[u] = xr[tid + u * 256]; s += vals[u]; }

    __shared__ float red[256];
    red[tid] = s;
    __syncthreads();
    for (int off = 128; off > 0; off >>= 1) {
        if (tid < off) red[tid] += red[tid + off];
        __syncthreads();
    }
    const float mean = red[0] / (float)D;
    __syncthreads();

    float vs = 0.0f;
#pragma unroll
    for (int u = 0; u < 3; ++u) { float d = vals[u] - mean; vs += d * d; }
    red[tid] = vs;
    __syncthreads();
    for (int off = 128; off > 0; off >>= 1) {
        if (tid < off) red[tid] += red[tid + off];
        __syncthreads();
    }
    const float var  = red[0] / (float)D;
    const float rstd = rsqrtf(var + 1e-6f);

#pragma unroll
    for (int u = 0; u < 3; ++u) {
        const int c = tid + u * 256;
        const float y = (vals[u] - mean) * rstd * g[c] + b[c];
        Yb[(long long)row * D + c] = (bf16_t)y;
        if (Yf) Yf[(long long)row * D + c] = y;
    }
}

// ---------------------------------------------------------------------------
// Fused flash attention (causal, hd=64, S=512), 2-phase K/V pipeline.
// ---------------------------------------------------------------------------
__global__ __launch_bounds__(256) void flash_attn(
    const bf16_t* __restrict__ qkv, const bf16_t* __restrict__ vT,
    bf16_t* __restrict__ o)
{
    constexpr int S = 512, TD = 2304, D = 768, H = 12;
    const int qt = blockIdx.x;
    const int z  = blockIdx.y;
    const int bb = z / H, hh = z - bb * H;
    const int tid = threadIdx.x, lane = tid & 63, w = tid >> 6;
    const int fr = lane & 15, g = lane >> 4, sub = g * 8;

    __shared__ bf16_t kS[2][4096];
    __shared__ bf16_t vS[2][4096];
    __shared__ bf16_t pS[4][32 * 72];

    bf16x8 qf[2][2];
    const bf16_t* qbase = qkv + (size_t)(bb * S + qt * 128 + w * 32) * TD + hh * 64;
#pragma unroll
    for (int m = 0; m < 2; ++m)
#pragma unroll
        for (int ks = 0; ks < 2; ++ks) {
            bf16x8 v = *(const bf16x8*)&qbase[(size_t)(m * 16 + fr) * TD + ks * 32 + sub];
#pragma unroll
            for (int j = 0; j < 8; ++j) v[j] = v[j] * (bf16_t)0.125f;
            qf[m][ks] = v;
        }

    f32x4 oacc[2][4];
    float mrun[2][4], lrun[2][4];
#pragma unroll
    for (int m = 0; m < 2; ++m)
#pragma unroll
        for (int r = 0; r < 4; ++r) { mrun[m][r] = -3.0e38f; lrun[m][r] = 0.0f; }
#pragma unroll
    for (int m = 0; m < 2; ++m)
#pragma unroll
        for (int n = 0; n < 4; ++n)
            oacc[m][n] = (f32x4){0.f, 0.f, 0.f, 0.f};

    int qr[2][4];
#pragma unroll
    for (int m = 0; m < 2; ++m)
#pragma unroll
        for (int r = 0; r < 4; ++r)
            qr[m][r] = qt * 128 + w * 32 + m * 16 + g * 4 + r;

    const int srow8  = lane >> 3;
    const int schunk = (lane & 7) ^ (srow8 & 7);

    const bf16_t* kGbase = qkv + (size_t)(bb * S) * TD + D + hh * 64;
    const bf16_t* vGbase = vT + (size_t)z * 64 * S;
    const int nkv = 2 * qt + 2;

#define STAGE_KV(buf, t)                                                        \
    {                                                                           \
        _Pragma("unroll")                                                       \
        for (int it = 0; it < 2; ++it) {                                        \
            const int row = it * 32 + w * 8 + srow8;                            \
            gload16(kGbase + (size_t)((t) * 64 + row) * TD + schunk * 8,        \
                    &kS[buf][it * 2048 + w * 512]);                             \
            gload16(vGbase + (size_t)row * S + (t) * 64 + schunk * 8,           \
                    &vS[buf][it * 2048 + w * 512]);                             \
        }                                                                       \
    }

    STAGE_KV(0, 0);
    drain_and_barrier();

    int cur = 0;
    for (int t = 0; t < nkv; ++t) {
        if (t + 1 < nkv) STAGE_KV(cur ^ 1, t + 1);

        f32x4 sacc[2][4];
#pragma unroll
        for (int m = 0; m < 2; ++m)
#pragma unroll
            for (int n = 0; n < 4; ++n)
                sacc[m][n] = (f32x4){0.f, 0.f, 0.f, 0.f};
#pragma unroll
        for (int ks = 0; ks < 2; ++ks) {
            bf16x8 bK[4];
#pragma unroll
            for (int n = 0; n < 4; ++n) {
                const int rw = n * 16 + fr;
                const int c  = ks * 4 + g;
                bK[n] = *(const bf16x8*)&kS[cur][rw * 64 + ((c ^ (rw & 7)) << 3)];
            }
#pragma unroll
            for (int m = 0; m < 2; ++m)
#pragma unroll
                for (int n = 0; n < 4; ++n)
                    sacc[m][n] = __builtin_amdgcn_mfma_f32_16x16x32_bf16(
                        qf[m][ks], bK[n], sacc[m][n], 0, 0, 0);
        }

        if (t >= 2 * qt) {
#pragma unroll
            for (int m = 0; m < 2; ++m)
#pragma unroll
                for (int n = 0; n < 4; ++n) {
                    const int key = t * 64 + n * 16 + fr;
#pragma unroll
                    for (int r = 0; r < 4; ++r)
                        if (key > qr[m][r]) sacc[m][n][r] = -3.0e38f;
                }
        }

        float sf[2][4], rs[2][4];
#pragma unroll
        for (int m = 0; m < 2; ++m)
#pragma unroll
            for (int r = 0; r < 4; ++r) {
                float v = fmaxf(fmaxf(sacc[m][0][r], sacc[m][1][r]),
                                fmaxf(sacc[m][2][r], sacc[m][3][r]));
#pragma unroll
                for (int off = 1; off < 16; off <<= 1)
                    v = fmaxf(v, __shfl_xor(v, off));
                const float mn = fmaxf(mrun[m][r], v);
                sf[m][r] = __expf(mrun[m][r] - mn);
                mrun[m][r] = mn;
                lrun[m][r] *= sf[m][r];
            }
#pragma unroll
        for (int m = 0; m < 2; ++m)
#pragma unroll
            for (int n = 0; n < 4; ++n)
#pragma unroll
                for (int r = 0; r < 4; ++r)
                    oacc[m][n][r] *= sf[m][r];
#pragma unroll
        for (int m = 0; m < 2; ++m)
#pragma unroll
            for (int r = 0; r < 4; ++r) rs[m][r] = 0.0f;
#pragma unroll
        for (int m = 0; m < 2; ++m)
#pragma unroll
            for (int n = 0; n < 4; ++n)
#pragma unroll
                for (int r = 0; r < 4; ++r) {
                    const float p = __expf(sacc[m][n][r] - mrun[m][r]);
                    sacc[m][n][r] = p;
                    rs[m][r] += p;
                }
#pragma unroll
        for (int m = 0; m < 2; ++m)
#pragma unroll
            for (int r = 0; r < 4; ++r) {
                float v = rs[m][r];
#pragma unroll
                for (int off = 1; off < 16; off <<= 1) v += __shfl_xor(v, off);
                lrun[m][r] += v;
            }

        bf16_t* pw = pS[w];
#pragma unroll
        for (int m = 0; m < 2; ++m)
#pragma unroll
            for (int n = 0; n < 4; ++n)
#pragma unroll
                for (int r = 0; r < 4; ++r)
                    pw[(m * 16 + g * 4 + r) * 72 + n * 16 + fr] = (bf16_t)sacc[m][n][r];

#pragma unroll
        for (int ks = 0; ks < 2; ++ks) {
            bf16x8 pa[2], vb[4];
#pragma unroll
            for (int m = 0; m < 2; ++m)
                pa[m] = *(const bf16x8*)&pw[(m * 16 + fr) * 72 + ks * 32 + sub];
#pragma unroll
            for (int n = 0; n < 4; ++n) {
                const int rw = n * 16 + fr;
                const int c  = ks * 4 + g;
                vb[n] = *(const bf16x8*)&vS[cur][rw * 64 + ((c ^ (rw & 7)) << 3)];
            }
#pragma unroll
            for (int m = 0; m < 2; ++m)
#pragma unroll
                for (int n = 0; n < 4; ++n)
                    oacc[m][n] = __builtin_amdgcn_mfma_f32_16x16x32_bf16(
                        pa[m], vb[n], oacc[m][n], 0, 0, 0);
        }
        drain_and_barrier();
        cur ^= 1;
    }
#undef STAGE_KV

    bf16_t* obase = o + (size_t)(bb * S + qt * 128 + w * 32) * D + hh * 64;
#pragma unroll
    for (int m = 0; m < 2; ++m)
#pragma unroll
        for (int r = 0; r < 4; ++r) {
            const float inv = 1.0f / lrun[m][r];
#pragma unroll
            for (int n = 0; n < 4; ++n)
                obase[(size_t)(m * 16 + g * 4 + r) * D + n * 16 + fr] =
                    (bf16_t)(oacc[m][n][r] * inv);
        }
}

// ---------------------------------------------------------------------------
// Vocab softmax: bf16 logits (stride Vp) -> f32 probs (stride V).
// ---------------------------------------------------------------------------
__global__ __launch_bounds__(256) void softmax_vocab(
    const bf16_t* __restrict__ logits, float* __restrict__ probs, int V, int Vp)
{
    const int tid = threadIdx.x;
    const bf16_t* lr = logits + (size_t)blockIdx.x * Vp;
    float* pr = probs + (size_t)blockIdx.x * V;
    const int n8 = V >> 3;

    float m = -3.0e38f, s = 0.0f;
    for (int c8 = tid; c8 < n8; c8 += 256) {
        const bf16x8 v = *(const bf16x8*)(lr + (size_t)c8 * 8);
        float f[8], lm = -3.0e38f;
#pragma unroll
        for (int j = 0; j < 8; ++j) { f[j] = (float)v[j]; lm = fmaxf(lm, f[j]); }
        if (lm > m) { s *= __expf(m - lm); m = lm; }
#pragma unroll
        for (int j = 0; j < 8; ++j) s += __expf(f[j] - m);
    }
    for (int c = n8 * 8 + tid; c < V; c += 256) {
        const float f = (float)lr[c];
        if (f > m) { s *= __expf(m - f); m = f; }
        s += __expf(f - m);
    }

    __shared__ float mS[256], sS[256];
    mS[tid] = m; sS[tid] = s;
    __syncthreads();
    for (int off = 128; off > 0; off >>= 1) {
        if (tid < off) {
            const float m1 = mS[tid], m2 = mS[tid + off];
            const float M_ = fmaxf(m1, m2);
            sS[tid] = sS[tid] * __expf(m1 - M_) + sS[tid + off] * __expf(m2 - M_);
            mS[tid] = M_;
        }
        __syncthreads();
    }
    const float M_  = mS[0];
    const float inv = 1.0f / sS[0];

    for (int c8 = tid; c8 < n8; c8 += 256) {
        const bf16x8 v = *(const bf16x8*)(lr + (size_t)c8 * 8);
#pragma unroll
        for (int j = 0; j < 8; ++j)
            pr[(size_t)c8 * 8 + j] = __expf((float)v[j] - M_) * inv;
    }
    for (int c = n8 * 8 + tid; c < V; c += 256)
        pr[c] = __expf((float)lr[c] - M_) * inv;
}

// ---------------------------------------------------------------------------
// bf16 MFMA GEMM body: C[M,128 or 64-wide tile] = A @ B^T + bias
//   DB   : double-buffered 2-phase pipeline (64/48KB LDS) vs single (32/24KB)
//   HALFN: 128x64 tile (grid.y = N/64), 4 waves x 32 rows, acc 2x4
//   else : 128x128 tile, 2x2 waves x 64x64, acc 4x4
// ---------------------------------------------------------------------------
template<bool ADD, bool GELU_, bool OUTBF, bool DB, bool HALFN>
__device__ __forceinline__ void gemm_body(
    const bf16_t* __restrict__ A, const bf16_t* __restrict__ Bw,
    const float* __restrict__ bias, void* __restrict__ Cv,
    int M, int N, int K, int lda, int ldb, int ldc)
{
    constexpr int BN  = HALFN ? 64 : 128;
    constexpr int BUF = HALFN ? 12288 : 16384;     // elements per buffer
    __shared__ bf16_t lds[(DB ? 2 : 1) * BUF];

    const int tid  = threadIdx.x;
    const int lane = tid & 63;
    const int w    = tid >> 6;
    const int row0 = blockIdx.x * 128;
    const int col0 = blockIdx.y * BN;

    const int row8 = lane >> 3;
    const int sch  = (lane & 7) ^ row8;
    const int fr   = lane & 15;
    const int g    = lane >> 4;

    const int aRowB = row0 + w * 32;
    const int bRowB = HALFN ? (col0 + w * 16) : (col0 + w * 32);

    constexpr int MR = HALFN ? 2 : 4;
    const int wr = HALFN ? w : (w >> 1);
    const int wc = HALFN ? 0 : (w & 1);

    f32x4 acc[MR][4];
#pragma unroll
    for (int m = 0; m < MR; ++m)
#pragma unroll
        for (int n = 0; n < 4; ++n)
            acc[m][n] = (f32x4){0.f, 0.f, 0.f, 0.f};

    auto STAGE = [&](int buf, int k0) {
        bf16_t* lb = lds + buf * BUF;
#pragma unroll
        for (int it = 0; it < 4; ++it) {
            const int ar = aRowB + it * 8 + row8;
            gload16(A + (size_t)ar * lda + k0 + sch * 8, lb + w * 2048 + it * 512);
        }
#pragma unroll
        for (int it = 0; it < (HALFN ? 2 : 4); ++it) {
            int br = bRowB + it * 8 + row8;
            if (br >= N) br = 0;
            gload16(Bw + (size_t)br * ldb + k0 + sch * 8,
                    lb + 8192 + w * (HALFN ? 1024 : 2048) + it * 512);
        }
    };

    auto COMPUTE = [&](int buf) {
        bf16_t* lb = lds + buf * BUF;
#pragma unroll
        for (int ks = 0; ks < 2; ++ks) {
            bf16x8 af[MR], bfr[4];
            const int cs = ks * 4 + g;
#pragma unroll
            for (int m = 0; m < MR; ++m) {
                const int row = (HALFN ? w * 32 : wr * 64) + m * 16 + fr;
                af[m] = *(const bf16x8*)&lb[row * 64 + ((cs ^ (fr & 7)) << 3)];
            }
#pragma unroll
            for (int n = 0; n < 4; ++n) {
                const int row = (HALFN ? 0 : wc * 64) + n * 16 + fr;
                bfr[n] = *(const bf16x8*)&lb[8192 + row * 64 + ((cs ^ (fr & 7)) << 3)];
            }
#pragma unroll
            for (int m = 0; m < MR; ++m)
#pragma unroll
                for (int n = 0; n < 4; ++n)
                    acc[m][n] = __builtin_amdgcn_mfma_f32_16x16x32_bf16(
                        af[m], bfr[n], acc[m][n], 0, 0, 0);
        }
    };

    const int nt = K >> 6;
    if (DB) {
        STAGE(0, 0);
        drain_and_barrier();
        int cur = 0;
        for (int t = 0; t < nt; ++t) {
            if (t + 1 < nt) STAGE(cur ^ 1, (t + 1) << 6);
            COMPUTE(cur);
            drain_and_barrier();
            cur ^= 1;
        }
    } else {
        for (int t = 0; t < nt; ++t) {
            STAGE(0, t << 6);
            __syncthreads();
            COMPUTE(0);
            __syncthreads();
        }
    }

    // epilogue: n innermost -> 4 consecutive stores fill each 128B row segment
    const int rBase = row0 + (HALFN ? w * 32 : wr * 64) + g * 4;
    const int cBase = col0 + (HALFN ? 0 : wc * 64) + fr;
    float bv[4];
#pragma unroll
    for (int n = 0; n < 4; ++n) {
        const int c = cBase + n * 16;
        bv[n] = (bias && c < N) ? bias[c] : 0.0f;
    }
#pragma unroll
    for (int m = 0; m < MR; ++m) {
#pragma unroll
        for (int r = 0; r < 4; ++r) {
            const int rr = rBase + m * 16 + r;
#pragma unroll
            for (int n = 0; n < 4; ++n) {
                const int c = cBase + n * 16;
                if (c >= N) continue;
                float v = acc[m][n][r] + bv[n];
                if (GELU_) v = 0.5f * v * (1.0f + erff(v * 0.70710678118654752f));
                if (OUTBF) {
                    ((bf16_t*)Cv)[(size_t)rr * ldc + c] = (bf16_t)v;
                } else {
                    float* Cf = (float*)Cv;
                    const size_t idx = (size_t)rr * ldc + c;
                    if (ADD) v += Cf[idx];
                    Cf[idx] = v;
                }
            }
        }
    }
}

// distinct kernel names for profiler attribution
__global__ __launch_bounds__(256) void k_gemm_qkv(
    const bf16_t* A, const bf16_t* B, const float* bias, void* C,
    int M, int N, int K, int lda, int ldb, int ldc)
{ gemm_body<false, false, true, true, false>(A, B, bias, C, M, N, K, lda, ldb, ldc); }

__global__ __launch_bounds__(256) void k_gemm_oproj(
    const bf16_t* A, const bf16_t* B, const float* bias, void* C,
    int M, int N, int K, int lda, int ldb, int ldc)
{ gemm_body<true, false, false, true, true>(A, B, bias, C, M, N, K, lda, ldb, ldc); }

__global__ __launch_bounds__(256) void k_gemm_fc(
    const bf16_t* A, const bf16_t* B, const float* bias, void* C,
    int M, int N, int K, int lda, int ldb, int ldc)
{ gemm_body<false, true, true, true, false>(A, B, bias, C, M, N, K, lda, ldb, ldc); }

__global__ __launch_bounds__(256) void k_gemm_proj(
    const bf16_t* A, const bf16_t* B, const float* bias, void* C,
    int M, int N, int K, int lda, int ldb, int ldc)
{ gemm_body<true, false, false, true, true>(A, B, bias, C, M, N, K, lda, ldb, ldc); }

__global__ __launch_bounds__(256) void k_gemm_head(
    const bf16_t* A, const bf16_t* B, const float* bias, void* C,
    int M, int N, int K, int lda, int ldb, int ldc)
{ gemm_body<false, false, true, false, false>(A, B, bias, C, M, N, K, lda, ldb, ldc); }

// ---------------------------------------------------------------------------
// Launcher
// ---------------------------------------------------------------------------
extern "C" void kernel_launch(void* const* d_in, const int* in_sizes, int n_in,
                              void* d_out, int out_size, void* d_ws, size_t ws_size,
                              hipStream_t stream)
{
    constexpr int B = 4, S = 512, D = 768, L = 12, V = 50257, H = 12, F = 3072;
    constexpr int M  = B * S;     // 2048
    constexpr int TD = 3 * D;     // 2304
    constexpr int BH = B * H;     // 48
    constexpr int Vp = 50264;     // V padded to multiple of 8

    const int*   x    = (const int*)  d_in[0];
    const float* emb  = (const float*)d_in[1];
    const float* pos  = (const float*)d_in[2];
    const float* ln1g = (const float*)d_in[3];
    const float* ln1b = (const float*)d_in[4];
    const float* wqkv = (const float*)d_in[5];
    const float* bqkv = (const float*)d_in[6];
    const float* wo   = (const float*)d_in[7];
    const float* bo   = (const float*)d_in[8];
    const float* ln2g = (const float*)d_in[9];
    const float* ln2b = (const float*)d_in[10];
    const float* wfc  = (const float*)d_in[11];
    const float* bfc  = (const float*)d_in[12];
    const float* wpr  = (const float*)d_in[13];
    const float* bpr  = (const float*)d_in[14];
    const float* lnfg = (const float*)d_in[15];
    const float* lnfb = (const float*)d_in[16];

    float* probs  = (float*)d_out;                    // [M, V]
    float* hidden = probs + (size_t)M * V;            // [M, D]

    // ---- workspace layout -------------------------------------------------
    float*  h      = (float*)d_ws;                    // [M,D] f32
    bf16_t* qkv_bf = (bf16_t*)(h + (size_t)M * D);    // [M,TD]
    bf16_t* vT     = qkv_bf + (size_t)M * TD;         // [BH,64,S]
    bf16_t* xn_bf  = vT     + (size_t)BH * 64 * S;    // [M,D]
    bf16_t* o_bf   = xn_bf  + (size_t)M * D;          // [M,D]
    bf16_t* mid_bf = o_bf   + (size_t)M * D;          // [M,F]
    bf16_t* wqkvT  = mid_bf + (size_t)M * F;          // [L,TD,D]
    bf16_t* woT    = wqkvT  + (size_t)L * D * TD;     // [L,D,D]
    bf16_t* wfcT   = woT    + (size_t)L * D * D;      // [L,F,D]
    bf16_t* wprT   = wfcT   + (size_t)L * D * F;      // [L,D,F]
    bf16_t* hid_bf = wprT   + (size_t)L * F * D;      // [M,D]   (live at end)
    bf16_t* embB   = hid_bf + (size_t)M * D;          // [V,D]   (live at end)
    bf16_t* logits = (bf16_t*)d_ws;                   // [M,Vp] alias (h dead)

    // ---- weight prep ------------------------------------------------------
    convert_bf16<<<2048, 256, 0, stream>>>(emb, embB, (V * D) / 4);
    transpose_to_bf16<<<dim3(TD / 32, D / 32, L), dim3(32, 8), 0, stream>>>(wqkv, wqkvT, D, TD);
    transpose_to_bf16<<<dim3(D / 32,  D / 32, L), dim3(32, 8), 0, stream>>>(wo,   woT,   D, D);
    transpose_to_bf16<<<dim3(F / 32,  D / 32, L), dim3(32, 8), 0, stream>>>(wfc,  wfcT,  D, F);
    transpose_to_bf16<<<dim3(D / 32,  F / 32, L), dim3(32, 8), 0, stream>>>(wpr,  wprT,  F, D);

    // ---- embedding
    embed_kernel<<<dim3((M * D + 255) / 256), 256, 0, stream>>>(x, emb, pos, h, S, D, M * D);

    for (int i = 0; i < L; ++i) {
        layernorm_dual<<<M, 256, 0, stream>>>(h, ln1g + (size_t)i * D, ln1b + (size_t)i * D,
                                              xn_bf, nullptr, D);

        k_gemm_qkv<<<dim3(M / 128, TD / 128), 256, 0, stream>>>(
            xn_bf, wqkvT + (size_t)i * D * TD, bqkv + (size_t)i * TD, qkv_bf,
            M, TD, D, D, D, TD);

        transpose_v<<<dim3(S / 64, BH), 256, 0, stream>>>(qkv_bf, vT);

        flash_attn<<<dim3(S / 128, BH), 256, 0, stream>>>(qkv_bf, vT, o_bf);

        k_gemm_oproj<<<dim3(M / 128, D / 64), 256, 0, stream>>>(
            o_bf, woT + (size_t)i * D * D, bo + (size_t)i * D, h,
            M, D, D, D, D, D);

        layernorm_dual<<<M, 256, 0, stream>>>(h, ln2g + (size_t)i * D, ln2b + (size_t)i * D,
                                              xn_bf, nullptr, D);

        k_gemm_fc<<<dim3(M / 128, F / 128), 256, 0, stream>>>(
            xn_bf, wfcT + (size_t)i * D * F, bfc + (size_t)i * F, mid_bf,
            M, F, D, D, D, F);

        k_gemm_proj<<<dim3(M / 128, D / 64), 256, 0, stream>>>(
            mid_bf, wprT + (size_t)i * F * D, bpr + (size_t)i * D, h,
            M, D, F, F, F, D);
    }

    layernorm_dual<<<M, 256, 0, stream>>>(h, lnfg, lnfb, hid_bf, hidden, D);

    k_gemm_head<<<dim3(M / 128, (V + 127) / 128), 256, 0, stream>>>(
        hid_bf, embB, nullptr, logits,
        M, V, D, D, D, Vp);

    softmax_vocab<<<M, 256, 0, stream>>>(logits, probs, V, Vp);
}

// Round 8
// 2370.335 us; speedup vs baseline: 5.9120x; 1.0109x over previous
//
#include <hip/hip_runtime.h>
#include <hip/hip_bf16.h>

typedef __bf16 bf16_t;
typedef bf16_t bf16x8 __attribute__((ext_vector_type(8)));
typedef float  f32x4  __attribute__((ext_vector_type(4)));

// ---------------------------------------------------------------------------
// global -> LDS async copy, 16B per lane. lds base must be wave-uniform.
// ---------------------------------------------------------------------------
__device__ __forceinline__ void gload16(const void* g, void* l) {
    __builtin_amdgcn_global_load_lds(
        (const __attribute__((address_space(1))) unsigned int*)g,
        (__attribute__((address_space(3))) unsigned int*)l, 16, 0, 0);
}

__device__ __forceinline__ void drain_and_barrier() {
    __builtin_amdgcn_sched_barrier(0);
    asm volatile("s_waitcnt vmcnt(0)" ::: "memory");
    __builtin_amdgcn_s_barrier();
    __builtin_amdgcn_sched_barrier(0);
}

// ---------------------------------------------------------------------------
// Embedding: h[b,s,:] = emb[x[b,s],:] + posemb[s,:]
// ---------------------------------------------------------------------------
__global__ void embed_kernel(const int* __restrict__ x,
                             const float* __restrict__ emb,
                             const float* __restrict__ pos,
                             float* __restrict__ h,
                             int S, int D, int total)
{
    int i = blockIdx.x * blockDim.x + threadIdx.x;
    if (i >= total) return;
    int d  = i % D;
    int bs = i / D;
    int s  = bs % S;
    h[i] = emb[(long long)x[bs] * D + d] + pos[(long long)s * D + d];
}

// ---------------------------------------------------------------------------
// elementwise f32 -> bf16 (vectorized by 4)
// ---------------------------------------------------------------------------
__global__ void convert_bf16(const float* __restrict__ in, bf16_t* __restrict__ out, int n4)
{
    int i = blockIdx.x * blockDim.x + threadIdx.x;
    for (; i < n4; i += gridDim.x * blockDim.x) {
        float4 v = ((const float4*)in)[i];
        bf16_t* o = out + (size_t)i * 4;
        o[0] = (bf16_t)v.x; o[1] = (bf16_t)v.y; o[2] = (bf16_t)v.z; o[3] = (bf16_t)v.w;
    }
}

// ---------------------------------------------------------------------------
// Batched transpose + bf16 convert: out[z][n][k] = (bf16) in[z][k][n]
// ---------------------------------------------------------------------------
__global__ __launch_bounds__(256) void transpose_to_bf16(
    const float* __restrict__ in, bf16_t* __restrict__ out, int K, int N)
{
    const float* ip = in  + (size_t)blockIdx.z * K * N;
    bf16_t*      op = out + (size_t)blockIdx.z * K * N;
    __shared__ float t[32][33];
    const int n0 = blockIdx.x * 32, k0 = blockIdx.y * 32;
    const int tx = threadIdx.x, ty = threadIdx.y;
#pragma unroll
    for (int u = 0; u < 4; ++u)
        t[ty + u * 8][tx] = ip[(size_t)(k0 + ty + u * 8) * N + (n0 + tx)];
    __syncthreads();
#pragma unroll
    for (int u = 0; u < 4; ++u)
        op[(size_t)(n0 + ty + u * 8) * K + (k0 + tx)] = (bf16_t)t[tx][ty + u * 8];
}

// ---------------------------------------------------------------------------
// Per-head V transpose: vT[z][d][k] = qkv[bb*S + k][2D + hh*64 + d], z=bb*H+hh
// ---------------------------------------------------------------------------
__global__ __launch_bounds__(256) void transpose_v(
    const bf16_t* __restrict__ qkv, bf16_t* __restrict__ vT)
{
    constexpr int S = 512, TD = 2304, D = 768, H = 12;
    const int z = blockIdx.y, bb = z / H, hh = z - bb * H;
    const int k0 = blockIdx.x * 64;
    const bf16_t* src = qkv + (size_t)(bb * S + k0) * TD + 2 * D + hh * 64;
    bf16_t* dst = vT + (size_t)z * 64 * S + k0;
    __shared__ bf16_t sm[64][68];
    const int c = threadIdx.x & 63, rq = threadIdx.x >> 6;
#pragma unroll
    for (int u = 0; u < 16; ++u) {
        const int r = u * 4 + rq;
        sm[r][c] = src[(size_t)r * TD + c];
    }
    __syncthreads();
#pragma unroll
    for (int u = 0; u < 16; ++u) {
        const int d = u * 4 + rq;
        dst[(size_t)d * S + c] = sm[c][d];
    }
}

// ---------------------------------------------------------------------------
// LayerNorm rows of D=768; writes bf16 (always) and f32 (if Yf != nullptr).
// ---------------------------------------------------------------------------
__global__ __launch_bounds__(256) void layernorm_dual(
    const float* __restrict__ X, const float* __restrict__ g,
    const float* __restrict__ b, bf16_t* __restrict__ Yb,
    float* __restrict__ Yf, int D)
{
    const int row = blockIdx.x;
    const float* xr = X + (long long)row * D;
    const int tid = threadIdx.x;

    float vals[3];
    float s = 0.0f;
#pragma unroll
    for (int u = 0; u < 3; ++u) { vals[u] = xr[tid + u * 256]; s += vals[u]; }

    __shared__ float red[256];
    red[tid] = s;
    __syncthreads();
    for (int off = 128; off > 0; off >>= 1) {
        if (tid < off) red[tid] += red[tid + off];
        __syncthreads();
    }
    const float mean = red[0] / (float)D;
    __syncthreads();

    float vs = 0.0f;
#pragma unroll
    for (int u = 0; u < 3; ++u) { float d = vals[u] - mean; vs += d * d; }
    red[tid] = vs;
    __syncthreads();
    for (int off = 128; off > 0; off >>= 1) {
        if (tid < off) red[tid] += red[tid + off];
        __syncthreads();
    }
    const float var  = red[0] / (float)D;
    const float rstd = rsqrtf(var + 1e-6f);

#pragma unroll
    for (int u = 0; u < 3; ++u) {
        const int c = tid + u * 256;
        const float y = (vals[u] - mean) * rstd * g[c] + b[c];
        Yb[(long long)row * D + c] = (bf16_t)y;
        if (Yf) Yf[(long long)row * D + c] = y;
    }
}

// ---------------------------------------------------------------------------
// Fused flash attention (causal, hd=64, S=512), 2-phase K/V pipeline.
// ---------------------------------------------------------------------------
__global__ __launch_bounds__(256) void flash_attn(
    const bf16_t* __restrict__ qkv, const bf16_t* __restrict__ vT,
    bf16_t* __restrict__ o)
{
    constexpr int S = 512, TD = 2304, D = 768, H = 12;
    const int qt = blockIdx.x;
    const int z  = blockIdx.y;
    const int bb = z / H, hh = z - bb * H;
    const int tid = threadIdx.x, lane = tid & 63, w = tid >> 6;
    const int fr = lane & 15, g = lane >> 4, sub = g * 8;

    __shared__ bf16_t kS[2][4096];
    __shared__ bf16_t vS[2][4096];
    __shared__ bf16_t pS[4][32 * 72];

    bf16x8 qf[2][2];
    const bf16_t* qbase = qkv + (size_t)(bb * S + qt * 128 + w * 32) * TD + hh * 64;
#pragma unroll
    for (int m = 0; m < 2; ++m)
#pragma unroll
        for (int ks = 0; ks < 2; ++ks) {
            bf16x8 v = *(const bf16x8*)&qbase[(size_t)(m * 16 + fr) * TD + ks * 32 + sub];
#pragma unroll
            for (int j = 0; j < 8; ++j) v[j] = v[j] * (bf16_t)0.125f;
            qf[m][ks] = v;
        }

    f32x4 oacc[2][4];
    float mrun[2][4], lrun[2][4];
#pragma unroll
    for (int m = 0; m < 2; ++m)
#pragma unroll
        for (int r = 0; r < 4; ++r) { mrun[m][r] = -3.0e38f; lrun[m][r] = 0.0f; }
#pragma unroll
    for (int m = 0; m < 2; ++m)
#pragma unroll
        for (int n = 0; n < 4; ++n)
            oacc[m][n] = (f32x4){0.f, 0.f, 0.f, 0.f};

    int qr[2][4];
#pragma unroll
    for (int m = 0; m < 2; ++m)
#pragma unroll
        for (int r = 0; r < 4; ++r)
            qr[m][r] = qt * 128 + w * 32 + m * 16 + g * 4 + r;

    const int srow8  = lane >> 3;
    const int schunk = (lane & 7) ^ (srow8 & 7);

    const bf16_t* kGbase = qkv + (size_t)(bb * S) * TD + D + hh * 64;
    const bf16_t* vGbase = vT + (size_t)z * 64 * S;
    const int nkv = 2 * qt + 2;

#define STAGE_KV(buf, t)                                                        \
    {                                                                           \
        _Pragma("unroll")                                                       \
        for (int it = 0; it < 2; ++it) {                                        \
            const int row = it * 32 + w * 8 + srow8;                            \
            gload16(kGbase + (size_t)((t) * 64 + row) * TD + schunk * 8,        \
                    &kS[buf][it * 2048 + w * 512]);                             \
            gload16(vGbase + (size_t)row * S + (t) * 64 + schunk * 8,           \
                    &vS[buf][it * 2048 + w * 512]);                             \
        }                                                                       \
    }

    STAGE_KV(0, 0);
    drain_and_barrier();

    int cur = 0;
    for (int t = 0; t < nkv; ++t) {
        if (t + 1 < nkv) STAGE_KV(cur ^ 1, t + 1);

        f32x4 sacc[2][4];
#pragma unroll
        for (int m = 0; m < 2; ++m)
#pragma unroll
            for (int n = 0; n < 4; ++n)
                sacc[m][n] = (f32x4){0.f, 0.f, 0.f, 0.f};
#pragma unroll
        for (int ks = 0; ks < 2; ++ks) {
            bf16x8 bK[4];
#pragma unroll
            for (int n = 0; n < 4; ++n) {
                const int rw = n * 16 + fr;
                const int c  = ks * 4 + g;
                bK[n] = *(const bf16x8*)&kS[cur][rw * 64 + ((c ^ (rw & 7)) << 3)];
            }
#pragma unroll
            for (int m = 0; m < 2; ++m)
#pragma unroll
                for (int n = 0; n < 4; ++n)
                    sacc[m][n] = __builtin_amdgcn_mfma_f32_16x16x32_bf16(
                        qf[m][ks], bK[n], sacc[m][n], 0, 0, 0);
        }

        if (t >= 2 * qt) {
#pragma unroll
            for (int m = 0; m < 2; ++m)
#pragma unroll
                for (int n = 0; n < 4; ++n) {
                    const int key = t * 64 + n * 16 + fr;
#pragma unroll
                    for (int r = 0; r < 4; ++r)
                        if (key > qr[m][r]) sacc[m][n][r] = -3.0e38f;
                }
        }

        float sf[2][4], rs[2][4];
#pragma unroll
        for (int m = 0; m < 2; ++m)
#pragma unroll
            for (int r = 0; r < 4; ++r) {
                float v = fmaxf(fmaxf(sacc[m][0][r], sacc[m][1][r]),
                                fmaxf(sacc[m][2][r], sacc[m][3][r]));
#pragma unroll
                for (int off = 1; off < 16; off <<= 1)
                    v = fmaxf(v, __shfl_xor(v, off));
                const float mn = fmaxf(mrun[m][r], v);
                sf[m][r] = __expf(mrun[m][r] - mn);
                mrun[m][r] = mn;
                lrun[m][r] *= sf[m][r];
            }
#pragma unroll
        for (int m = 0; m < 2; ++m)
#pragma unroll
            for (int n = 0; n < 4; ++n)
#pragma unroll
                for (int r = 0; r < 4; ++r)
                    oacc[m][n][r] *= sf[m][r];
#pragma unroll
        for (int m = 0; m < 2; ++m)
#pragma unroll
            for (int r = 0; r < 4; ++r) rs[m][r] = 0.0f;
#pragma unroll
        for (int m = 0; m < 2; ++m)
#pragma unroll
            for (int n = 0; n < 4; ++n)
#pragma unroll
                for (int r = 0; r < 4; ++r) {
                    const float p = __expf(sacc[m][n][r] - mrun[m][r]);
                    sacc[m][n][r] = p;
                    rs[m][r] += p;
                }
#pragma unroll
        for (int m = 0; m < 2; ++m)
#pragma unroll
            for (int r = 0; r < 4; ++r) {
                float v = rs[m][r];
#pragma unroll
                for (int off = 1; off < 16; off <<= 1) v += __shfl_xor(v, off);
                lrun[m][r] += v;
            }

        bf16_t* pw = pS[w];
#pragma unroll
        for (int m = 0; m < 2; ++m)
#pragma unroll
            for (int n = 0; n < 4; ++n)
#pragma unroll
                for (int r = 0; r < 4; ++r)
                    pw[(m * 16 + g * 4 + r) * 72 + n * 16 + fr] = (bf16_t)sacc[m][n][r];

#pragma unroll
        for (int ks = 0; ks < 2; ++ks) {
            bf16x8 pa[2], vb[4];
#pragma unroll
            for (int m = 0; m < 2; ++m)
                pa[m] = *(const bf16x8*)&pw[(m * 16 + fr) * 72 + ks * 32 + sub];
#pragma unroll
            for (int n = 0; n < 4; ++n) {
                const int rw = n * 16 + fr;
                const int c  = ks * 4 + g;
                vb[n] = *(const bf16x8*)&vS[cur][rw * 64 + ((c ^ (rw & 7)) << 3)];
            }
#pragma unroll
            for (int m = 0; m < 2; ++m)
#pragma unroll
                for (int n = 0; n < 4; ++n)
                    oacc[m][n] = __builtin_amdgcn_mfma_f32_16x16x32_bf16(
                        pa[m], vb[n], oacc[m][n], 0, 0, 0);
        }
        drain_and_barrier();
        cur ^= 1;
    }
#undef STAGE_KV

    bf16_t* obase = o + (size_t)(bb * S + qt * 128 + w * 32) * D + hh * 64;
#pragma unroll
    for (int m = 0; m < 2; ++m)
#pragma unroll
        for (int r = 0; r < 4; ++r) {
            const float inv = 1.0f / lrun[m][r];
#pragma unroll
            for (int n = 0; n < 4; ++n)
                obase[(size_t)(m * 16 + g * 4 + r) * D + n * 16 + fr] =
                    (bf16_t)(oacc[m][n][r] * inv);
        }
}

// ---------------------------------------------------------------------------
// Vocab softmax: bf16 logits (stride Vp) -> f32 probs (stride V).
// ---------------------------------------------------------------------------
__global__ __launch_bounds__(256) void softmax_vocab(
    const bf16_t* __restrict__ logits, float* __restrict__ probs, int V, int Vp)
{
    const int tid = threadIdx.x;
    const bf16_t* lr = logits + (size_t)blockIdx.x * Vp;
    float* pr = probs + (size_t)blockIdx.x * V;
    const int n8 = V >> 3;

    float m = -3.0e38f, s = 0.0f;
    for (int c8 = tid; c8 < n8; c8 += 256) {
        const bf16x8 v = *(const bf16x8*)(lr + (size_t)c8 * 8);
        float f[8], lm = -3.0e38f;
#pragma unroll
        for (int j = 0; j < 8; ++j) { f[j] = (float)v[j]; lm = fmaxf(lm, f[j]); }
        if (lm > m) { s *= __expf(m - lm); m = lm; }
#pragma unroll
        for (int j = 0; j < 8; ++j) s += __expf(f[j] - m);
    }
    for (int c = n8 * 8 + tid; c < V; c += 256) {
        const float f = (float)lr[c];
        if (f > m) { s *= __expf(m - f); m = f; }
        s += __expf(f - m);
    }

    __shared__ float mS[256], sS[256];
    mS[tid] = m; sS[tid] = s;
    __syncthreads();
    for (int off = 128; off > 0; off >>= 1) {
        if (tid < off) {
            const float m1 = mS[tid], m2 = mS[tid + off];
            const float M_ = fmaxf(m1, m2);
            sS[tid] = sS[tid] * __expf(m1 - M_) + sS[tid + off] * __expf(m2 - M_);
            mS[tid] = M_;
        }
        __syncthreads();
    }
    const float M_  = mS[0];
    const float inv = 1.0f / sS[0];

    for (int c8 = tid; c8 < n8; c8 += 256) {
        const bf16x8 v = *(const bf16x8*)(lr + (size_t)c8 * 8);
#pragma unroll
        for (int j = 0; j < 8; ++j)
            pr[(size_t)c8 * 8 + j] = __expf((float)v[j] - M_) * inv;
    }
    for (int c = n8 * 8 + tid; c < V; c += 256)
        pr[c] = __expf((float)lr[c] - M_) * inv;
}

// ---------------------------------------------------------------------------
// bf16 MFMA GEMM body (layer GEMMs): C[M, tile] = A @ B^T + bias
//   DB   : double-buffered 2-phase pipeline
//   HALFN: 128x64 tile, 4 waves x 32 rows, acc 2x4; else 128x128, 2x2 waves
// ---------------------------------------------------------------------------
template<bool ADD, bool GELU_, bool OUTBF, bool DB, bool HALFN>
__device__ __forceinline__ void gemm_body(
    const bf16_t* __restrict__ A, const bf16_t* __restrict__ Bw,
    const float* __restrict__ bias, void* __restrict__ Cv,
    int M, int N, int K, int lda, int ldb, int ldc)
{
    constexpr int BN  = HALFN ? 64 : 128;
    constexpr int BUF = HALFN ? 12288 : 16384;     // elements per buffer
    __shared__ bf16_t lds[(DB ? 2 : 1) * BUF];

    const int tid  = threadIdx.x;
    const int lane = tid & 63;
    const int w    = tid >> 6;
    const int row0 = blockIdx.x * 128;
    const int col0 = blockIdx.y * BN;

    const int row8 = lane >> 3;
    const int sch  = (lane & 7) ^ row8;
    const int fr   = lane & 15;
    const int g    = lane >> 4;

    const int aRowB = row0 + w * 32;
    const int bRowB = HALFN ? (col0 + w * 16) : (col0 + w * 32);

    constexpr int MR = HALFN ? 2 : 4;
    const int wr = HALFN ? w : (w >> 1);
    const int wc = HALFN ? 0 : (w & 1);

    f32x4 acc[MR][4];
#pragma unroll
    for (int m = 0; m < MR; ++m)
#pragma unroll
        for (int n = 0; n < 4; ++n)
            acc[m][n] = (f32x4){0.f, 0.f, 0.f, 0.f};

    auto STAGE = [&](int buf, int k0) {
        bf16_t* lb = lds + buf * BUF;
#pragma unroll
        for (int it = 0; it < 4; ++it) {
            const int ar = aRowB + it * 8 + row8;
            gload16(A + (size_t)ar * lda + k0 + sch * 8, lb + w * 2048 + it * 512);
        }
#pragma unroll
        for (int it = 0; it < (HALFN ? 2 : 4); ++it) {
            int br = bRowB + it * 8 + row8;
            if (br >= N) br = 0;
            gload16(Bw + (size_t)br * ldb + k0 + sch * 8,
                    lb + 8192 + w * (HALFN ? 1024 : 2048) + it * 512);
        }
    };

    auto COMPUTE = [&](int buf) {
        bf16_t* lb = lds + buf * BUF;
#pragma unroll
        for (int ks = 0; ks < 2; ++ks) {
            bf16x8 af[MR], bfr[4];
            const int cs = ks * 4 + g;
#pragma unroll
            for (int m = 0; m < MR; ++m) {
                const int row = (HALFN ? w * 32 : wr * 64) + m * 16 + fr;
                af[m] = *(const bf16x8*)&lb[row * 64 + ((cs ^ (fr & 7)) << 3)];
            }
#pragma unroll
            for (int n = 0; n < 4; ++n) {
                const int row = (HALFN ? 0 : wc * 64) + n * 16 + fr;
                bfr[n] = *(const bf16x8*)&lb[8192 + row * 64 + ((cs ^ (fr & 7)) << 3)];
            }
#pragma unroll
            for (int m = 0; m < MR; ++m)
#pragma unroll
                for (int n = 0; n < 4; ++n)
                    acc[m][n] = __builtin_amdgcn_mfma_f32_16x16x32_bf16(
                        af[m], bfr[n], acc[m][n], 0, 0, 0);
        }
    };

    const int nt = K >> 6;
    if (DB) {
        STAGE(0, 0);
        drain_and_barrier();
        int cur = 0;
        for (int t = 0; t < nt; ++t) {
            if (t + 1 < nt) STAGE(cur ^ 1, (t + 1) << 6);
            COMPUTE(cur);
            drain_and_barrier();
            cur ^= 1;
        }
    } else {
        for (int t = 0; t < nt; ++t) {
            STAGE(0, t << 6);
            __syncthreads();
            COMPUTE(0);
            __syncthreads();
        }
    }

    // epilogue: n innermost -> 4 consecutive stores fill each 128B row segment
    const int rBase = row0 + (HALFN ? w * 32 : wr * 64) + g * 4;
    const int cBase = col0 + (HALFN ? 0 : wc * 64) + fr;
    float bv[4];
#pragma unroll
    for (int n = 0; n < 4; ++n) {
        const int c = cBase + n * 16;
        bv[n] = (bias && c < N) ? bias[c] : 0.0f;
    }
#pragma unroll
    for (int m = 0; m < MR; ++m) {
#pragma unroll
        for (int r = 0; r < 4; ++r) {
            const int rr = rBase + m * 16 + r;
#pragma unroll
            for (int n = 0; n < 4; ++n) {
                const int c = cBase + n * 16;
                if (c >= N) continue;
                float v = acc[m][n][r] + bv[n];
                if (GELU_) v = 0.5f * v * (1.0f + erff(v * 0.70710678118654752f));
                if (OUTBF) {
                    ((bf16_t*)Cv)[(size_t)rr * ldc + c] = (bf16_t)v;
                } else {
                    float* Cf = (float*)Cv;
                    const size_t idx = (size_t)rr * ldc + c;
                    if (ADD) v += Cf[idx];
                    Cf[idx] = v;
                }
            }
        }
    }
}

// distinct kernel names for profiler attribution
__global__ __launch_bounds__(256) void k_gemm_qkv(
    const bf16_t* A, const bf16_t* B, const float* bias, void* C,
    int M, int N, int K, int lda, int ldb, int ldc)
{ gemm_body<false, false, true, true, true>(A, B, bias, C, M, N, K, lda, ldb, ldc); }

__global__ __launch_bounds__(256) void k_gemm_oproj(
    const bf16_t* A, const bf16_t* B, const float* bias, void* C,
    int M, int N, int K, int lda, int ldb, int ldc)
{ gemm_body<true, false, false, true, true>(A, B, bias, C, M, N, K, lda, ldb, ldc); }

__global__ __launch_bounds__(256) void k_gemm_fc(
    const bf16_t* A, const bf16_t* B, const float* bias, void* C,
    int M, int N, int K, int lda, int ldb, int ldc)
{ gemm_body<false, true, true, true, true>(A, B, bias, C, M, N, K, lda, ldb, ldc); }

__global__ __launch_bounds__(256) void k_gemm_proj(
    const bf16_t* A, const bf16_t* B, const float* bias, void* C,
    int M, int N, int K, int lda, int ldb, int ldc)
{ gemm_body<true, false, false, true, true>(A, B, bias, C, M, N, K, lda, ldb, ldc); }

// ---------------------------------------------------------------------------
// LM head GEMM: 128x256 tile, single-buffer BK=64 (48KB LDS), 4 waves.
// Each wave: 64 rows x 128 cols = 32 MFMA frags, acc[4][8] (128 VGPR).
// ---------------------------------------------------------------------------
__global__ __launch_bounds__(256) void k_gemm_head(
    const bf16_t* __restrict__ A, const bf16_t* __restrict__ Bw,
    bf16_t* __restrict__ C, int M, int N, int K, int lda, int ldb, int ldc)
{
    __shared__ bf16_t lds[24576];           // A[128][64] @0, B[256][64] @8192

    const int tid  = threadIdx.x;
    const int lane = tid & 63;
    const int w    = tid >> 6;
    const int wr   = w >> 1, wc = w & 1;
    const int row0 = blockIdx.x * 128;
    const int col0 = blockIdx.y * 256;

    const int row8 = lane >> 3;
    const int sch  = (lane & 7) ^ row8;
    const int fr   = lane & 15;
    const int g    = lane >> 4;

    const int aRowB = row0 + w * 32;
    const int bRowB = col0 + w * 64;

    f32x4 acc[4][8];
#pragma unroll
    for (int m = 0; m < 4; ++m)
#pragma unroll
        for (int n = 0; n < 8; ++n)
            acc[m][n] = (f32x4){0.f, 0.f, 0.f, 0.f};

    for (int k0 = 0; k0 < K; k0 += 64) {
#pragma unroll
        for (int it = 0; it < 4; ++it) {
            const int ar = aRowB + it * 8 + row8;
            gload16(A + (size_t)ar * lda + k0 + sch * 8, lds + w * 2048 + it * 512);
        }
#pragma unroll
        for (int it = 0; it < 8; ++it) {
            int br = bRowB + it * 8 + row8;
            if (br >= N) br = 0;
            gload16(Bw + (size_t)br * ldb + k0 + sch * 8,
                    lds + 8192 + w * 4096 + it * 512);
        }
        __syncthreads();

#pragma unroll
        for (int ks = 0; ks < 2; ++ks) {
            const int cs = ks * 4 + g;
            bf16x8 af[4];
#pragma unroll
            for (int m = 0; m < 4; ++m) {
                const int row = wr * 64 + m * 16 + fr;
                af[m] = *(const bf16x8*)&lds[row * 64 + ((cs ^ (fr & 7)) << 3)];
            }
#pragma unroll
            for (int hf = 0; hf < 2; ++hf) {
                bf16x8 bfr[4];
#pragma unroll
                for (int n = 0; n < 4; ++n) {
                    const int row = hf * 128 + wc * 64 + n * 16 + fr;
                    bfr[n] = *(const bf16x8*)&lds[8192 + row * 64 + ((cs ^ (fr & 7)) << 3)];
                }
#pragma unroll
                for (int m = 0; m < 4; ++m)
#pragma unroll
                    for (int n = 0; n < 4; ++n)
                        acc[m][hf * 4 + n] = __builtin_amdgcn_mfma_f32_16x16x32_bf16(
                            af[m], bfr[n], acc[m][hf * 4 + n], 0, 0, 0);
            }
        }
        __syncthreads();
    }

    // epilogue: n innermost within each 128-col half -> 128B write merge
    const int rBase = row0 + wr * 64 + g * 4;
#pragma unroll
    for (int m = 0; m < 4; ++m) {
#pragma unroll
        for (int r = 0; r < 4; ++r) {
            const int rr = rBase + m * 16 + r;
#pragma unroll
            for (int hf = 0; hf < 2; ++hf) {
#pragma unroll
                for (int n = 0; n < 4; ++n) {
                    const int c = col0 + hf * 128 + wc * 64 + n * 16 + fr;
                    if (c < N)
                        C[(size_t)rr * ldc + c] = (bf16_t)acc[m][hf * 4 + n][r];
                }
            }
        }
    }
}

// ---------------------------------------------------------------------------
// Launcher
// ---------------------------------------------------------------------------
extern "C" void kernel_launch(void* const* d_in, const int* in_sizes, int n_in,
                              void* d_out, int out_size, void* d_ws, size_t ws_size,
                              hipStream_t stream)
{
    constexpr int B = 4, S = 512, D = 768, L = 12, V = 50257, H = 12, F = 3072;
    constexpr int M  = B * S;     // 2048
    constexpr int TD = 3 * D;     // 2304
    constexpr int BH = B * H;     // 48
    constexpr int Vp = 50264;     // V padded to multiple of 8

    const int*   x    = (const int*)  d_in[0];
    const float* emb  = (const float*)d_in[1];
    const float* pos  = (const float*)d_in[2];
    const float* ln1g = (const float*)d_in[3];
    const float* ln1b = (const float*)d_in[4];
    const float* wqkv = (const float*)d_in[5];
    const float* bqkv = (const float*)d_in[6];
    const float* wo   = (const float*)d_in[7];
    const float* bo   = (const float*)d_in[8];
    const float* ln2g = (const float*)d_in[9];
    const float* ln2b = (const float*)d_in[10];
    const float* wfc  = (const float*)d_in[11];
    const float* bfc  = (const float*)d_in[12];
    const float* wpr  = (const float*)d_in[13];
    const float* bpr  = (const float*)d_in[14];
    const float* lnfg = (const float*)d_in[15];
    const float* lnfb = (const float*)d_in[16];

    float* probs  = (float*)d_out;                    // [M, V]
    float* hidden = probs + (size_t)M * V;            // [M, D]

    // ---- workspace layout -------------------------------------------------
    float*  h      = (float*)d_ws;                    // [M,D] f32
    bf16_t* qkv_bf = (bf16_t*)(h + (size_t)M * D);    // [M,TD]
    bf16_t* vT     = qkv_bf + (size_t)M * TD;         // [BH,64,S]
    bf16_t* xn_bf  = vT     + (size_t)BH * 64 * S;    // [M,D]
    bf16_t* o_bf   = xn_bf  + (size_t)M * D;          // [M,D]
    bf16_t* mid_bf = o_bf   + (size_t)M * D;          // [M,F]
    bf16_t* wqkvT  = mid_bf + (size_t)M * F;          // [L,TD,D]
    bf16_t* woT    = wqkvT  + (size_t)L * D * TD;     // [L,D,D]
    bf16_t* wfcT   = woT    + (size_t)L * D * D;      // [L,F,D]
    bf16_t* wprT   = wfcT   + (size_t)L * D * F;      // [L,D,F]
    bf16_t* hid_bf = wprT   + (size_t)L * F * D;      // [M,D]   (live at end)
    bf16_t* embB   = hid_bf + (size_t)M * D;          // [V,D]   (live at end)
    bf16_t* logits = (bf16_t*)d_ws;                   // [M,Vp] alias (h dead)

    // ---- weight prep ------------------------------------------------------
    convert_bf16<<<2048, 256, 0, stream>>>(emb, embB, (V * D) / 4);
    transpose_to_bf16<<<dim3(TD / 32, D / 32, L), dim3(32, 8), 0, stream>>>(wqkv, wqkvT, D, TD);
    transpose_to_bf16<<<dim3(D / 32,  D / 32, L), dim3(32, 8), 0, stream>>>(wo,   woT,   D, D);
    transpose_to_bf16<<<dim3(F / 32,  D / 32, L), dim3(32, 8), 0, stream>>>(wfc,  wfcT,  D, F);
    transpose_to_bf16<<<dim3(D / 32,  F / 32, L), dim3(32, 8), 0, stream>>>(wpr,  wprT,  F, D);

    // ---- embedding
    embed_kernel<<<dim3((M * D + 255) / 256), 256, 0, stream>>>(x, emb, pos, h, S, D, M * D);

    for (int i = 0; i < L; ++i) {
        layernorm_dual<<<M, 256, 0, stream>>>(h, ln1g + (size_t)i * D, ln1b + (size_t)i * D,
                                              xn_bf, nullptr, D);

        k_gemm_qkv<<<dim3(M / 128, TD / 64), 256, 0, stream>>>(
            xn_bf, wqkvT + (size_t)i * D * TD, bqkv + (size_t)i * TD, qkv_bf,
            M, TD, D, D, D, TD);

        transpose_v<<<dim3(S / 64, BH), 256, 0, stream>>>(qkv_bf, vT);

        flash_attn<<<dim3(S / 128, BH), 256, 0, stream>>>(qkv_bf, vT, o_bf);

        k_gemm_oproj<<<dim3(M / 128, D / 64), 256, 0, stream>>>(
            o_bf, woT + (size_t)i * D * D, bo + (size_t)i * D, h,
            M, D, D, D, D, D);

        layernorm_dual<<<M, 256, 0, stream>>>(h, ln2g + (size_t)i * D, ln2b + (size_t)i * D,
                                              xn_bf, nullptr, D);

        k_gemm_fc<<<dim3(M / 128, F / 64), 256, 0, stream>>>(
            xn_bf, wfcT + (size_t)i * D * F, bfc + (size_t)i * F, mid_bf,
            M, F, D, D, D, F);

        k_gemm_proj<<<dim3(M / 128, D / 64), 256, 0, stream>>>(
            mid_bf, wprT + (size_t)i * F * D, bpr + (size_t)i * D, h,
            M, D, F, F, F, D);
    }

    layernorm_dual<<<M, 256, 0, stream>>>(h, lnfg, lnfb, hid_bf, hidden, D);

    k_gemm_head<<<dim3(M / 128, (V + 255) / 256), 256, 0, stream>>>(
        hid_bf, embB, logits,
        M, V, D, D, D, Vp);

    softmax_vocab<<<M, 256, 0, stream>>>(logits, probs, V, Vp);
}

// Round 9
// 2163.921 us; speedup vs baseline: 6.4760x; 1.0954x over previous
//
#include <hip/hip_runtime.h>
#include <hip/hip_bf16.h>

typedef __bf16 bf16_t;
typedef bf16_t bf16x8 __attribute__((ext_vector_type(8)));
typedef float  f32x4  __attribute__((ext_vector_type(4)));

// ---------------------------------------------------------------------------
// global -> LDS async copy, 16B per lane. lds base must be wave-uniform.
// ---------------------------------------------------------------------------
__device__ __forceinline__ void gload16(const void* g, void* l) {
    __builtin_amdgcn_global_load_lds(
        (const __attribute__((address_space(1))) unsigned int*)g,
        (__attribute__((address_space(3))) unsigned int*)l, 16, 0, 0);
}

__device__ __forceinline__ void drain_and_barrier() {
    __builtin_amdgcn_sched_barrier(0);
    asm volatile("s_waitcnt vmcnt(0)" ::: "memory");
    __builtin_amdgcn_s_barrier();
    __builtin_amdgcn_sched_barrier(0);
}

// ---------------------------------------------------------------------------
// Embedding: h[b,s,:] = emb[x[b,s],:] + posemb[s,:]
// ---------------------------------------------------------------------------
__global__ void embed_kernel(const int* __restrict__ x,
                             const float* __restrict__ emb,
                             const float* __restrict__ pos,
                             float* __restrict__ h,
                             int S, int D, int total)
{
    int i = blockIdx.x * blockDim.x + threadIdx.x;
    if (i >= total) return;
    int d  = i % D;
    int bs = i / D;
    int s  = bs % S;
    h[i] = emb[(long long)x[bs] * D + d] + pos[(long long)s * D + d];
}

// ---------------------------------------------------------------------------
// elementwise f32 -> bf16 (vectorized by 4)
// ---------------------------------------------------------------------------
__global__ void convert_bf16(const float* __restrict__ in, bf16_t* __restrict__ out, int n4)
{
    int i = blockIdx.x * blockDim.x + threadIdx.x;
    for (; i < n4; i += gridDim.x * blockDim.x) {
        float4 v = ((const float4*)in)[i];
        bf16_t* o = out + (size_t)i * 4;
        o[0] = (bf16_t)v.x; o[1] = (bf16_t)v.y; o[2] = (bf16_t)v.z; o[3] = (bf16_t)v.w;
    }
}

// ---------------------------------------------------------------------------
// Batched transpose + bf16 convert: out[z][n][k] = (bf16) in[z][k][n]
// ---------------------------------------------------------------------------
__global__ __launch_bounds__(256) void transpose_to_bf16(
    const float* __restrict__ in, bf16_t* __restrict__ out, int K, int N)
{
    const float* ip = in  + (size_t)blockIdx.z * K * N;
    bf16_t*      op = out + (size_t)blockIdx.z * K * N;
    __shared__ float t[32][33];
    const int n0 = blockIdx.x * 32, k0 = blockIdx.y * 32;
    const int tx = threadIdx.x, ty = threadIdx.y;
#pragma unroll
    for (int u = 0; u < 4; ++u)
        t[ty + u * 8][tx] = ip[(size_t)(k0 + ty + u * 8) * N + (n0 + tx)];
    __syncthreads();
#pragma unroll
    for (int u = 0; u < 4; ++u)
        op[(size_t)(n0 + ty + u * 8) * K + (k0 + tx)] = (bf16_t)t[tx][ty + u * 8];
}

// ---------------------------------------------------------------------------
// LayerNorm rows of D=768; writes bf16 (always) and f32 (if Yf != nullptr).
// ---------------------------------------------------------------------------
__global__ __launch_bounds__(256) void layernorm_dual(
    const float* __restrict__ X, const float* __restrict__ g,
    const float* __restrict__ b, bf16_t* __restrict__ Yb,
    float* __restrict__ Yf, int D)
{
    const int row = blockIdx.x;
    const float* xr = X + (long long)row * D;
    const int tid = threadIdx.x;

    float vals[3];
    float s = 0.0f;
#pragma unroll
    for (int u = 0; u < 3; ++u) { vals[u] = xr[tid + u * 256]; s += vals[u]; }

    __shared__ float red[256];
    red[tid] = s;
    __syncthreads();
    for (int off = 128; off > 0; off >>= 1) {
        if (tid < off) red[tid] += red[tid + off];
        __syncthreads();
    }
    const float mean = red[0] / (float)D;
    __syncthreads();

    float vs = 0.0f;
#pragma unroll
    for (int u = 0; u < 3; ++u) { float d = vals[u] - mean; vs += d * d; }
    red[tid] = vs;
    __syncthreads();
    for (int off = 128; off > 0; off >>= 1) {
        if (tid < off) red[tid] += red[tid + off];
        __syncthreads();
    }
    const float var  = red[0] / (float)D;
    const float rstd = rsqrtf(var + 1e-6f);

#pragma unroll
    for (int u = 0; u < 3; ++u) {
        const int c = tid + u * 256;
        const float y = (vals[u] - mean) * rstd * g[c] + b[c];
        Yb[(long long)row * D + c] = (bf16_t)y;
        if (Yf) Yf[(long long)row * D + c] = y;
    }
}

// ---------------------------------------------------------------------------
// Fused flash attention (causal, hd=64, S=512), 2-phase K/V pipeline.
// V is reg-staged straight from qkv (no vT buffer): each thread owns one key
// row (key = lane) and dchunks w*2+{0,1}; after compute it scatters 16
// ds_write_b16 into the swizzled vS layout the PV loop reads (conflict-free:
// 64 distinct keys per write instruction cover all 32 banks).
// ---------------------------------------------------------------------------
__global__ __launch_bounds__(256) void flash_attn(
    const bf16_t* __restrict__ qkv, bf16_t* __restrict__ o)
{
    constexpr int S = 512, TD = 2304, D = 768, H = 12;
    const int qt = blockIdx.x;
    const int z  = blockIdx.y;
    const int bb = z / H, hh = z - bb * H;
    const int tid = threadIdx.x, lane = tid & 63, w = tid >> 6;
    const int fr = lane & 15, g = lane >> 4, sub = g * 8;

    __shared__ bf16_t kS[2][4096];       // K tile [64 key][64 k], chunk-swizzled
    __shared__ bf16_t vS[2][4096];       // V^T tile [64 d][64 key], chunk-swizzled
    __shared__ bf16_t pS[4][32 * 72];    // per-wave P [32 q][64 key], padded

    bf16x8 qf[2][2];
    const bf16_t* qbase = qkv + (size_t)(bb * S + qt * 128 + w * 32) * TD + hh * 64;
#pragma unroll
    for (int m = 0; m < 2; ++m)
#pragma unroll
        for (int ks = 0; ks < 2; ++ks) {
            bf16x8 v = *(const bf16x8*)&qbase[(size_t)(m * 16 + fr) * TD + ks * 32 + sub];
#pragma unroll
            for (int j = 0; j < 8; ++j) v[j] = v[j] * (bf16_t)0.125f;
            qf[m][ks] = v;
        }

    f32x4 oacc[2][4];
    float mrun[2][4], lrun[2][4];
#pragma unroll
    for (int m = 0; m < 2; ++m)
#pragma unroll
        for (int r = 0; r < 4; ++r) { mrun[m][r] = -3.0e38f; lrun[m][r] = 0.0f; }
#pragma unroll
    for (int m = 0; m < 2; ++m)
#pragma unroll
        for (int n = 0; n < 4; ++n)
            oacc[m][n] = (f32x4){0.f, 0.f, 0.f, 0.f};

    int qr[2][4];
#pragma unroll
    for (int m = 0; m < 2; ++m)
#pragma unroll
        for (int r = 0; r < 4; ++r)
            qr[m][r] = qt * 128 + w * 32 + m * 16 + g * 4 + r;

    const int srow8  = lane >> 3;
    const int schunk = (lane & 7) ^ (srow8 & 7);

    const bf16_t* kGbase = qkv + (size_t)(bb * S) * TD + D + hh * 64;
    const bf16_t* vGbase = qkv + (size_t)(bb * S) * TD + 2 * D + hh * 64;
    const int nkv = 2 * qt + 2;

    bf16x8 vreg[2];

    // issue next K tile (global_load_lds) + V rows (to regs)
#define STAGE_ISSUE(buf, t)                                                     \
    {                                                                           \
        _Pragma("unroll")                                                       \
        for (int it = 0; it < 2; ++it) {                                        \
            const int row = it * 32 + w * 8 + srow8;                            \
            gload16(kGbase + (size_t)((t) * 64 + row) * TD + schunk * 8,        \
                    &kS[buf][it * 2048 + w * 512]);                             \
        }                                                                       \
        _Pragma("unroll")                                                       \
        for (int it = 0; it < 2; ++it) {                                        \
            const int dch = w * 2 + it;                                         \
            vreg[it] = *(const bf16x8*)&vGbase[(size_t)((t) * 64 + lane) * TD + dch * 8]; \
        }                                                                       \
    }
    // scatter V regs into swizzled vS[d][key-chunk ^ (d&7)][key&7]
#define STAGE_WRITE(buf)                                                        \
    {                                                                           \
        _Pragma("unroll")                                                       \
        for (int it = 0; it < 2; ++it) {                                        \
            const int dch = w * 2 + it;                                         \
            _Pragma("unroll")                                                   \
            for (int j = 0; j < 8; ++j) {                                       \
                const int d = dch * 8 + j;                                      \
                vS[buf][d * 64 + (((lane >> 3) ^ j) << 3) + (lane & 7)] = vreg[it][j]; \
            }                                                                   \
        }                                                                       \
    }

    STAGE_ISSUE(0, 0);
    STAGE_WRITE(0);
    __syncthreads();

    int cur = 0;
    for (int t = 0; t < nkv; ++t) {
        if (t + 1 < nkv) STAGE_ISSUE(cur ^ 1, t + 1);

        f32x4 sacc[2][4];
#pragma unroll
        for (int m = 0; m < 2; ++m)
#pragma unroll
            for (int n = 0; n < 4; ++n)
                sacc[m][n] = (f32x4){0.f, 0.f, 0.f, 0.f};
#pragma unroll
        for (int ks = 0; ks < 2; ++ks) {
            bf16x8 bK[4];
#pragma unroll
            for (int n = 0; n < 4; ++n) {
                const int rw = n * 16 + fr;
                const int c  = ks * 4 + g;
                bK[n] = *(const bf16x8*)&kS[cur][rw * 64 + ((c ^ (rw & 7)) << 3)];
            }
#pragma unroll
            for (int m = 0; m < 2; ++m)
#pragma unroll
                for (int n = 0; n < 4; ++n)
                    sacc[m][n] = __builtin_amdgcn_mfma_f32_16x16x32_bf16(
                        qf[m][ks], bK[n], sacc[m][n], 0, 0, 0);
        }

        if (t >= 2 * qt) {
#pragma unroll
            for (int m = 0; m < 2; ++m)
#pragma unroll
                for (int n = 0; n < 4; ++n) {
                    const int key = t * 64 + n * 16 + fr;
#pragma unroll
                    for (int r = 0; r < 4; ++r)
                        if (key > qr[m][r]) sacc[m][n][r] = -3.0e38f;
                }
        }

        float sf[2][4], rs[2][4];
#pragma unroll
        for (int m = 0; m < 2; ++m)
#pragma unroll
            for (int r = 0; r < 4; ++r) {
                float v = fmaxf(fmaxf(sacc[m][0][r], sacc[m][1][r]),
                                fmaxf(sacc[m][2][r], sacc[m][3][r]));
#pragma unroll
                for (int off = 1; off < 16; off <<= 1)
                    v = fmaxf(v, __shfl_xor(v, off));
                const float mn = fmaxf(mrun[m][r], v);
                sf[m][r] = __expf(mrun[m][r] - mn);
                mrun[m][r] = mn;
                lrun[m][r] *= sf[m][r];
            }
#pragma unroll
        for (int m = 0; m < 2; ++m)
#pragma unroll
            for (int n = 0; n < 4; ++n)
#pragma unroll
                for (int r = 0; r < 4; ++r)
                    oacc[m][n][r] *= sf[m][r];
#pragma unroll
        for (int m = 0; m < 2; ++m)
#pragma unroll
            for (int r = 0; r < 4; ++r) rs[m][r] = 0.0f;
#pragma unroll
        for (int m = 0; m < 2; ++m)
#pragma unroll
            for (int n = 0; n < 4; ++n)
#pragma unroll
                for (int r = 0; r < 4; ++r) {
                    const float p = __expf(sacc[m][n][r] - mrun[m][r]);
                    sacc[m][n][r] = p;
                    rs[m][r] += p;
                }
#pragma unroll
        for (int m = 0; m < 2; ++m)
#pragma unroll
            for (int r = 0; r < 4; ++r) {
                float v = rs[m][r];
#pragma unroll
                for (int off = 1; off < 16; off <<= 1) v += __shfl_xor(v, off);
                lrun[m][r] += v;
            }

        bf16_t* pw = pS[w];
#pragma unroll
        for (int m = 0; m < 2; ++m)
#pragma unroll
            for (int n = 0; n < 4; ++n)
#pragma unroll
                for (int r = 0; r < 4; ++r)
                    pw[(m * 16 + g * 4 + r) * 72 + n * 16 + fr] = (bf16_t)sacc[m][n][r];

#pragma unroll
        for (int ks = 0; ks < 2; ++ks) {
            bf16x8 pa[2], vb[4];
#pragma unroll
            for (int m = 0; m < 2; ++m)
                pa[m] = *(const bf16x8*)&pw[(m * 16 + fr) * 72 + ks * 32 + sub];
#pragma unroll
            for (int n = 0; n < 4; ++n) {
                const int rw = n * 16 + fr;
                const int c  = ks * 4 + g;
                vb[n] = *(const bf16x8*)&vS[cur][rw * 64 + ((c ^ (rw & 7)) << 3)];
            }
#pragma unroll
            for (int m = 0; m < 2; ++m)
#pragma unroll
                for (int n = 0; n < 4; ++n)
                    oacc[m][n] = __builtin_amdgcn_mfma_f32_16x16x32_bf16(
                        pa[m], vb[n], oacc[m][n], 0, 0, 0);
        }

        if (t + 1 < nkv) STAGE_WRITE(cur ^ 1);   // compiler waits vreg deps
        __syncthreads();                          // drains vmcnt+lgkm, barrier
        cur ^= 1;
    }
#undef STAGE_ISSUE
#undef STAGE_WRITE

    bf16_t* obase = o + (size_t)(bb * S + qt * 128 + w * 32) * D + hh * 64;
#pragma unroll
    for (int m = 0; m < 2; ++m)
#pragma unroll
        for (int r = 0; r < 4; ++r) {
            const float inv = 1.0f / lrun[m][r];
#pragma unroll
            for (int n = 0; n < 4; ++n)
                obase[(size_t)(m * 16 + g * 4 + r) * D + n * 16 + fr] =
                    (bf16_t)(oacc[m][n][r] * inv);
        }
}

// ---------------------------------------------------------------------------
// Vocab softmax: bf16 logits (stride Vp) -> f32 probs (stride V).
// ---------------------------------------------------------------------------
__global__ __launch_bounds__(256) void softmax_vocab(
    const bf16_t* __restrict__ logits, float* __restrict__ probs, int V, int Vp)
{
    const int tid = threadIdx.x;
    const bf16_t* lr = logits + (size_t)blockIdx.x * Vp;
    float* pr = probs + (size_t)blockIdx.x * V;
    const int n8 = V >> 3;

    float m = -3.0e38f, s = 0.0f;
    for (int c8 = tid; c8 < n8; c8 += 256) {
        const bf16x8 v = *(const bf16x8*)(lr + (size_t)c8 * 8);
        float f[8], lm = -3.0e38f;
#pragma unroll
        for (int j = 0; j < 8; ++j) { f[j] = (float)v[j]; lm = fmaxf(lm, f[j]); }
        if (lm > m) { s *= __expf(m - lm); m = lm; }
#pragma unroll
        for (int j = 0; j < 8; ++j) s += __expf(f[j] - m);
    }
    for (int c = n8 * 8 + tid; c < V; c += 256) {
        const float f = (float)lr[c];
        if (f > m) { s *= __expf(m - f); m = f; }
        s += __expf(f - m);
    }

    __shared__ float mS[256], sS[256];
    mS[tid] = m; sS[tid] = s;
    __syncthreads();
    for (int off = 128; off > 0; off >>= 1) {
        if (tid < off) {
            const float m1 = mS[tid], m2 = mS[tid + off];
            const float M_ = fmaxf(m1, m2);
            sS[tid] = sS[tid] * __expf(m1 - M_) + sS[tid + off] * __expf(m2 - M_);
            mS[tid] = M_;
        }
        __syncthreads();
    }
    const float M_  = mS[0];
    const float inv = 1.0f / sS[0];

    for (int c8 = tid; c8 < n8; c8 += 256) {
        const bf16x8 v = *(const bf16x8*)(lr + (size_t)c8 * 8);
#pragma unroll
        for (int j = 0; j < 8; ++j)
            pr[(size_t)c8 * 8 + j] = __expf((float)v[j] - M_) * inv;
    }
    for (int c = n8 * 8 + tid; c < V; c += 256)
        pr[c] = __expf((float)lr[c] - M_) * inv;
}

// ---------------------------------------------------------------------------
// bf16 MFMA GEMM body (layer GEMMs): C[M, tile] = A @ B^T + bias
//   DB   : double-buffered 2-phase pipeline
//   HALFN: 128x64 tile, 4 waves x 32 rows, acc 2x4; else 128x128, 2x2 waves
// ---------------------------------------------------------------------------
template<bool ADD, bool GELU_, bool OUTBF, bool DB, bool HALFN>
__device__ __forceinline__ void gemm_body(
    const bf16_t* __restrict__ A, const bf16_t* __restrict__ Bw,
    const float* __restrict__ bias, void* __restrict__ Cv,
    int M, int N, int K, int lda, int ldb, int ldc)
{
    constexpr int BN  = HALFN ? 64 : 128;
    constexpr int BUF = HALFN ? 12288 : 16384;     // elements per buffer
    __shared__ bf16_t lds[(DB ? 2 : 1) * BUF];

    const int tid  = threadIdx.x;
    const int lane = tid & 63;
    const int w    = tid >> 6;
    const int row0 = blockIdx.x * 128;
    const int col0 = blockIdx.y * BN;

    const int row8 = lane >> 3;
    const int sch  = (lane & 7) ^ row8;
    const int fr   = lane & 15;
    const int g    = lane >> 4;

    const int aRowB = row0 + w * 32;
    const int bRowB = HALFN ? (col0 + w * 16) : (col0 + w * 32);

    constexpr int MR = HALFN ? 2 : 4;
    const int wr = HALFN ? w : (w >> 1);
    const int wc = HALFN ? 0 : (w & 1);

    f32x4 acc[MR][4];
#pragma unroll
    for (int m = 0; m < MR; ++m)
#pragma unroll
        for (int n = 0; n < 4; ++n)
            acc[m][n] = (f32x4){0.f, 0.f, 0.f, 0.f};

    auto STAGE = [&](int buf, int k0) {
        bf16_t* lb = lds + buf * BUF;
#pragma unroll
        for (int it = 0; it < 4; ++it) {
            const int ar = aRowB + it * 8 + row8;
            gload16(A + (size_t)ar * lda + k0 + sch * 8, lb + w * 2048 + it * 512);
        }
#pragma unroll
        for (int it = 0; it < (HALFN ? 2 : 4); ++it) {
            int br = bRowB + it * 8 + row8;
            if (br >= N) br = 0;
            gload16(Bw + (size_t)br * ldb + k0 + sch * 8,
                    lb + 8192 + w * (HALFN ? 1024 : 2048) + it * 512);
        }
    };

    auto COMPUTE = [&](int buf) {
        bf16_t* lb = lds + buf * BUF;
#pragma unroll
        for (int ks = 0; ks < 2; ++ks) {
            bf16x8 af[MR], bfr[4];
            const int cs = ks * 4 + g;
#pragma unroll
            for (int m = 0; m < MR; ++m) {
                const int row = (HALFN ? w * 32 : wr * 64) + m * 16 + fr;
                af[m] = *(const bf16x8*)&lb[row * 64 + ((cs ^ (fr & 7)) << 3)];
            }
#pragma unroll
            for (int n = 0; n < 4; ++n) {
                const int row = (HALFN ? 0 : wc * 64) + n * 16 + fr;
                bfr[n] = *(const bf16x8*)&lb[8192 + row * 64 + ((cs ^ (fr & 7)) << 3)];
            }
#pragma unroll
            for (int m = 0; m < MR; ++m)
#pragma unroll
                for (int n = 0; n < 4; ++n)
                    acc[m][n] = __builtin_amdgcn_mfma_f32_16x16x32_bf16(
                        af[m], bfr[n], acc[m][n], 0, 0, 0);
        }
    };

    const int nt = K >> 6;
    if (DB) {
        STAGE(0, 0);
        drain_and_barrier();
        int cur = 0;
        for (int t = 0; t < nt; ++t) {
            if (t + 1 < nt) STAGE(cur ^ 1, (t + 1) << 6);
            COMPUTE(cur);
            drain_and_barrier();
            cur ^= 1;
        }
    } else {
        for (int t = 0; t < nt; ++t) {
            STAGE(0, t << 6);
            __syncthreads();
            COMPUTE(0);
            __syncthreads();
        }
    }

    // epilogue: n innermost -> 4 consecutive stores fill each 128B row segment
    const int rBase = row0 + (HALFN ? w * 32 : wr * 64) + g * 4;
    const int cBase = col0 + (HALFN ? 0 : wc * 64) + fr;
    float bv[4];
#pragma unroll
    for (int n = 0; n < 4; ++n) {
        const int c = cBase + n * 16;
        bv[n] = (bias && c < N) ? bias[c] : 0.0f;
    }
#pragma unroll
    for (int m = 0; m < MR; ++m) {
#pragma unroll
        for (int r = 0; r < 4; ++r) {
            const int rr = rBase + m * 16 + r;
#pragma unroll
            for (int n = 0; n < 4; ++n) {
                const int c = cBase + n * 16;
                if (c >= N) continue;
                float v = acc[m][n][r] + bv[n];
                if (GELU_) v = 0.5f * v * (1.0f + erff(v * 0.70710678118654752f));
                if (OUTBF) {
                    ((bf16_t*)Cv)[(size_t)rr * ldc + c] = (bf16_t)v;
                } else {
                    float* Cf = (float*)Cv;
                    const size_t idx = (size_t)rr * ldc + c;
                    if (ADD) v += Cf[idx];
                    Cf[idx] = v;
                }
            }
        }
    }
}

// distinct kernel names for profiler attribution
__global__ __launch_bounds__(256) void k_gemm_qkv(
    const bf16_t* A, const bf16_t* B, const float* bias, void* C,
    int M, int N, int K, int lda, int ldb, int ldc)
{ gemm_body<false, false, true, true, true>(A, B, bias, C, M, N, K, lda, ldb, ldc); }

__global__ __launch_bounds__(256) void k_gemm_oproj(
    const bf16_t* A, const bf16_t* B, const float* bias, void* C,
    int M, int N, int K, int lda, int ldb, int ldc)
{ gemm_body<true, false, false, true, true>(A, B, bias, C, M, N, K, lda, ldb, ldc); }

__global__ __launch_bounds__(256) void k_gemm_fc(
    const bf16_t* A, const bf16_t* B, const float* bias, void* C,
    int M, int N, int K, int lda, int ldb, int ldc)
{ gemm_body<false, true, true, true, true>(A, B, bias, C, M, N, K, lda, ldb, ldc); }

__global__ __launch_bounds__(256) void k_gemm_proj(
    const bf16_t* A, const bf16_t* B, const float* bias, void* C,
    int M, int N, int K, int lda, int ldb, int ldc)
{ gemm_body<true, false, false, true, true>(A, B, bias, C, M, N, K, lda, ldb, ldc); }

// ---------------------------------------------------------------------------
// LM head GEMM: measured-best config (round-4): 128x128 tile, BK=64,
// single-buffer 32KB LDS, 4 waves 2x2, n-outer epilogue. ~80 VGPR.
// ---------------------------------------------------------------------------
__global__ __launch_bounds__(256) void k_gemm_head(
    const bf16_t* __restrict__ A, const bf16_t* __restrict__ Bw,
    bf16_t* __restrict__ C, int M, int N, int K, int lda, int ldb, int ldc)
{
    __shared__ bf16_t lds[16384];           // A [128][64] @0, B [128][64] @8192

    const int tid  = threadIdx.x;
    const int lane = tid & 63;
    const int w    = tid >> 6;
    const int wr   = w >> 1, wc = w & 1;
    const int row0 = blockIdx.x * 128;
    const int col0 = blockIdx.y * 128;

    const int row8 = lane >> 3;
    const int sch  = (lane & 7) ^ row8;
    const int fr   = lane & 15;
    const int g    = lane >> 4;

    const int aRowB = row0 + w * 32;
    const int bRowB = col0 + w * 32;

    f32x4 acc[4][4];
#pragma unroll
    for (int m = 0; m < 4; ++m)
#pragma unroll
        for (int n = 0; n < 4; ++n)
            acc[m][n] = (f32x4){0.f, 0.f, 0.f, 0.f};

    for (int k0 = 0; k0 < K; k0 += 64) {
#pragma unroll
        for (int it = 0; it < 4; ++it) {
            const int ar = aRowB + it * 8 + row8;
            gload16(A + (size_t)ar * lda + k0 + sch * 8,
                    lds + w * 2048 + it * 512);
            int br = bRowB + it * 8 + row8;
            if (br >= N) br = 0;
            gload16(Bw + (size_t)br * ldb + k0 + sch * 8,
                    lds + 8192 + w * 2048 + it * 512);
        }
        __syncthreads();

#pragma unroll
        for (int ks = 0; ks < 2; ++ks) {
            bf16x8 af[4], bfr[4];
            const int cs = ks * 4 + g;
#pragma unroll
            for (int m = 0; m < 4; ++m) {
                const int row = wr * 64 + m * 16 + fr;
                af[m] = *(const bf16x8*)&lds[row * 64 + ((cs ^ (fr & 7)) << 3)];
            }
#pragma unroll
            for (int n = 0; n < 4; ++n) {
                const int row = wc * 64 + n * 16 + fr;
                bfr[n] = *(const bf16x8*)&lds[8192 + row * 64 + ((cs ^ (fr & 7)) << 3)];
            }
#pragma unroll
            for (int m = 0; m < 4; ++m)
#pragma unroll
                for (int n = 0; n < 4; ++n)
                    acc[m][n] = __builtin_amdgcn_mfma_f32_16x16x32_bf16(
                        af[m], bfr[n], acc[m][n], 0, 0, 0);
        }
        __syncthreads();
    }

    const int rBase = row0 + wr * 64 + g * 4;
    const int cBase = col0 + wc * 64 + fr;
#pragma unroll
    for (int n = 0; n < 4; ++n) {
        const int c = cBase + n * 16;
        if (c >= N) continue;
#pragma unroll
        for (int m = 0; m < 4; ++m)
#pragma unroll
            for (int r = 0; r < 4; ++r)
                C[(size_t)(rBase + m * 16 + r) * ldc + c] = (bf16_t)acc[m][n][r];
    }
}

// ---------------------------------------------------------------------------
// Launcher
// ---------------------------------------------------------------------------
extern "C" void kernel_launch(void* const* d_in, const int* in_sizes, int n_in,
                              void* d_out, int out_size, void* d_ws, size_t ws_size,
                              hipStream_t stream)
{
    constexpr int B = 4, S = 512, D = 768, L = 12, V = 50257, H = 12, F = 3072;
    constexpr int M  = B * S;     // 2048
    constexpr int TD = 3 * D;     // 2304
    constexpr int BH = B * H;     // 48
    constexpr int Vp = 50264;     // V padded to multiple of 8

    const int*   x    = (const int*)  d_in[0];
    const float* emb  = (const float*)d_in[1];
    const float* pos  = (const float*)d_in[2];
    const float* ln1g = (const float*)d_in[3];
    const float* ln1b = (const float*)d_in[4];
    const float* wqkv = (const float*)d_in[5];
    const float* bqkv = (const float*)d_in[6];
    const float* wo   = (const float*)d_in[7];
    const float* bo   = (const float*)d_in[8];
    const float* ln2g = (const float*)d_in[9];
    const float* ln2b = (const float*)d_in[10];
    const float* wfc  = (const float*)d_in[11];
    const float* bfc  = (const float*)d_in[12];
    const float* wpr  = (const float*)d_in[13];
    const float* bpr  = (const float*)d_in[14];
    const float* lnfg = (const float*)d_in[15];
    const float* lnfb = (const float*)d_in[16];

    float* probs  = (float*)d_out;                    // [M, V]
    float* hidden = probs + (size_t)M * V;            // [M, D]

    // ---- workspace layout -------------------------------------------------
    float*  h      = (float*)d_ws;                    // [M,D] f32
    bf16_t* qkv_bf = (bf16_t*)(h + (size_t)M * D);    // [M,TD]
    bf16_t* xn_bf  = qkv_bf + (size_t)M * TD;         // [M,D]
    bf16_t* o_bf   = xn_bf  + (size_t)M * D;          // [M,D]
    bf16_t* mid_bf = o_bf   + (size_t)M * D;          // [M,F]
    bf16_t* wqkvT  = mid_bf + (size_t)M * F;          // [L,TD,D]
    bf16_t* woT    = wqkvT  + (size_t)L * D * TD;     // [L,D,D]
    bf16_t* wfcT   = woT    + (size_t)L * D * D;      // [L,F,D]
    bf16_t* wprT   = wfcT   + (size_t)L * D * F;      // [L,D,F]
    bf16_t* hid_bf = wprT   + (size_t)L * F * D;      // [M,D]   (live at end)
    bf16_t* embB   = hid_bf + (size_t)M * D;          // [V,D]   (live at end)
    bf16_t* logits = (bf16_t*)d_ws;                   // [M,Vp] alias (h dead)

    // ---- weight prep ------------------------------------------------------
    convert_bf16<<<2048, 256, 0, stream>>>(emb, embB, (V * D) / 4);
    transpose_to_bf16<<<dim3(TD / 32, D / 32, L), dim3(32, 8), 0, stream>>>(wqkv, wqkvT, D, TD);
    transpose_to_bf16<<<dim3(D / 32,  D / 32, L), dim3(32, 8), 0, stream>>>(wo,   woT,   D, D);
    transpose_to_bf16<<<dim3(F / 32,  D / 32, L), dim3(32, 8), 0, stream>>>(wfc,  wfcT,  D, F);
    transpose_to_bf16<<<dim3(D / 32,  F / 32, L), dim3(32, 8), 0, stream>>>(wpr,  wprT,  F, D);

    // ---- embedding
    embed_kernel<<<dim3((M * D + 255) / 256), 256, 0, stream>>>(x, emb, pos, h, S, D, M * D);

    for (int i = 0; i < L; ++i) {
        layernorm_dual<<<M, 256, 0, stream>>>(h, ln1g + (size_t)i * D, ln1b + (size_t)i * D,
                                              xn_bf, nullptr, D);

        k_gemm_qkv<<<dim3(M / 128, TD / 64), 256, 0, stream>>>(
            xn_bf, wqkvT + (size_t)i * D * TD, bqkv + (size_t)i * TD, qkv_bf,
            M, TD, D, D, D, TD);

        flash_attn<<<dim3(S / 128, BH), 256, 0, stream>>>(qkv_bf, o_bf);

        k_gemm_oproj<<<dim3(M / 128, D / 64), 256, 0, stream>>>(
            o_bf, woT + (size_t)i * D * D, bo + (size_t)i * D, h,
            M, D, D, D, D, D);

        layernorm_dual<<<M, 256, 0, stream>>>(h, ln2g + (size_t)i * D, ln2b + (size_t)i * D,
                                              xn_bf, nullptr, D);

        k_gemm_fc<<<dim3(M / 128, F / 64), 256, 0, stream>>>(
            xn_bf, wfcT + (size_t)i * D * F, bfc + (size_t)i * F, mid_bf,
            M, F, D, D, D, F);

        k_gemm_proj<<<dim3(M / 128, D / 64), 256, 0, stream>>>(
            mid_bf, wprT + (size_t)i * F * D, bpr + (size_t)i * D, h,
            M, D, F, F, F, D);
    }

    layernorm_dual<<<M, 256, 0, stream>>>(h, lnfg, lnfb, hid_bf, hidden, D);

    k_gemm_head<<<dim3(M / 128, (V + 127) / 128), 256, 0, stream>>>(
        hid_bf, embB, logits,
        M, V, D, D, D, Vp);

    softmax_vocab<<<M, 256, 0, stream>>>(logits, probs, V, Vp);
}

// Round 10
// 2163.862 us; speedup vs baseline: 6.4761x; 1.0000x over previous
//
#include <hip/hip_runtime.h>
#include <hip/hip_bf16.h>

typedef __bf16 bf16_t;
typedef bf16_t bf16x8 __attribute__((ext_vector_type(8)));
typedef float  f32x4  __attribute__((ext_vector_type(4)));

// ---------------------------------------------------------------------------
// global -> LDS async copy, 16B per lane. lds base must be wave-uniform.
// ---------------------------------------------------------------------------
__device__ __forceinline__ void gload16(const void* g, void* l) {
    __builtin_amdgcn_global_load_lds(
        (const __attribute__((address_space(1))) unsigned int*)g,
        (__attribute__((address_space(3))) unsigned int*)l, 16, 0, 0);
}

__device__ __forceinline__ void drain_and_barrier() {
    __builtin_amdgcn_sched_barrier(0);
    asm volatile("s_waitcnt vmcnt(0)" ::: "memory");
    __builtin_amdgcn_s_barrier();
    __builtin_amdgcn_sched_barrier(0);
}

// ---------------------------------------------------------------------------
// Embedding: h[b,s,:] = emb[x[b,s],:] + posemb[s,:]
// ---------------------------------------------------------------------------
__global__ void embed_kernel(const int* __restrict__ x,
                             const float* __restrict__ emb,
                             const float* __restrict__ pos,
                             float* __restrict__ h,
                             int S, int D, int total)
{
    int i = blockIdx.x * blockDim.x + threadIdx.x;
    if (i >= total) return;
    int d  = i % D;
    int bs = i / D;
    int s  = bs % S;
    h[i] = emb[(long long)x[bs] * D + d] + pos[(long long)s * D + d];
}

// ---------------------------------------------------------------------------
// elementwise f32 -> bf16 (vectorized by 4)
// ---------------------------------------------------------------------------
__global__ void convert_bf16(const float* __restrict__ in, bf16_t* __restrict__ out, int n4)
{
    int i = blockIdx.x * blockDim.x + threadIdx.x;
    for (; i < n4; i += gridDim.x * blockDim.x) {
        float4 v = ((const float4*)in)[i];
        bf16_t* o = out + (size_t)i * 4;
        o[0] = (bf16_t)v.x; o[1] = (bf16_t)v.y; o[2] = (bf16_t)v.z; o[3] = (bf16_t)v.w;
    }
}

// ---------------------------------------------------------------------------
// Batched transpose + bf16 convert: out[z][n][k] = (bf16) in[z][k][n]
// ---------------------------------------------------------------------------
__global__ __launch_bounds__(256) void transpose_to_bf16(
    const float* __restrict__ in, bf16_t* __restrict__ out, int K, int N)
{
    const float* ip = in  + (size_t)blockIdx.z * K * N;
    bf16_t*      op = out + (size_t)blockIdx.z * K * N;
    __shared__ float t[32][33];
    const int n0 = blockIdx.x * 32, k0 = blockIdx.y * 32;
    const int tx = threadIdx.x, ty = threadIdx.y;
#pragma unroll
    for (int u = 0; u < 4; ++u)
        t[ty + u * 8][tx] = ip[(size_t)(k0 + ty + u * 8) * N + (n0 + tx)];
    __syncthreads();
#pragma unroll
    for (int u = 0; u < 4; ++u)
        op[(size_t)(n0 + ty + u * 8) * K + (k0 + tx)] = (bf16_t)t[tx][ty + u * 8];
}

// ---------------------------------------------------------------------------
// LayerNorm rows of D=768; writes bf16 (always) and f32 (if Yf != nullptr).
// ---------------------------------------------------------------------------
__global__ __launch_bounds__(256) void layernorm_dual(
    const float* __restrict__ X, const float* __restrict__ g,
    const float* __restrict__ b, bf16_t* __restrict__ Yb,
    float* __restrict__ Yf, int D)
{
    const int row = blockIdx.x;
    const float* xr = X + (long long)row * D;
    const int tid = threadIdx.x;

    float vals[3];
    float s = 0.0f;
#pragma unroll
    for (int u = 0; u < 3; ++u) { vals[u] = xr[tid + u * 256]; s += vals[u]; }

    __shared__ float red[256];
    red[tid] = s;
    __syncthreads();
    for (int off = 128; off > 0; off >>= 1) {
        if (tid < off) red[tid] += red[tid + off];
        __syncthreads();
    }
    const float mean = red[0] / (float)D;
    __syncthreads();

    float vs = 0.0f;
#pragma unroll
    for (int u = 0; u < 3; ++u) { float d = vals[u] - mean; vs += d * d; }
    red[tid] = vs;
    __syncthreads();
    for (int off = 128; off > 0; off >>= 1) {
        if (tid < off) red[tid] += red[tid + off];
        __syncthreads();
    }
    const float var  = red[0] / (float)D;
    const float rstd = rsqrtf(var + 1e-6f);

#pragma unroll
    for (int u = 0; u < 3; ++u) {
        const int c = tid + u * 256;
        const float y = (vals[u] - mean) * rstd * g[c] + b[c];
        Yb[(long long)row * D + c] = (bf16_t)y;
        if (Yf) Yf[(long long)row * D + c] = y;
    }
}

// ---------------------------------------------------------------------------
// Fused flash attention (causal, hd=64, S=512), 64-row q-tiles.
// Grid: (S/64=8, B*H=48)=384 blocks; 4 waves x 16 q-rows each.
// V reg-staged from qkv; scatter into swizzled vS after compute (T14 split).
// ---------------------------------------------------------------------------
__global__ __launch_bounds__(256) void flash_attn(
    const bf16_t* __restrict__ qkv, bf16_t* __restrict__ o)
{
    constexpr int S = 512, TD = 2304, D = 768, H = 12;
    const int qt = blockIdx.x;          // 0..7
    const int z  = blockIdx.y;
    const int bb = z / H, hh = z - bb * H;
    const int tid = threadIdx.x, lane = tid & 63, w = tid >> 6;
    const int fr = lane & 15, g = lane >> 4, sub = g * 8;

    __shared__ bf16_t kS[2][4096];       // K tile [64 key][64 k], chunk-swizzled
    __shared__ bf16_t vS[2][4096];       // V^T tile [64 d][64 key], chunk-swizzled
    __shared__ bf16_t pS[4][16 * 72];    // per-wave P [16 q][64 key], padded

    // Q fragments: rows qt*64 + w*16 + fr, scaled by 1/8
    bf16x8 qf[2];
    const bf16_t* qbase = qkv + (size_t)(bb * S + qt * 64 + w * 16) * TD + hh * 64;
#pragma unroll
    for (int ks = 0; ks < 2; ++ks) {
        bf16x8 v = *(const bf16x8*)&qbase[(size_t)fr * TD + ks * 32 + sub];
#pragma unroll
        for (int j = 0; j < 8; ++j) v[j] = v[j] * (bf16_t)0.125f;
        qf[ks] = v;
    }

    f32x4 oacc[4];
    float mrun[4], lrun[4];
#pragma unroll
    for (int r = 0; r < 4; ++r) { mrun[r] = -3.0e38f; lrun[r] = 0.0f; }
#pragma unroll
    for (int n = 0; n < 4; ++n) oacc[n] = (f32x4){0.f, 0.f, 0.f, 0.f};

    int qr[4];
#pragma unroll
    for (int r = 0; r < 4; ++r) qr[r] = qt * 64 + w * 16 + g * 4 + r;

    const int srow8  = lane >> 3;
    const int schunk = (lane & 7) ^ (srow8 & 7);

    const bf16_t* kGbase = qkv + (size_t)(bb * S) * TD + D + hh * 64;
    const bf16_t* vGbase = qkv + (size_t)(bb * S) * TD + 2 * D + hh * 64;
    const int nkv = qt + 1;

    bf16x8 vreg[2];

#define STAGE_ISSUE(buf, t)                                                     \
    {                                                                           \
        _Pragma("unroll")                                                       \
        for (int it = 0; it < 2; ++it) {                                        \
            const int row = it * 32 + w * 8 + srow8;                            \
            gload16(kGbase + (size_t)((t) * 64 + row) * TD + schunk * 8,        \
                    &kS[buf][it * 2048 + w * 512]);                             \
        }                                                                       \
        _Pragma("unroll")                                                       \
        for (int it = 0; it < 2; ++it) {                                        \
            const int dch = w * 2 + it;                                         \
            vreg[it] = *(const bf16x8*)&vGbase[(size_t)((t) * 64 + lane) * TD + dch * 8]; \
        }                                                                       \
    }
#define STAGE_WRITE(buf)                                                        \
    {                                                                           \
        _Pragma("unroll")                                                       \
        for (int it = 0; it < 2; ++it) {                                        \
            const int dch = w * 2 + it;                                         \
            _Pragma("unroll")                                                   \
            for (int j = 0; j < 8; ++j) {                                       \
                const int d = dch * 8 + j;                                      \
                vS[buf][d * 64 + (((lane >> 3) ^ j) << 3) + (lane & 7)] = vreg[it][j]; \
            }                                                                   \
        }                                                                       \
    }

    STAGE_ISSUE(0, 0);
    STAGE_WRITE(0);
    __syncthreads();

    int cur = 0;
    for (int t = 0; t < nkv; ++t) {
        if (t + 1 < nkv) STAGE_ISSUE(cur ^ 1, t + 1);

        f32x4 sacc[4];
#pragma unroll
        for (int n = 0; n < 4; ++n) sacc[n] = (f32x4){0.f, 0.f, 0.f, 0.f};
#pragma unroll
        for (int ks = 0; ks < 2; ++ks) {
            bf16x8 bK[4];
#pragma unroll
            for (int n = 0; n < 4; ++n) {
                const int rw = n * 16 + fr;
                const int c  = ks * 4 + g;
                bK[n] = *(const bf16x8*)&kS[cur][rw * 64 + ((c ^ (rw & 7)) << 3)];
            }
#pragma unroll
            for (int n = 0; n < 4; ++n)
                sacc[n] = __builtin_amdgcn_mfma_f32_16x16x32_bf16(
                    qf[ks], bK[n], sacc[n], 0, 0, 0);
        }

        if (t == qt) {
#pragma unroll
            for (int n = 0; n < 4; ++n) {
                const int key = t * 64 + n * 16 + fr;
#pragma unroll
                for (int r = 0; r < 4; ++r)
                    if (key > qr[r]) sacc[n][r] = -3.0e38f;
            }
        }

        float sf[4], rs[4];
#pragma unroll
        for (int r = 0; r < 4; ++r) {
            float v = fmaxf(fmaxf(sacc[0][r], sacc[1][r]),
                            fmaxf(sacc[2][r], sacc[3][r]));
#pragma unroll
            for (int off = 1; off < 16; off <<= 1)
                v = fmaxf(v, __shfl_xor(v, off));
            const float mn = fmaxf(mrun[r], v);
            sf[r] = __expf(mrun[r] - mn);
            mrun[r] = mn;
            lrun[r] *= sf[r];
        }
#pragma unroll
        for (int n = 0; n < 4; ++n)
#pragma unroll
            for (int r = 0; r < 4; ++r)
                oacc[n][r] *= sf[r];
#pragma unroll
        for (int r = 0; r < 4; ++r) rs[r] = 0.0f;
#pragma unroll
        for (int n = 0; n < 4; ++n)
#pragma unroll
            for (int r = 0; r < 4; ++r) {
                const float p = __expf(sacc[n][r] - mrun[r]);
                sacc[n][r] = p;
                rs[r] += p;
            }
#pragma unroll
        for (int r = 0; r < 4; ++r) {
            float v = rs[r];
#pragma unroll
            for (int off = 1; off < 16; off <<= 1) v += __shfl_xor(v, off);
            lrun[r] += v;
        }

        bf16_t* pw = pS[w];
#pragma unroll
        for (int n = 0; n < 4; ++n)
#pragma unroll
            for (int r = 0; r < 4; ++r)
                pw[(g * 4 + r) * 72 + n * 16 + fr] = (bf16_t)sacc[n][r];

#pragma unroll
        for (int ks = 0; ks < 2; ++ks) {
            bf16x8 pa, vb[4];
            pa = *(const bf16x8*)&pw[fr * 72 + ks * 32 + sub];
#pragma unroll
            for (int n = 0; n < 4; ++n) {
                const int rw = n * 16 + fr;
                const int c  = ks * 4 + g;
                vb[n] = *(const bf16x8*)&vS[cur][rw * 64 + ((c ^ (rw & 7)) << 3)];
            }
#pragma unroll
            for (int n = 0; n < 4; ++n)
                oacc[n] = __builtin_amdgcn_mfma_f32_16x16x32_bf16(
                    pa, vb[n], oacc[n], 0, 0, 0);
        }

        if (t + 1 < nkv) STAGE_WRITE(cur ^ 1);
        __syncthreads();
        cur ^= 1;
    }
#undef STAGE_ISSUE
#undef STAGE_WRITE

    bf16_t* obase = o + (size_t)(bb * S + qt * 64 + w * 16) * D + hh * 64;
#pragma unroll
    for (int r = 0; r < 4; ++r) {
        const float inv = 1.0f / lrun[r];
#pragma unroll
        for (int n = 0; n < 4; ++n)
            obase[(size_t)(g * 4 + r) * D + n * 16 + fr] =
                (bf16_t)(oacc[n][r] * inv);
    }
}

// ---------------------------------------------------------------------------
// Vocab softmax: merge per-panel (max,sum) partials, then one logits pass.
// ---------------------------------------------------------------------------
__global__ __launch_bounds__(256) void softmax_vocab(
    const bf16_t* __restrict__ logits, const float* __restrict__ pmax,
    const float* __restrict__ psum, float* __restrict__ probs,
    int V, int Vp, int NP)
{
    const int tid = threadIdx.x;
    const int row = blockIdx.x;
    const bf16_t* lr = logits + (size_t)row * Vp;
    float* pr = probs + (size_t)row * V;
    const float* pm = pmax + (size_t)row * 400;
    const float* ps = psum + (size_t)row * 400;

    float m = -3.0e38f, s = 0.0f;
    for (int p = tid; p < NP; p += 256) {
        const float om = pm[p], os = ps[p];
        const float M_ = fmaxf(m, om);
        s = s * __expf(m - M_) + os * __expf(om - M_);
        m = M_;
    }

    __shared__ float mS[256], sS[256];
    mS[tid] = m; sS[tid] = s;
    __syncthreads();
    for (int off = 128; off > 0; off >>= 1) {
        if (tid < off) {
            const float m1 = mS[tid], m2 = mS[tid + off];
            const float M_ = fmaxf(m1, m2);
            sS[tid] = sS[tid] * __expf(m1 - M_) + sS[tid + off] * __expf(m2 - M_);
            mS[tid] = M_;
        }
        __syncthreads();
    }
    const float M_  = mS[0];
    const float inv = 1.0f / sS[0];

    const int n8 = V >> 3;
    for (int c8 = tid; c8 < n8; c8 += 256) {
        const bf16x8 v = *(const bf16x8*)(lr + (size_t)c8 * 8);
#pragma unroll
        for (int j = 0; j < 8; ++j)
            pr[(size_t)c8 * 8 + j] = __expf((float)v[j] - M_) * inv;
    }
    for (int c = n8 * 8 + tid; c < V; c += 256)
        pr[c] = __expf((float)lr[c] - M_) * inv;
}

// ---------------------------------------------------------------------------
// bf16 MFMA GEMM body (layer GEMMs): C[M, tile] = A @ B^T + bias
// ---------------------------------------------------------------------------
template<bool ADD, bool GELU_, bool OUTBF, bool DB, bool HALFN>
__device__ __forceinline__ void gemm_body(
    const bf16_t* __restrict__ A, const bf16_t* __restrict__ Bw,
    const float* __restrict__ bias, void* __restrict__ Cv,
    int M, int N, int K, int lda, int ldb, int ldc)
{
    constexpr int BN  = HALFN ? 64 : 128;
    constexpr int BUF = HALFN ? 12288 : 16384;
    __shared__ bf16_t lds[(DB ? 2 : 1) * BUF];

    const int tid  = threadIdx.x;
    const int lane = tid & 63;
    const int w    = tid >> 6;
    const int row0 = blockIdx.x * 128;
    const int col0 = blockIdx.y * BN;

    const int row8 = lane >> 3;
    const int sch  = (lane & 7) ^ row8;
    const int fr   = lane & 15;
    const int g    = lane >> 4;

    const int aRowB = row0 + w * 32;
    const int bRowB = HALFN ? (col0 + w * 16) : (col0 + w * 32);

    constexpr int MR = HALFN ? 2 : 4;
    const int wr = HALFN ? w : (w >> 1);
    const int wc = HALFN ? 0 : (w & 1);

    f32x4 acc[MR][4];
#pragma unroll
    for (int m = 0; m < MR; ++m)
#pragma unroll
        for (int n = 0; n < 4; ++n)
            acc[m][n] = (f32x4){0.f, 0.f, 0.f, 0.f};

    auto STAGE = [&](int buf, int k0) {
        bf16_t* lb = lds + buf * BUF;
#pragma unroll
        for (int it = 0; it < 4; ++it) {
            const int ar = aRowB + it * 8 + row8;
            gload16(A + (size_t)ar * lda + k0 + sch * 8, lb + w * 2048 + it * 512);
        }
#pragma unroll
        for (int it = 0; it < (HALFN ? 2 : 4); ++it) {
            int br = bRowB + it * 8 + row8;
            if (br >= N) br = 0;
            gload16(Bw + (size_t)br * ldb + k0 + sch * 8,
                    lb + 8192 + w * (HALFN ? 1024 : 2048) + it * 512);
        }
    };

    auto COMPUTE = [&](int buf) {
        bf16_t* lb = lds + buf * BUF;
#pragma unroll
        for (int ks = 0; ks < 2; ++ks) {
            bf16x8 af[MR], bfr[4];
            const int cs = ks * 4 + g;
#pragma unroll
            for (int m = 0; m < MR; ++m) {
                const int row = (HALFN ? w * 32 : wr * 64) + m * 16 + fr;
                af[m] = *(const bf16x8*)&lb[row * 64 + ((cs ^ (fr & 7)) << 3)];
            }
#pragma unroll
            for (int n = 0; n < 4; ++n) {
                const int row = (HALFN ? 0 : wc * 64) + n * 16 + fr;
                bfr[n] = *(const bf16x8*)&lb[8192 + row * 64 + ((cs ^ (fr & 7)) << 3)];
            }
#pragma unroll
            for (int m = 0; m < MR; ++m)
#pragma unroll
                for (int n = 0; n < 4; ++n)
                    acc[m][n] = __builtin_amdgcn_mfma_f32_16x16x32_bf16(
                        af[m], bfr[n], acc[m][n], 0, 0, 0);
        }
    };

    const int nt = K >> 6;
    if (DB) {
        STAGE(0, 0);
        drain_and_barrier();
        int cur = 0;
        for (int t = 0; t < nt; ++t) {
            if (t + 1 < nt) STAGE(cur ^ 1, (t + 1) << 6);
            COMPUTE(cur);
            drain_and_barrier();
            cur ^= 1;
        }
    } else {
        for (int t = 0; t < nt; ++t) {
            STAGE(0, t << 6);
            __syncthreads();
            COMPUTE(0);
            __syncthreads();
        }
    }

    const int rBase = row0 + (HALFN ? w * 32 : wr * 64) + g * 4;
    const int cBase = col0 + (HALFN ? 0 : wc * 64) + fr;
    float bv[4];
#pragma unroll
    for (int n = 0; n < 4; ++n) {
        const int c = cBase + n * 16;
        bv[n] = (bias && c < N) ? bias[c] : 0.0f;
    }
#pragma unroll
    for (int m = 0; m < MR; ++m) {
#pragma unroll
        for (int r = 0; r < 4; ++r) {
            const int rr = rBase + m * 16 + r;
#pragma unroll
            for (int n = 0; n < 4; ++n) {
                const int c = cBase + n * 16;
                if (c >= N) continue;
                float v = acc[m][n][r] + bv[n];
                if (GELU_) v = 0.5f * v * (1.0f + erff(v * 0.70710678118654752f));
                if (OUTBF) {
                    ((bf16_t*)Cv)[(size_t)rr * ldc + c] = (bf16_t)v;
                } else {
                    float* Cf = (float*)Cv;
                    const size_t idx = (size_t)rr * ldc + c;
                    if (ADD) v += Cf[idx];
                    Cf[idx] = v;
                }
            }
        }
    }
}

__global__ __launch_bounds__(256) void k_gemm_qkv(
    const bf16_t* A, const bf16_t* B, const float* bias, void* C,
    int M, int N, int K, int lda, int ldb, int ldc)
{ gemm_body<false, false, true, true, true>(A, B, bias, C, M, N, K, lda, ldb, ldc); }

__global__ __launch_bounds__(256) void k_gemm_oproj(
    const bf16_t* A, const bf16_t* B, const float* bias, void* C,
    int M, int N, int K, int lda, int ldb, int ldc)
{ gemm_body<true, false, false, true, true>(A, B, bias, C, M, N, K, lda, ldb, ldc); }

__global__ __launch_bounds__(256) void k_gemm_fc(
    const bf16_t* A, const bf16_t* B, const float* bias, void* C,
    int M, int N, int K, int lda, int ldb, int ldc)
{ gemm_body<false, true, true, true, true>(A, B, bias, C, M, N, K, lda, ldb, ldc); }

__global__ __launch_bounds__(256) void k_gemm_proj(
    const bf16_t* A, const bf16_t* B, const float* bias, void* C,
    int M, int N, int K, int lda, int ldb, int ldc)
{ gemm_body<true, false, false, true, true>(A, B, bias, C, M, N, K, lda, ldb, ldc); }

// ---------------------------------------------------------------------------
// LM head GEMM: 128x128 tile, BK=64, single-buffer, 4 waves 2x2.
// Epilogue additionally reduces per-row (max, sum-exp) partials for softmax.
// ---------------------------------------------------------------------------
__global__ __launch_bounds__(256) void k_gemm_head(
    const bf16_t* __restrict__ A, const bf16_t* __restrict__ Bw,
    bf16_t* __restrict__ C, float* __restrict__ pmax, float* __restrict__ psum,
    int M, int N, int K, int lda, int ldb, int ldc)
{
    __shared__ bf16_t lds[16384];

    const int tid  = threadIdx.x;
    const int lane = tid & 63;
    const int w    = tid >> 6;
    const int wr   = w >> 1, wc = w & 1;
    const int row0 = blockIdx.x * 128;
    const int col0 = blockIdx.y * 128;

    const int row8 = lane >> 3;
    const int sch  = (lane & 7) ^ row8;
    const int fr   = lane & 15;
    const int g    = lane >> 4;

    const int aRowB = row0 + w * 32;
    const int bRowB = col0 + w * 32;

    f32x4 acc[4][4];
#pragma unroll
    for (int m = 0; m < 4; ++m)
#pragma unroll
        for (int n = 0; n < 4; ++n)
            acc[m][n] = (f32x4){0.f, 0.f, 0.f, 0.f};

    for (int k0 = 0; k0 < K; k0 += 64) {
#pragma unroll
        for (int it = 0; it < 4; ++it) {
            const int ar = aRowB + it * 8 + row8;
            gload16(A + (size_t)ar * lda + k0 + sch * 8,
                    lds + w * 2048 + it * 512);
            int br = bRowB + it * 8 + row8;
            if (br >= N) br = 0;
            gload16(Bw + (size_t)br * ldb + k0 + sch * 8,
                    lds + 8192 + w * 2048 + it * 512);
        }
        __syncthreads();

#pragma unroll
        for (int ks = 0; ks < 2; ++ks) {
            bf16x8 af[4], bfr[4];
            const int cs = ks * 4 + g;
#pragma unroll
            for (int m = 0; m < 4; ++m) {
                const int row = wr * 64 + m * 16 + fr;
                af[m] = *(const bf16x8*)&lds[row * 64 + ((cs ^ (fr & 7)) << 3)];
            }
#pragma unroll
            for (int n = 0; n < 4; ++n) {
                const int row = wc * 64 + n * 16 + fr;
                bfr[n] = *(const bf16x8*)&lds[8192 + row * 64 + ((cs ^ (fr & 7)) << 3)];
            }
#pragma unroll
            for (int m = 0; m < 4; ++m)
#pragma unroll
                for (int n = 0; n < 4; ++n)
                    acc[m][n] = __builtin_amdgcn_mfma_f32_16x16x32_bf16(
                        af[m], bfr[n], acc[m][n], 0, 0, 0);
        }
        __syncthreads();
    }

    const int rBase = row0 + wr * 64 + g * 4;
    const int cBase = col0 + wc * 64 + fr;
#pragma unroll
    for (int n = 0; n < 4; ++n) {
        const int c = cBase + n * 16;
        if (c >= N) continue;
#pragma unroll
        for (int m = 0; m < 4; ++m)
#pragma unroll
            for (int r = 0; r < 4; ++r)
                C[(size_t)(rBase + m * 16 + r) * ldc + c] = (bf16_t)acc[m][n][r];
    }

    // ---- per-row (max, sum-exp) partial for this 128-col panel
    float* sred = (float*)lds;          // [2][128] max + [2][128] sum (2KB)
#pragma unroll
    for (int m = 0; m < 4; ++m) {
#pragma unroll
        for (int r = 0; r < 4; ++r) {
            float lm = -3.0e38f;
#pragma unroll
            for (int n = 0; n < 4; ++n) {
                const int c = cBase + n * 16;
                if (c < N) lm = fmaxf(lm, (float)(bf16_t)acc[m][n][r]);
            }
            float ls = 0.0f;
#pragma unroll
            for (int n = 0; n < 4; ++n) {
                const int c = cBase + n * 16;
                if (c < N) ls += __expf((float)(bf16_t)acc[m][n][r] - lm);
            }
#pragma unroll
            for (int off = 1; off < 16; off <<= 1) {
                const float om = __shfl_xor(lm, off);
                const float os = __shfl_xor(ls, off);
                const float M_ = fmaxf(lm, om);
                ls = ls * __expf(lm - M_) + os * __expf(om - M_);
                lm = M_;
            }
            if (fr == 0) {
                const int rl = wr * 64 + m * 16 + g * 4 + r;
                sred[wc * 128 + rl] = lm;
                sred[256 + wc * 128 + rl] = ls;
            }
        }
    }
    __syncthreads();
    if ((w & 1) == 0) {
        const int rl = (w >> 1) * 64 + lane;
        const float m0 = sred[rl],       m1 = sred[128 + rl];
        const float s0 = sred[256 + rl], s1 = sred[384 + rl];
        const float M_ = fmaxf(m0, m1);
        const float S_ = s0 * __expf(m0 - M_) + s1 * __expf(m1 - M_);
        const size_t grow = row0 + rl;
        pmax[grow * 400 + blockIdx.y] = M_;
        psum[grow * 400 + blockIdx.y] = S_;
    }
}

// ---------------------------------------------------------------------------
// Launcher
// ---------------------------------------------------------------------------
extern "C" void kernel_launch(void* const* d_in, const int* in_sizes, int n_in,
                              void* d_out, int out_size, void* d_ws, size_t ws_size,
                              hipStream_t stream)
{
    constexpr int B = 4, S = 512, D = 768, L = 12, V = 50257, H = 12, F = 3072;
    constexpr int M  = B * S;     // 2048
    constexpr int TD = 3 * D;     // 2304
    constexpr int BH = B * H;     // 48
    constexpr int Vp = 50264;     // V padded to multiple of 8
    constexpr int NP = (V + 127) / 128;   // 393 column panels

    const int*   x    = (const int*)  d_in[0];
    const float* emb  = (const float*)d_in[1];
    const float* pos  = (const float*)d_in[2];
    const float* ln1g = (const float*)d_in[3];
    const float* ln1b = (const float*)d_in[4];
    const float* wqkv = (const float*)d_in[5];
    const float* bqkv = (const float*)d_in[6];
    const float* wo   = (const float*)d_in[7];
    const float* bo   = (const float*)d_in[8];
    const float* ln2g = (const float*)d_in[9];
    const float* ln2b = (const float*)d_in[10];
    const float* wfc  = (const float*)d_in[11];
    const float* bfc  = (const float*)d_in[12];
    const float* wpr  = (const float*)d_in[13];
    const float* bpr  = (const float*)d_in[14];
    const float* lnfg = (const float*)d_in[15];
    const float* lnfb = (const float*)d_in[16];

    float* probs  = (float*)d_out;                    // [M, V]
    float* hidden = probs + (size_t)M * V;            // [M, D]

    // ---- workspace layout (bump allocator, 256B aligned) ------------------
    char* wsb = (char*)d_ws;
    size_t off = 0;
    auto alloc = [&](size_t bytes) -> char* {
        char* p = wsb + off;
        off += (bytes + 255) & ~(size_t)255;
        return p;
    };
    // live-at-head buffers FIRST (never aliased by logits)
    bf16_t* hid_bf = (bf16_t*)alloc((size_t)M * D * 2);
    bf16_t* embB   = (bf16_t*)alloc((size_t)V * D * 2);
    // trunk region (dead at head time) — logits aliases it
    const size_t trunk_start = off;
    float*  h      = (float*) alloc((size_t)M * D * 4);
    bf16_t* qkv_bf = (bf16_t*)alloc((size_t)M * TD * 2);
    bf16_t* xn_bf  = (bf16_t*)alloc((size_t)M * D * 2);
    bf16_t* o_bf   = (bf16_t*)alloc((size_t)M * D * 2);
    bf16_t* mid_bf = (bf16_t*)alloc((size_t)M * F * 2);
    bf16_t* wqkvT  = (bf16_t*)alloc((size_t)L * D * TD * 2);
    bf16_t* woT    = (bf16_t*)alloc((size_t)L * D * D * 2);
    bf16_t* wfcT   = (bf16_t*)alloc((size_t)L * D * F * 2);
    bf16_t* wprT   = (bf16_t*)alloc((size_t)L * F * D * 2);
    const size_t logits_bytes = (size_t)M * Vp * 2;
    if (off < trunk_start + logits_bytes) off = trunk_start + logits_bytes;
    bf16_t* logits = (bf16_t*)(wsb + trunk_start);
    // softmax partials (live during head) AFTER the logits region
    float* pmax = (float*)alloc((size_t)M * 400 * 4);
    float* psum = (float*)alloc((size_t)M * 400 * 4);

    // ---- weight prep ------------------------------------------------------
    convert_bf16<<<2048, 256, 0, stream>>>(emb, embB, (V * D) / 4);
    transpose_to_bf16<<<dim3(TD / 32, D / 32, L), dim3(32, 8), 0, stream>>>(wqkv, wqkvT, D, TD);
    transpose_to_bf16<<<dim3(D / 32,  D / 32, L), dim3(32, 8), 0, stream>>>(wo,   woT,   D, D);
    transpose_to_bf16<<<dim3(F / 32,  D / 32, L), dim3(32, 8), 0, stream>>>(wfc,  wfcT,  D, F);
    transpose_to_bf16<<<dim3(D / 32,  F / 32, L), dim3(32, 8), 0, stream>>>(wpr,  wprT,  F, D);

    // ---- embedding
    embed_kernel<<<dim3((M * D + 255) / 256), 256, 0, stream>>>(x, emb, pos, h, S, D, M * D);

    for (int i = 0; i < L; ++i) {
        layernorm_dual<<<M, 256, 0, stream>>>(h, ln1g + (size_t)i * D, ln1b + (size_t)i * D,
                                              xn_bf, nullptr, D);

        k_gemm_qkv<<<dim3(M / 128, TD / 64), 256, 0, stream>>>(
            xn_bf, wqkvT + (size_t)i * D * TD, bqkv + (size_t)i * TD, qkv_bf,
            M, TD, D, D, D, TD);

        flash_attn<<<dim3(S / 64, BH), 256, 0, stream>>>(qkv_bf, o_bf);

        k_gemm_oproj<<<dim3(M / 128, D / 64), 256, 0, stream>>>(
            o_bf, woT + (size_t)i * D * D, bo + (size_t)i * D, h,
            M, D, D, D, D, D);

        layernorm_dual<<<M, 256, 0, stream>>>(h, ln2g + (size_t)i * D, ln2b + (size_t)i * D,
                                              xn_bf, nullptr, D);

        k_gemm_fc<<<dim3(M / 128, F / 64), 256, 0, stream>>>(
            xn_bf, wfcT + (size_t)i * D * F, bfc + (size_t)i * F, mid_bf,
            M, F, D, D, D, F);

        k_gemm_proj<<<dim3(M / 128, D / 64), 256, 0, stream>>>(
            mid_bf, wprT + (size_t)i * F * D, bpr + (size_t)i * D, h,
            M, D, F, F, F, D);
    }

    layernorm_dual<<<M, 256, 0, stream>>>(h, lnfg, lnfb, hid_bf, hidden, D);

    k_gemm_head<<<dim3(M / 128, NP), 256, 0, stream>>>(
        hid_bf, embB, logits, pmax, psum,
        M, V, D, D, D, Vp);

    softmax_vocab<<<M, 256, 0, stream>>>(logits, pmax, psum, probs, V, Vp, NP);
}

// Round 11
// 2065.269 us; speedup vs baseline: 6.7853x; 1.0477x over previous
//
#include <hip/hip_runtime.h>
#include <hip/hip_bf16.h>

typedef __bf16 bf16_t;
typedef bf16_t bf16x8 __attribute__((ext_vector_type(8)));
typedef float  f32x4  __attribute__((ext_vector_type(4)));

// ---------------------------------------------------------------------------
// global -> LDS async copy, 16B per lane. lds base must be wave-uniform.
// ---------------------------------------------------------------------------
__device__ __forceinline__ void gload16(const void* g, void* l) {
    __builtin_amdgcn_global_load_lds(
        (const __attribute__((address_space(1))) unsigned int*)g,
        (__attribute__((address_space(3))) unsigned int*)l, 16, 0, 0);
}

__device__ __forceinline__ void drain_and_barrier() {
    __builtin_amdgcn_sched_barrier(0);
    asm volatile("s_waitcnt vmcnt(0)" ::: "memory");
    __builtin_amdgcn_s_barrier();
    __builtin_amdgcn_sched_barrier(0);
}

// ---------------------------------------------------------------------------
// Embedding: h[b,s,:] = emb[x[b,s],:] + posemb[s,:]
// ---------------------------------------------------------------------------
__global__ void embed_kernel(const int* __restrict__ x,
                             const float* __restrict__ emb,
                             const float* __restrict__ pos,
                             float* __restrict__ h,
                             int S, int D, int total)
{
    int i = blockIdx.x * blockDim.x + threadIdx.x;
    if (i >= total) return;
    int d  = i % D;
    int bs = i / D;
    int s  = bs % S;
    h[i] = emb[(long long)x[bs] * D + d] + pos[(long long)s * D + d];
}

// ---------------------------------------------------------------------------
// elementwise f32 -> bf16 (vectorized by 4)
// ---------------------------------------------------------------------------
__global__ void convert_bf16(const float* __restrict__ in, bf16_t* __restrict__ out, int n4)
{
    int i = blockIdx.x * blockDim.x + threadIdx.x;
    for (; i < n4; i += gridDim.x * blockDim.x) {
        float4 v = ((const float4*)in)[i];
        bf16_t* o = out + (size_t)i * 4;
        o[0] = (bf16_t)v.x; o[1] = (bf16_t)v.y; o[2] = (bf16_t)v.z; o[3] = (bf16_t)v.w;
    }
}

// ---------------------------------------------------------------------------
// Batched transpose + bf16 convert: out[z][n][k] = (bf16) in[z][k][n]
// ---------------------------------------------------------------------------
__global__ __launch_bounds__(256) void transpose_to_bf16(
    const float* __restrict__ in, bf16_t* __restrict__ out, int K, int N)
{
    const float* ip = in  + (size_t)blockIdx.z * K * N;
    bf16_t*      op = out + (size_t)blockIdx.z * K * N;
    __shared__ float t[32][33];
    const int n0 = blockIdx.x * 32, k0 = blockIdx.y * 32;
    const int tx = threadIdx.x, ty = threadIdx.y;
#pragma unroll
    for (int u = 0; u < 4; ++u)
        t[ty + u * 8][tx] = ip[(size_t)(k0 + ty + u * 8) * N + (n0 + tx)];
    __syncthreads();
#pragma unroll
    for (int u = 0; u < 4; ++u)
        op[(size_t)(n0 + ty + u * 8) * K + (k0 + tx)] = (bf16_t)t[tx][ty + u * 8];
}

// ---------------------------------------------------------------------------
// LayerNorm rows of D=768; writes bf16 (always) and f32 (if Yf != nullptr).
// ---------------------------------------------------------------------------
__global__ __launch_bounds__(256) void layernorm_dual(
    const float* __restrict__ X, const float* __restrict__ g,
    const float* __restrict__ b, bf16_t* __restrict__ Yb,
    float* __restrict__ Yf, int D)
{
    const int row = blockIdx.x;
    const float* xr = X + (long long)row * D;
    const int tid = threadIdx.x;

    float vals[3];
    float s = 0.0f;
#pragma unroll
    for (int u = 0; u < 3; ++u) { vals[u] = xr[tid + u * 256]; s += vals[u]; }

    __shared__ float red[256];
    red[tid] = s;
    __syncthreads();
    for (int off = 128; off > 0; off >>= 1) {
        if (tid < off) red[tid] += red[tid + off];
        __syncthreads();
    }
    const float mean = red[0] / (float)D;
    __syncthreads();

    float vs = 0.0f;
#pragma unroll
    for (int u = 0; u < 3; ++u) { float d = vals[u] - mean; vs += d * d; }
    red[tid] = vs;
    __syncthreads();
    for (int off = 128; off > 0; off >>= 1) {
        if (tid < off) red[tid] += red[tid + off];
        __syncthreads();
    }
    const float var  = red[0] / (float)D;
    const float rstd = rsqrtf(var + 1e-6f);

#pragma unroll
    for (int u = 0; u < 3; ++u) {
        const int c = tid + u * 256;
        const float y = (vals[u] - mean) * rstd * g[c] + b[c];
        Yb[(long long)row * D + c] = (bf16_t)y;
        if (Yf) Yf[(long long)row * D + c] = y;
    }
}

// ---------------------------------------------------------------------------
// Fused flash attention (causal, hd=64, S=512), 64-row q-tiles.
// Grid: (S/64=8, B*H=48)=384 blocks; 4 waves x 16 q-rows each.
// ---------------------------------------------------------------------------
__global__ __launch_bounds__(256) void flash_attn(
    const bf16_t* __restrict__ qkv, bf16_t* __restrict__ o)
{
    constexpr int S = 512, TD = 2304, D = 768, H = 12;
    const int qt = blockIdx.x;          // 0..7
    const int z  = blockIdx.y;
    const int bb = z / H, hh = z - bb * H;
    const int tid = threadIdx.x, lane = tid & 63, w = tid >> 6;
    const int fr = lane & 15, g = lane >> 4, sub = g * 8;

    __shared__ bf16_t kS[2][4096];
    __shared__ bf16_t vS[2][4096];
    __shared__ bf16_t pS[4][16 * 72];

    bf16x8 qf[2];
    const bf16_t* qbase = qkv + (size_t)(bb * S + qt * 64 + w * 16) * TD + hh * 64;
#pragma unroll
    for (int ks = 0; ks < 2; ++ks) {
        bf16x8 v = *(const bf16x8*)&qbase[(size_t)fr * TD + ks * 32 + sub];
#pragma unroll
        for (int j = 0; j < 8; ++j) v[j] = v[j] * (bf16_t)0.125f;
        qf[ks] = v;
    }

    f32x4 oacc[4];
    float mrun[4], lrun[4];
#pragma unroll
    for (int r = 0; r < 4; ++r) { mrun[r] = -3.0e38f; lrun[r] = 0.0f; }
#pragma unroll
    for (int n = 0; n < 4; ++n) oacc[n] = (f32x4){0.f, 0.f, 0.f, 0.f};

    int qr[4];
#pragma unroll
    for (int r = 0; r < 4; ++r) qr[r] = qt * 64 + w * 16 + g * 4 + r;

    const int srow8  = lane >> 3;
    const int schunk = (lane & 7) ^ (srow8 & 7);

    const bf16_t* kGbase = qkv + (size_t)(bb * S) * TD + D + hh * 64;
    const bf16_t* vGbase = qkv + (size_t)(bb * S) * TD + 2 * D + hh * 64;
    const int nkv = qt + 1;

    bf16x8 vreg[2];

#define STAGE_ISSUE(buf, t)                                                     \
    {                                                                           \
        _Pragma("unroll")                                                       \
        for (int it = 0; it < 2; ++it) {                                        \
            const int row = it * 32 + w * 8 + srow8;                            \
            gload16(kGbase + (size_t)((t) * 64 + row) * TD + schunk * 8,        \
                    &kS[buf][it * 2048 + w * 512]);                             \
        }                                                                       \
        _Pragma("unroll")                                                       \
        for (int it = 0; it < 2; ++it) {                                        \
            const int dch = w * 2 + it;                                         \
            vreg[it] = *(const bf16x8*)&vGbase[(size_t)((t) * 64 + lane) * TD + dch * 8]; \
        }                                                                       \
    }
#define STAGE_WRITE(buf)                                                        \
    {                                                                           \
        _Pragma("unroll")                                                       \
        for (int it = 0; it < 2; ++it) {                                        \
            const int dch = w * 2 + it;                                         \
            _Pragma("unroll")                                                   \
            for (int j = 0; j < 8; ++j) {                                       \
                const int d = dch * 8 + j;                                      \
                vS[buf][d * 64 + (((lane >> 3) ^ j) << 3) + (lane & 7)] = vreg[it][j]; \
            }                                                                   \
        }                                                                       \
    }

    STAGE_ISSUE(0, 0);
    STAGE_WRITE(0);
    __syncthreads();

    int cur = 0;
    for (int t = 0; t < nkv; ++t) {
        if (t + 1 < nkv) STAGE_ISSUE(cur ^ 1, t + 1);

        f32x4 sacc[4];
#pragma unroll
        for (int n = 0; n < 4; ++n) sacc[n] = (f32x4){0.f, 0.f, 0.f, 0.f};
#pragma unroll
        for (int ks = 0; ks < 2; ++ks) {
            bf16x8 bK[4];
#pragma unroll
            for (int n = 0; n < 4; ++n) {
                const int rw = n * 16 + fr;
                const int c  = ks * 4 + g;
                bK[n] = *(const bf16x8*)&kS[cur][rw * 64 + ((c ^ (rw & 7)) << 3)];
            }
#pragma unroll
            for (int n = 0; n < 4; ++n)
                sacc[n] = __builtin_amdgcn_mfma_f32_16x16x32_bf16(
                    qf[ks], bK[n], sacc[n], 0, 0, 0);
        }

        if (t == qt) {
#pragma unroll
            for (int n = 0; n < 4; ++n) {
                const int key = t * 64 + n * 16 + fr;
#pragma unroll
                for (int r = 0; r < 4; ++r)
                    if (key > qr[r]) sacc[n][r] = -3.0e38f;
            }
        }

        float sf[4], rs[4];
#pragma unroll
        for (int r = 0; r < 4; ++r) {
            float v = fmaxf(fmaxf(sacc[0][r], sacc[1][r]),
                            fmaxf(sacc[2][r], sacc[3][r]));
#pragma unroll
            for (int off = 1; off < 16; off <<= 1)
                v = fmaxf(v, __shfl_xor(v, off));
            const float mn = fmaxf(mrun[r], v);
            sf[r] = __expf(mrun[r] - mn);
            mrun[r] = mn;
            lrun[r] *= sf[r];
        }
#pragma unroll
        for (int n = 0; n < 4; ++n)
#pragma unroll
            for (int r = 0; r < 4; ++r)
                oacc[n][r] *= sf[r];
#pragma unroll
        for (int r = 0; r < 4; ++r) rs[r] = 0.0f;
#pragma unroll
        for (int n = 0; n < 4; ++n)
#pragma unroll
            for (int r = 0; r < 4; ++r) {
                const float p = __expf(sacc[n][r] - mrun[r]);
                sacc[n][r] = p;
                rs[r] += p;
            }
#pragma unroll
        for (int r = 0; r < 4; ++r) {
            float v = rs[r];
#pragma unroll
            for (int off = 1; off < 16; off <<= 1) v += __shfl_xor(v, off);
            lrun[r] += v;
        }

        bf16_t* pw = pS[w];
#pragma unroll
        for (int n = 0; n < 4; ++n)
#pragma unroll
            for (int r = 0; r < 4; ++r)
                pw[(g * 4 + r) * 72 + n * 16 + fr] = (bf16_t)sacc[n][r];

#pragma unroll
        for (int ks = 0; ks < 2; ++ks) {
            bf16x8 pa, vb[4];
            pa = *(const bf16x8*)&pw[fr * 72 + ks * 32 + sub];
#pragma unroll
            for (int n = 0; n < 4; ++n) {
                const int rw = n * 16 + fr;
                const int c  = ks * 4 + g;
                vb[n] = *(const bf16x8*)&vS[cur][rw * 64 + ((c ^ (rw & 7)) << 3)];
            }
#pragma unroll
            for (int n = 0; n < 4; ++n)
                oacc[n] = __builtin_amdgcn_mfma_f32_16x16x32_bf16(
                    pa, vb[n], oacc[n], 0, 0, 0);
        }

        if (t + 1 < nkv) STAGE_WRITE(cur ^ 1);
        __syncthreads();
        cur ^= 1;
    }
#undef STAGE_ISSUE
#undef STAGE_WRITE

    bf16_t* obase = o + (size_t)(bb * S + qt * 64 + w * 16) * D + hh * 64;
#pragma unroll
    for (int r = 0; r < 4; ++r) {
        const float inv = 1.0f / lrun[r];
#pragma unroll
        for (int n = 0; n < 4; ++n)
            obase[(size_t)(g * 4 + r) * D + n * 16 + fr] =
                (bf16_t)(oacc[n][r] * inv);
    }
}

// ---------------------------------------------------------------------------
// Vocab softmax: merge per-panel (max,sum) partials, then one logits pass.
// ---------------------------------------------------------------------------
__global__ __launch_bounds__(256) void softmax_vocab(
    const bf16_t* __restrict__ logits, const float* __restrict__ pmax,
    const float* __restrict__ psum, float* __restrict__ probs,
    int V, int Vp, int NP)
{
    const int tid = threadIdx.x;
    const int row = blockIdx.x;
    const bf16_t* lr = logits + (size_t)row * Vp;
    float* pr = probs + (size_t)row * V;
    const float* pm = pmax + (size_t)row * 400;
    const float* ps = psum + (size_t)row * 400;

    float m = -3.0e38f, s = 0.0f;
    for (int p = tid; p < NP; p += 256) {
        const float om = pm[p], os = ps[p];
        const float M_ = fmaxf(m, om);
        s = s * __expf(m - M_) + os * __expf(om - M_);
        m = M_;
    }

    __shared__ float mS[256], sS[256];
    mS[tid] = m; sS[tid] = s;
    __syncthreads();
    for (int off = 128; off > 0; off >>= 1) {
        if (tid < off) {
            const float m1 = mS[tid], m2 = mS[tid + off];
            const float M_ = fmaxf(m1, m2);
            sS[tid] = sS[tid] * __expf(m1 - M_) + sS[tid + off] * __expf(m2 - M_);
            mS[tid] = M_;
        }
        __syncthreads();
    }
    const float M_  = mS[0];
    const float inv = 1.0f / sS[0];

    const int n8 = V >> 3;
    for (int c8 = tid; c8 < n8; c8 += 256) {
        const bf16x8 v = *(const bf16x8*)(lr + (size_t)c8 * 8);
#pragma unroll
        for (int j = 0; j < 8; ++j)
            pr[(size_t)c8 * 8 + j] = __expf((float)v[j] - M_) * inv;
    }
    for (int c = n8 * 8 + tid; c < V; c += 256)
        pr[c] = __expf((float)lr[c] - M_) * inv;
}

// ---------------------------------------------------------------------------
// bf16 MFMA GEMM body (qkv/fc): 128x64 tile, DB 2-phase, 4 waves x 32 rows.
// ---------------------------------------------------------------------------
template<bool ADD, bool GELU_, bool OUTBF>
__device__ __forceinline__ void gemm_body(
    const bf16_t* __restrict__ A, const bf16_t* __restrict__ Bw,
    const float* __restrict__ bias, void* __restrict__ Cv,
    int M, int N, int K, int lda, int ldb, int ldc)
{
    constexpr int BUF = 12288;
    __shared__ bf16_t lds[2 * BUF];

    const int tid  = threadIdx.x;
    const int lane = tid & 63;
    const int w    = tid >> 6;
    const int row0 = blockIdx.x * 128;
    const int col0 = blockIdx.y * 64;

    const int row8 = lane >> 3;
    const int sch  = (lane & 7) ^ row8;
    const int fr   = lane & 15;
    const int g    = lane >> 4;

    const int aRowB = row0 + w * 32;
    const int bRowB = col0 + w * 16;

    f32x4 acc[2][4];
#pragma unroll
    for (int m = 0; m < 2; ++m)
#pragma unroll
        for (int n = 0; n < 4; ++n)
            acc[m][n] = (f32x4){0.f, 0.f, 0.f, 0.f};

    auto STAGE = [&](int buf, int k0) {
        bf16_t* lb = lds + buf * BUF;
#pragma unroll
        for (int it = 0; it < 4; ++it) {
            const int ar = aRowB + it * 8 + row8;
            gload16(A + (size_t)ar * lda + k0 + sch * 8, lb + w * 2048 + it * 512);
        }
#pragma unroll
        for (int it = 0; it < 2; ++it) {
            int br = bRowB + it * 8 + row8;
            if (br >= N) br = 0;
            gload16(Bw + (size_t)br * ldb + k0 + sch * 8,
                    lb + 8192 + w * 1024 + it * 512);
        }
    };

    auto COMPUTE = [&](int buf) {
        bf16_t* lb = lds + buf * BUF;
#pragma unroll
        for (int ks = 0; ks < 2; ++ks) {
            bf16x8 af[2], bfr[4];
            const int cs = ks * 4 + g;
#pragma unroll
            for (int m = 0; m < 2; ++m) {
                const int row = w * 32 + m * 16 + fr;
                af[m] = *(const bf16x8*)&lb[row * 64 + ((cs ^ (fr & 7)) << 3)];
            }
#pragma unroll
            for (int n = 0; n < 4; ++n) {
                const int row = n * 16 + fr;
                bfr[n] = *(const bf16x8*)&lb[8192 + row * 64 + ((cs ^ (fr & 7)) << 3)];
            }
#pragma unroll
            for (int m = 0; m < 2; ++m)
#pragma unroll
                for (int n = 0; n < 4; ++n)
                    acc[m][n] = __builtin_amdgcn_mfma_f32_16x16x32_bf16(
                        af[m], bfr[n], acc[m][n], 0, 0, 0);
        }
    };

    const int nt = K >> 6;
    STAGE(0, 0);
    drain_and_barrier();
    int cur = 0;
    for (int t = 0; t < nt; ++t) {
        if (t + 1 < nt) STAGE(cur ^ 1, (t + 1) << 6);
        COMPUTE(cur);
        drain_and_barrier();
        cur ^= 1;
    }

    const int rBase = row0 + w * 32 + g * 4;
    const int cBase = col0 + fr;
    float bv[4];
#pragma unroll
    for (int n = 0; n < 4; ++n) {
        const int c = cBase + n * 16;
        bv[n] = (bias && c < N) ? bias[c] : 0.0f;
    }
#pragma unroll
    for (int m = 0; m < 2; ++m) {
#pragma unroll
        for (int r = 0; r < 4; ++r) {
            const int rr = rBase + m * 16 + r;
#pragma unroll
            for (int n = 0; n < 4; ++n) {
                const int c = cBase + n * 16;
                if (c >= N) continue;
                float v = acc[m][n][r] + bv[n];
                if (GELU_) v = 0.5f * v * (1.0f + erff(v * 0.70710678118654752f));
                if (OUTBF) {
                    ((bf16_t*)Cv)[(size_t)rr * ldc + c] = (bf16_t)v;
                } else {
                    float* Cf = (float*)Cv;
                    const size_t idx = (size_t)rr * ldc + c;
                    if (ADD) v += Cf[idx];
                    Cf[idx] = v;
                }
            }
        }
    }
}

__global__ __launch_bounds__(256) void k_gemm_qkv(
    const bf16_t* A, const bf16_t* B, const float* bias, void* C,
    int M, int N, int K, int lda, int ldb, int ldc)
{ gemm_body<false, false, true>(A, B, bias, C, M, N, K, lda, ldb, ldc); }

__global__ __launch_bounds__(256) void k_gemm_fc(
    const bf16_t* A, const bf16_t* B, const float* bias, void* C,
    int M, int N, int K, int lda, int ldb, int ldc)
{ gemm_body<false, true, true>(A, B, bias, C, M, N, K, lda, ldb, ldc); }

// ---------------------------------------------------------------------------
// Small GEMM (oproj/proj): 64x64 tile, DB 2-phase, 16KB/buf -> ~5 blocks/CU.
// 4 waves; wave w computes all 64 rows x cols [w*16, w*16+16). f32 C += v.
// ---------------------------------------------------------------------------
__global__ __launch_bounds__(256) void k_gemm_small(
    const bf16_t* __restrict__ A, const bf16_t* __restrict__ Bw,
    const float* __restrict__ bias, float* __restrict__ C,
    int M, int N, int K, int lda, int ldb, int ldc)
{
    constexpr int BUF = 8192;               // A[64][64] @0, B[64][64] @4096
    __shared__ bf16_t lds[2 * BUF];

    const int tid  = threadIdx.x;
    const int lane = tid & 63;
    const int w    = tid >> 6;
    const int row0 = blockIdx.x * 64;
    const int col0 = blockIdx.y * 64;

    const int row8 = lane >> 3;
    const int sch  = (lane & 7) ^ row8;
    const int fr   = lane & 15;
    const int g    = lane >> 4;

    f32x4 acc[4];
#pragma unroll
    for (int m = 0; m < 4; ++m) acc[m] = (f32x4){0.f, 0.f, 0.f, 0.f};

    auto STAGE = [&](int buf, int k0) {
        bf16_t* lb = lds + buf * BUF;
#pragma unroll
        for (int it = 0; it < 2; ++it) {
            const int ar = row0 + it * 32 + w * 8 + row8;
            gload16(A + (size_t)ar * lda + k0 + sch * 8,
                    lb + (it * 32 + w * 8) * 64);
            const int br = col0 + it * 32 + w * 8 + row8;
            gload16(Bw + (size_t)br * ldb + k0 + sch * 8,
                    lb + 4096 + (it * 32 + w * 8) * 64);
        }
    };

    auto COMPUTE = [&](int buf) {
        bf16_t* lb = lds + buf * BUF;
#pragma unroll
        for (int ks = 0; ks < 2; ++ks) {
            const int cs = ks * 4 + g;
            const int bRow = w * 16 + fr;
            bf16x8 bfr = *(const bf16x8*)&lb[4096 + bRow * 64 + ((cs ^ (fr & 7)) << 3)];
#pragma unroll
            for (int m = 0; m < 4; ++m) {
                const int row = m * 16 + fr;
                bf16x8 af = *(const bf16x8*)&lb[row * 64 + ((cs ^ (fr & 7)) << 3)];
                acc[m] = __builtin_amdgcn_mfma_f32_16x16x32_bf16(
                    af, bfr, acc[m], 0, 0, 0);
            }
        }
    };

    const int nt = K >> 6;
    STAGE(0, 0);
    drain_and_barrier();
    int cur = 0;
    for (int t = 0; t < nt; ++t) {
        if (t + 1 < nt) STAGE(cur ^ 1, (t + 1) << 6);
        COMPUTE(cur);
        drain_and_barrier();
        cur ^= 1;
    }

    const int c = col0 + w * 16 + fr;
    const float bv = bias ? bias[c] : 0.0f;
#pragma unroll
    for (int m = 0; m < 4; ++m) {
#pragma unroll
        for (int r = 0; r < 4; ++r) {
            const int rr = row0 + m * 16 + g * 4 + r;
            const size_t idx = (size_t)rr * ldc + c;
            C[idx] += acc[m][r] + bv;
        }
    }
}

// ---------------------------------------------------------------------------
// LM head GEMM: 128x128 tile, BK=64, single-buffer, 4 waves 2x2.
// Epilogue: per-row (max, sum-exp) partials via cheap two-phase butterfly.
// ---------------------------------------------------------------------------
__global__ __launch_bounds__(256) void k_gemm_head(
    const bf16_t* __restrict__ A, const bf16_t* __restrict__ Bw,
    bf16_t* __restrict__ C, float* __restrict__ pmax, float* __restrict__ psum,
    int M, int N, int K, int lda, int ldb, int ldc)
{
    __shared__ bf16_t lds[16384];

    const int tid  = threadIdx.x;
    const int lane = tid & 63;
    const int w    = tid >> 6;
    const int wr   = w >> 1, wc = w & 1;
    const int row0 = blockIdx.x * 128;
    const int col0 = blockIdx.y * 128;

    const int row8 = lane >> 3;
    const int sch  = (lane & 7) ^ row8;
    const int fr   = lane & 15;
    const int g    = lane >> 4;

    const int aRowB = row0 + w * 32;
    const int bRowB = col0 + w * 32;

    f32x4 acc[4][4];
#pragma unroll
    for (int m = 0; m < 4; ++m)
#pragma unroll
        for (int n = 0; n < 4; ++n)
            acc[m][n] = (f32x4){0.f, 0.f, 0.f, 0.f};

    for (int k0 = 0; k0 < K; k0 += 64) {
#pragma unroll
        for (int it = 0; it < 4; ++it) {
            const int ar = aRowB + it * 8 + row8;
            gload16(A + (size_t)ar * lda + k0 + sch * 8,
                    lds + w * 2048 + it * 512);
            int br = bRowB + it * 8 + row8;
            if (br >= N) br = 0;
            gload16(Bw + (size_t)br * ldb + k0 + sch * 8,
                    lds + 8192 + w * 2048 + it * 512);
        }
        __syncthreads();

#pragma unroll
        for (int ks = 0; ks < 2; ++ks) {
            bf16x8 af[4], bfr[4];
            const int cs = ks * 4 + g;
#pragma unroll
            for (int m = 0; m < 4; ++m) {
                const int row = wr * 64 + m * 16 + fr;
                af[m] = *(const bf16x8*)&lds[row * 64 + ((cs ^ (fr & 7)) << 3)];
            }
#pragma unroll
            for (int n = 0; n < 4; ++n) {
                const int row = wc * 64 + n * 16 + fr;
                bfr[n] = *(const bf16x8*)&lds[8192 + row * 64 + ((cs ^ (fr & 7)) << 3)];
            }
#pragma unroll
            for (int m = 0; m < 4; ++m)
#pragma unroll
                for (int n = 0; n < 4; ++n)
                    acc[m][n] = __builtin_amdgcn_mfma_f32_16x16x32_bf16(
                        af[m], bfr[n], acc[m][n], 0, 0, 0);
        }
        __syncthreads();
    }

    const int rBase = row0 + wr * 64 + g * 4;
    const int cBase = col0 + wc * 64 + fr;
#pragma unroll
    for (int n = 0; n < 4; ++n) {
        const int c = cBase + n * 16;
        if (c >= N) continue;
#pragma unroll
        for (int m = 0; m < 4; ++m)
#pragma unroll
            for (int r = 0; r < 4; ++r)
                C[(size_t)(rBase + m * 16 + r) * ldc + c] = (bf16_t)acc[m][n][r];
    }

    // ---- per-row (max, sum-exp) partials: two-phase butterfly (no exp in merge)
    float* sred = (float*)lds;          // [2][128] max + [2][128] sum
#pragma unroll
    for (int m = 0; m < 4; ++m) {
#pragma unroll
        for (int r = 0; r < 4; ++r) {
            float lm = -3.0e38f;
#pragma unroll
            for (int n = 0; n < 4; ++n) {
                const int c = cBase + n * 16;
                if (c < N) lm = fmaxf(lm, (float)(bf16_t)acc[m][n][r]);
            }
#pragma unroll
            for (int off = 1; off < 16; off <<= 1)
                lm = fmaxf(lm, __shfl_xor(lm, off));
            float ls = 0.0f;
#pragma unroll
            for (int n = 0; n < 4; ++n) {
                const int c = cBase + n * 16;
                if (c < N) ls += __expf((float)(bf16_t)acc[m][n][r] - lm);
            }
#pragma unroll
            for (int off = 1; off < 16; off <<= 1)
                ls += __shfl_xor(ls, off);
            if (fr == 0) {
                const int rl = wr * 64 + m * 16 + g * 4 + r;
                sred[wc * 128 + rl] = lm;
                sred[256 + wc * 128 + rl] = ls;
            }
        }
    }
    __syncthreads();
    if ((w & 1) == 0) {
        const int rl = (w >> 1) * 64 + lane;
        const float m0 = sred[rl],       m1 = sred[128 + rl];
        const float s0 = sred[256 + rl], s1 = sred[384 + rl];
        const float M_ = fmaxf(m0, m1);
        const float S_ = s0 * __expf(m0 - M_) + s1 * __expf(m1 - M_);
        const size_t grow = row0 + rl;
        pmax[grow * 400 + blockIdx.y] = M_;
        psum[grow * 400 + blockIdx.y] = S_;
    }
}

// ---------------------------------------------------------------------------
// Launcher
// ---------------------------------------------------------------------------
extern "C" void kernel_launch(void* const* d_in, const int* in_sizes, int n_in,
                              void* d_out, int out_size, void* d_ws, size_t ws_size,
                              hipStream_t stream)
{
    constexpr int B = 4, S = 512, D = 768, L = 12, V = 50257, H = 12, F = 3072;
    constexpr int M  = B * S;     // 2048
    constexpr int TD = 3 * D;     // 2304
    constexpr int BH = B * H;     // 48
    constexpr int Vp = 50264;     // V padded to multiple of 8
    constexpr int NP = (V + 127) / 128;   // 393 column panels

    const int*   x    = (const int*)  d_in[0];
    const float* emb  = (const float*)d_in[1];
    const float* pos  = (const float*)d_in[2];
    const float* ln1g = (const float*)d_in[3];
    const float* ln1b = (const float*)d_in[4];
    const float* wqkv = (const float*)d_in[5];
    const float* bqkv = (const float*)d_in[6];
    const float* wo   = (const float*)d_in[7];
    const float* bo   = (const float*)d_in[8];
    const float* ln2g = (const float*)d_in[9];
    const float* ln2b = (const float*)d_in[10];
    const float* wfc  = (const float*)d_in[11];
    const float* bfc  = (const float*)d_in[12];
    const float* wpr  = (const float*)d_in[13];
    const float* bpr  = (const float*)d_in[14];
    const float* lnfg = (const float*)d_in[15];
    const float* lnfb = (const float*)d_in[16];

    float* probs  = (float*)d_out;                    // [M, V]
    float* hidden = probs + (size_t)M * V;            // [M, D]

    // ---- workspace layout (bump allocator, 256B aligned) ------------------
    char* wsb = (char*)d_ws;
    size_t off = 0;
    auto alloc = [&](size_t bytes) -> char* {
        char* p = wsb + off;
        off += (bytes + 255) & ~(size_t)255;
        return p;
    };
    // live-at-head buffers FIRST (never aliased by logits)
    bf16_t* hid_bf = (bf16_t*)alloc((size_t)M * D * 2);
    bf16_t* embB   = (bf16_t*)alloc((size_t)V * D * 2);
    // trunk region (dead at head time) — logits aliases it
    const size_t trunk_start = off;
    float*  h      = (float*) alloc((size_t)M * D * 4);
    bf16_t* qkv_bf = (bf16_t*)alloc((size_t)M * TD * 2);
    bf16_t* xn_bf  = (bf16_t*)alloc((size_t)M * D * 2);
    bf16_t* o_bf   = (bf16_t*)alloc((size_t)M * D * 2);
    bf16_t* mid_bf = (bf16_t*)alloc((size_t)M * F * 2);
    bf16_t* wqkvT  = (bf16_t*)alloc((size_t)L * D * TD * 2);
    bf16_t* woT    = (bf16_t*)alloc((size_t)L * D * D * 2);
    bf16_t* wfcT   = (bf16_t*)alloc((size_t)L * D * F * 2);
    bf16_t* wprT   = (bf16_t*)alloc((size_t)L * F * D * 2);
    const size_t logits_bytes = (size_t)M * Vp * 2;
    if (off < trunk_start + logits_bytes) off = trunk_start + logits_bytes;
    bf16_t* logits = (bf16_t*)(wsb + trunk_start);
    // softmax partials (live during head) AFTER the logits region
    float* pmax = (float*)alloc((size_t)M * 400 * 4);
    float* psum = (float*)alloc((size_t)M * 400 * 4);

    // ---- weight prep ------------------------------------------------------
    convert_bf16<<<2048, 256, 0, stream>>>(emb, embB, (V * D) / 4);
    transpose_to_bf16<<<dim3(TD / 32, D / 32, L), dim3(32, 8), 0, stream>>>(wqkv, wqkvT, D, TD);
    transpose_to_bf16<<<dim3(D / 32,  D / 32, L), dim3(32, 8), 0, stream>>>(wo,   woT,   D, D);
    transpose_to_bf16<<<dim3(F / 32,  D / 32, L), dim3(32, 8), 0, stream>>>(wfc,  wfcT,  D, F);
    transpose_to_bf16<<<dim3(D / 32,  F / 32, L), dim3(32, 8), 0, stream>>>(wpr,  wprT,  F, D);

    // ---- embedding
    embed_kernel<<<dim3((M * D + 255) / 256), 256, 0, stream>>>(x, emb, pos, h, S, D, M * D);

    for (int i = 0; i < L; ++i) {
        layernorm_dual<<<M, 256, 0, stream>>>(h, ln1g + (size_t)i * D, ln1b + (size_t)i * D,
                                              xn_bf, nullptr, D);

        k_gemm_qkv<<<dim3(M / 128, TD / 64), 256, 0, stream>>>(
            xn_bf, wqkvT + (size_t)i * D * TD, bqkv + (size_t)i * TD, qkv_bf,
            M, TD, D, D, D, TD);

        flash_attn<<<dim3(S / 64, BH), 256, 0, stream>>>(qkv_bf, o_bf);

        k_gemm_small<<<dim3(M / 64, D / 64), 256, 0, stream>>>(
            o_bf, woT + (size_t)i * D * D, bo + (size_t)i * D, h,
            M, D, D, D, D, D);

        layernorm_dual<<<M, 256, 0, stream>>>(h, ln2g + (size_t)i * D, ln2b + (size_t)i * D,
                                              xn_bf, nullptr, D);

        k_gemm_fc<<<dim3(M / 128, F / 64), 256, 0, stream>>>(
            xn_bf, wfcT + (size_t)i * D * F, bfc + (size_t)i * F, mid_bf,
            M, F, D, D, D, F);

        k_gemm_small<<<dim3(M / 64, D / 64), 256, 0, stream>>>(
            mid_bf, wprT + (size_t)i * F * D, bpr + (size_t)i * D, h,
            M, D, F, F, F, D);
    }

    layernorm_dual<<<M, 256, 0, stream>>>(h, lnfg, lnfb, hid_bf, hidden, D);

    k_gemm_head<<<dim3(M / 128, NP), 256, 0, stream>>>(
        hid_bf, embB, logits, pmax, psum,
        M, V, D, D, D, Vp);

    softmax_vocab<<<M, 256, 0, stream>>>(logits, pmax, psum, probs, V, Vp, NP);
}